// Round 4
// baseline (1670.537 us; speedup 1.0000x reference)
//
#include <hip/hip_runtime.h>

typedef unsigned short u16;
typedef unsigned int   u32;

typedef __attribute__((ext_vector_type(8))) __bf16 bf16x8;
typedef __attribute__((ext_vector_type(4))) float  f32x4;

// ---------- scalar/vec conversion helpers ----------
__device__ __forceinline__ float bf2f(u16 v) {
    return __uint_as_float(((u32)v) << 16);
}
__device__ __forceinline__ u16 f2bf(float f) {
    u32 u = __float_as_uint(f);
    u32 r = (u + 0x7fffu + ((u >> 16) & 1u)) >> 16;  // round-to-nearest-even
    return (u16)r;
}
__device__ __forceinline__ float ld1(const u16* p)   { return bf2f(*p); }
__device__ __forceinline__ float ld1(const float* p) { return *p; }

// ---------- problem constants ----------
#define BB 4
#define NTOK 2048
#define NATOM 16384
#define CTOK 384
#define CA 128
#define NQ 32
#define NK 128
#define NH 4
#define DH 32
#define NWIN 512
#define PAD 48

// Transposed-weight workspace layout (u16 elements).
// Each matrix stored as [N][K] hi-plane, then lo-plane (f32 path only).
#define WT_WA   0          // [128][384], lo plane at +49152
#define WT_L0   98304      // per-layer block start
#define WT_LSZ  393216     // Q 0 | K 32768 | V 65536 | O 98304 | T1 131072 | T2 262144
#define WT_WO   1277952    // [128][128], lo plane at +16384
#define WT_TOT  1310720

// =====================================================================
// dtype detector: look at low u16 of 1024 words of W_a.
// flag = 1 (bf16 inputs) or 0 (f32 inputs)
// =====================================================================
__global__ __launch_bounds__(256) void detect_kernel(const u32* __restrict__ wa,
                                                     int* __restrict__ flag)
{
    __shared__ int cnt;
    if (threadIdx.x == 0) cnt = 0;
    __syncthreads();
    int local = 0;
#pragma unroll
    for (int i = 0; i < 4; i++) {
        u32 w = wa[threadIdx.x * 4 + i];
        u32 e = (w >> 7) & 0xFFu;   // exponent field of the LOW u16 as bf16
        if (e >= 95u && e <= 135u) local++;
    }
    atomicAdd(&cnt, local);
    __syncthreads();
    if (threadIdx.x == 0) *flag = (cnt >= 614) ? 1 : 0;
}

// =====================================================================
// Weight transpose (+ bf16 split for f32 inputs) into WT workspace.
// 40 tiles of 128x128: Wa(3) | Wq/k/v/o x3 (12) | Wt1 (12) | Wt2 (12) | Wout(1)
// dst[n][k] = src[k][n]; f32 path: hi = bf16(w), lo = bf16(w - hi).
// =====================================================================
template<typename TIN, int SPLIT>
__global__ __launch_bounds__(256) void wtrans_kernel(
    const int* __restrict__ flag, int want,
    const TIN* __restrict__ Wa, const TIN* __restrict__ Wq,
    const TIN* __restrict__ Wk, const TIN* __restrict__ Wv,
    const TIN* __restrict__ Wo, const TIN* __restrict__ Wt1,
    const TIN* __restrict__ Wt2, const TIN* __restrict__ Wout,
    u16* __restrict__ WT)
{
    if (*flag != want) return;
    const int t = blockIdx.x;
    const TIN* S; int sld; u16* D; int dld; int plane;
    if (t < 3) {                                     // W_a [384][128]
        S = Wa + t * 128 * 128; sld = 128;
        D = WT + WT_WA + t * 128; dld = 384; plane = 49152;
    } else if (t < 15) {                             // Wq/k/v/o [128][128]
        const int i = t - 3, l = i >> 2, m = i & 3;
        const TIN* ms = (m == 0) ? Wq : (m == 1) ? Wk : (m == 2) ? Wv : Wo;
        S = ms + l * 16384; sld = 128;
        D = WT + WT_L0 + l * WT_LSZ + m * 32768; dld = 128; plane = 16384;
    } else if (t < 27) {                             // Wt1 [128][512] col-chunk c
        const int i = t - 15, l = i >> 2, c = i & 3;
        S = Wt1 + l * 65536 + c * 128; sld = 512;
        D = WT + WT_L0 + l * WT_LSZ + 131072 + c * 128 * 128; dld = 128; plane = 65536;
    } else if (t < 39) {                             // Wt2 [512][128] row-chunk c
        const int i = t - 27, l = i >> 2, c = i & 3;
        S = Wt2 + l * 65536 + c * 128 * 128; sld = 128;
        D = WT + WT_L0 + l * WT_LSZ + 262144 + c * 128; dld = 512; plane = 65536;
    } else {                                         // W_out [128][128]
        S = Wout; sld = 128;
        D = WT + WT_WO; dld = 128; plane = 16384;
    }
    const int tid = threadIdx.x;
    for (int id = tid; id < 2048; id += 256) {
        const int n = id >> 4, k0 = (id & 15) << 3;
        union { u16 s[8]; uint4 v; } hi, lo;
#pragma unroll
        for (int j = 0; j < 8; j++) {
            if constexpr (sizeof(TIN) == 2) {
                hi.s[j] = ((const u16*)(const void*)S)[(k0 + j) * sld + n];
                lo.s[j] = 0;
            } else {
                const float v = ((const float*)(const void*)S)[(k0 + j) * sld + n];
                const u16 hv = f2bf(v);
                hi.s[j] = hv;
                lo.s[j] = f2bf(v - bf2f(hv));
            }
        }
        *(uint4*)(D + n * dld + k0) = hi.v;
        if (SPLIT == 2) *(uint4*)(D + plane + n * dld + k0) = lo.v;
    }
}

// =====================================================================
// MFMA GEMM (8 waves x 16 rows): C[M x 128] = A[M x K](bf16) @ WT[128][K].
// grid.x = M/128, 512 threads. No LDS, no barriers.
// NSPLIT=2 adds the lo-plane MFMA (f32 weights split into hi+lo bf16).
// =====================================================================
template<int NSPLIT, int K, bool OUT_BF16, bool ADD>
__global__ __launch_bounds__(512, 4) void mgemm(
    const int* __restrict__ flag, int want,
    const u16* __restrict__ A, int lda,
    const u16* __restrict__ WT, int ldk,
    void* __restrict__ Cv, int ldc)
{
    if (*flag != want) return;
    const int tid  = threadIdx.x;
    const int lane = tid & 63, wv = tid >> 6;     // 8 waves
    const int l15  = lane & 15, lg = lane >> 4;
    const long long row0 = (long long)blockIdx.x * 128 + wv * 16;
    const int plane = ldk << 7;   // 128 * ldk

    f32x4 acc[8];
    {
        f32x4 z = {0.f, 0.f, 0.f, 0.f};
#pragma unroll
        for (int n = 0; n < 8; n++) acc[n] = z;
    }

    const u16* A0 = A + (row0 + l15) * (long long)lda + lg * 8;
    const u16* W0 = WT + (long long)l15 * ldk + lg * 8;

    for (int kk = 0; kk < K; kk += 32) {
        const bf16x8 a0 = *(const bf16x8*)(A0 + kk);
#pragma unroll
        for (int n = 0; n < 8; n++) {
            const bf16x8 b = *(const bf16x8*)(W0 + n * 16 * ldk + kk);
            acc[n] = __builtin_amdgcn_mfma_f32_16x16x32_bf16(a0, b, acc[n], 0, 0, 0);
            if (NSPLIT == 2) {
                const bf16x8 bl = *(const bf16x8*)(W0 + plane + n * 16 * ldk + kk);
                acc[n] = __builtin_amdgcn_mfma_f32_16x16x32_bf16(a0, bl, acc[n], 0, 0, 0);
            }
        }
    }

#pragma unroll
    for (int r = 0; r < 4; r++) {
        const long long row = row0 + lg * 4 + r;
        if (OUT_BF16) {
            u16* C = (u16*)Cv + row * ldc;
#pragma unroll
            for (int n = 0; n < 8; n++) C[n * 16 + l15] = f2bf(acc[n][r]);
        } else {
            float* C = (float*)Cv + row * ldc;
#pragma unroll
            for (int n = 0; n < 8; n++) {
                float v = acc[n][r];
                if (ADD) v += C[n * 16 + l15];
                C[n * 16 + l15] = v;
            }
        }
    }
}

// =====================================================================
// MFMA GEMM with f32 A split in-kernel into hi+lo bf16 (8 waves x 16 rows).
// acc = Ahi@Whi + Alo@Whi (+ Ahi@Wlo for NSPLIT=2; lo*lo dropped, ~2^-32).
// =====================================================================
template<int NSPLIT, int K, bool OUT_BF16>
__global__ __launch_bounds__(512, 4) void msgemm(
    const int* __restrict__ flag, int want,
    const float* __restrict__ A, int lda,
    const u16* __restrict__ WT, int ldk,
    void* __restrict__ Cv, int ldc)
{
    if (*flag != want) return;
    const int tid  = threadIdx.x;
    const int lane = tid & 63, wv = tid >> 6;
    const int l15  = lane & 15, lg = lane >> 4;
    const long long row0 = (long long)blockIdx.x * 128 + wv * 16;
    const int plane = ldk << 7;

    f32x4 acc[8];
    {
        f32x4 z = {0.f, 0.f, 0.f, 0.f};
#pragma unroll
        for (int n = 0; n < 8; n++) acc[n] = z;
    }

    const float* A0 = A + (row0 + l15) * (long long)lda + lg * 8;
    const u16* W0 = WT + (long long)l15 * ldk + lg * 8;

    for (int kk = 0; kk < K; kk += 32) {
        const float4 f0 = *(const float4*)(A0 + kk);
        const float4 f1 = *(const float4*)(A0 + kk + 4);
        const float f[8] = {f0.x, f0.y, f0.z, f0.w, f1.x, f1.y, f1.z, f1.w};
        union { u16 s[8]; bf16x8 v; } hi, lo;
#pragma unroll
        for (int j = 0; j < 8; j++) {
            const u16 hv = f2bf(f[j]);
            hi.s[j] = hv;
            lo.s[j] = f2bf(f[j] - bf2f(hv));
        }
#pragma unroll
        for (int n = 0; n < 8; n++) {
            const bf16x8 b = *(const bf16x8*)(W0 + n * 16 * ldk + kk);
            acc[n] = __builtin_amdgcn_mfma_f32_16x16x32_bf16(hi.v, b, acc[n], 0, 0, 0);
            acc[n] = __builtin_amdgcn_mfma_f32_16x16x32_bf16(lo.v, b, acc[n], 0, 0, 0);
            if (NSPLIT == 2) {
                const bf16x8 bl = *(const bf16x8*)(W0 + plane + n * 16 * ldk + kk);
                acc[n] = __builtin_amdgcn_mfma_f32_16x16x32_bf16(hi.v, bl, acc[n], 0, 0, 0);
            }
        }
    }

#pragma unroll
    for (int r = 0; r < 4; r++) {
        const long long row = row0 + lg * 4 + r;
        if (OUT_BF16) {
            u16* C = (u16*)Cv + row * ldc;
#pragma unroll
            for (int n = 0; n < 8; n++) C[n * 16 + l15] = f2bf(acc[n][r]);
        } else {
            float* C = (float*)Cv + row * ldc;
#pragma unroll
            for (int n = 0; n < 8; n++) C[n * 16 + l15] = acc[n][r];
        }
    }
}

// =====================================================================
// Fused MLP (8 waves x 16 rows): x += relu(h @ Wt1) @ Wt2, looping the
// 4 hidden chunks in-register; hidden (bf16) round-trips via per-wave LDS.
// =====================================================================
template<int NSPLIT>
__global__ __launch_bounds__(512, 4) void mlp_fused(
    const int* __restrict__ flag, int want,
    const u16* __restrict__ h,
    const u16* __restrict__ W1T, const u16* __restrict__ W2T,
    float* __restrict__ x)
{
    if (*flag != want) return;
    __shared__ __align__(16) u16 Pl[8][16][132];
    const int tid  = threadIdx.x;
    const int lane = tid & 63, wv = tid >> 6;
    const int l15  = lane & 15, lg = lane >> 4;
    const long long row0 = (long long)blockIdx.x * 128 + wv * 16;

    bf16x8 ah[4];
#pragma unroll
    for (int kk = 0; kk < 4; kk++)
        ah[kk] = *(const bf16x8*)(h + (row0 + l15) * 128 + kk * 32 + lg * 8);

    f32x4 xacc[8];
    {
        f32x4 z = {0.f, 0.f, 0.f, 0.f};
#pragma unroll
        for (int n = 0; n < 8; n++) xacc[n] = z;
    }

    for (int c = 0; c < 4; c++) {
        f32x4 hacc[8];
        {
            f32x4 z = {0.f, 0.f, 0.f, 0.f};
#pragma unroll
            for (int n = 0; n < 8; n++) hacc[n] = z;
        }
#pragma unroll
        for (int kk = 0; kk < 4; kk++) {
#pragma unroll
            for (int n = 0; n < 8; n++) {
                const u16* wp = W1T + (c * 128 + n * 16 + l15) * 128 + kk * 32 + lg * 8;
                const bf16x8 b = *(const bf16x8*)wp;
                hacc[n] = __builtin_amdgcn_mfma_f32_16x16x32_bf16(ah[kk], b, hacc[n], 0, 0, 0);
                if (NSPLIT == 2) {
                    const bf16x8 bl = *(const bf16x8*)(wp + 65536);
                    hacc[n] = __builtin_amdgcn_mfma_f32_16x16x32_bf16(ah[kk], bl, hacc[n], 0, 0, 0);
                }
            }
        }
        // relu + bf16 -> per-wave LDS (WAR: drain prior chunk's reads first)
        asm volatile("s_waitcnt lgkmcnt(0)" ::: "memory");
#pragma unroll
        for (int n = 0; n < 8; n++)
#pragma unroll
            for (int r = 0; r < 4; r++)
                Pl[wv][lg * 4 + r][n * 16 + l15] = f2bf(fmaxf(hacc[n][r], 0.f));
        asm volatile("s_waitcnt lgkmcnt(0)" ::: "memory");

        bf16x8 a2[4];
#pragma unroll
        for (int kk = 0; kk < 4; kk++) {
            union { uint2 u[2]; bf16x8 v; } tmp;
            tmp.u[0] = *(const uint2*)&Pl[wv][l15][kk * 32 + lg * 8];
            tmp.u[1] = *(const uint2*)&Pl[wv][l15][kk * 32 + lg * 8 + 4];
            a2[kk] = tmp.v;
        }
#pragma unroll
        for (int kk = 0; kk < 4; kk++) {
#pragma unroll
            for (int n = 0; n < 8; n++) {
                const u16* wp = W2T + (n * 16 + l15) * 512 + c * 128 + kk * 32 + lg * 8;
                const bf16x8 b = *(const bf16x8*)wp;
                xacc[n] = __builtin_amdgcn_mfma_f32_16x16x32_bf16(a2[kk], b, xacc[n], 0, 0, 0);
                if (NSPLIT == 2) {
                    const bf16x8 bl = *(const bf16x8*)(wp + 65536);
                    xacc[n] = __builtin_amdgcn_mfma_f32_16x16x32_bf16(a2[kk], bl, xacc[n], 0, 0, 0);
                }
            }
        }
    }

#pragma unroll
    for (int r = 0; r < 4; r++) {
        float* X = x + (row0 + lg * 4 + r) * 128;
#pragma unroll
        for (int n = 0; n < 8; n++) X[n * 16 + l15] += xacc[n][r];
    }
}

// =====================================================================
// Gather: x[b,n,:] = a_tok[b, idx[b,n], :]   (f32 -> f32)
// =====================================================================
__global__ __launch_bounds__(256) void gather_kernel(
    const int* __restrict__ flag, int want,
    const float* __restrict__ a_tok, const int* __restrict__ idx,
    float* __restrict__ x)
{
    if (*flag != want) return;
    const size_t i = (size_t)blockIdx.x * 256 + threadIdx.x;  // B*N*128 total
    const int c = (int)(i & 127);
    const size_t an = i >> 7;
    const int b = (int)(an >> 14);
    const int n = (int)(an & (NATOM - 1));
    const int t = idx[b * NATOM + n];
    x[i] = a_tok[(((size_t)b * NTOK) + t) * CA + c];
}

// =====================================================================
// LayerNorm: h = (x-m)*rsqrt(var+1e-5)*g + b   (f32 in, bf16 out)
// =====================================================================
template<typename TW>
__global__ __launch_bounds__(256) void ln_kernel(
    const int* __restrict__ flag, int want,
    const float* __restrict__ x, const TW* __restrict__ g,
    const TW* __restrict__ b, u16* __restrict__ h)
{
    if (*flag != want) return;
    const int lane = threadIdx.x & 63;
    const int wv   = threadIdx.x >> 6;
    const size_t atom = (size_t)blockIdx.x * 4 + wv;
    const float* xr = x + atom * CA;
    const float v0 = xr[lane], v1 = xr[lane + 64];
    float s  = v0 + v1;
    float sq = v0 * v0 + v1 * v1;
#pragma unroll
    for (int off = 32; off > 0; off >>= 1) {
        s  += __shfl_xor(s,  off, 64);
        sq += __shfl_xor(sq, off, 64);
    }
    const float mean = s * 0.0078125f;
    const float var  = sq * 0.0078125f - mean * mean;
    const float inv  = rsqrtf(var + 1e-5f);
    u16* hr = h + atom * CA;
    hr[lane]      = f2bf((v0 - mean) * inv * ld1(g + lane)      + ld1(b + lane));
    hr[lane + 64] = f2bf((v1 - mean) * inv * ld1(g + lane + 64) + ld1(b + lane + 64));
}

// =====================================================================
// Bias: t[b,a,h] for a < 128 from the pair-MLP; single block, 512 threads
// =====================================================================
template<typename TW>
__global__ __launch_bounds__(512) void bias_kernel(
    const int* __restrict__ flag, int want,
    const float* __restrict__ x,
    const TW* __restrict__ Wcl, const TW* __restrict__ Wcm,
    const TW* __restrict__ Wm1, const TW* __restrict__ Wm2,
    const TW* __restrict__ Wpb, float* __restrict__ tb)
{
    if (*flag != want) return;
    __shared__ float Wsum[128][16];
    __shared__ float M1[16][16];
    __shared__ float M2[16][16];
    __shared__ float Pb[16][4];
    const int tid = threadIdx.x;
    for (int i = tid; i < 128 * 16; i += 512)
        Wsum[i >> 4][i & 15] = ld1(Wcl + i) + ld1(Wcm + i);
    if (tid < 256) M1[tid >> 4][tid & 15] = ld1(Wm1 + tid);
    if (tid >= 256 && tid < 512) { int t2 = tid - 256; M2[t2 >> 4][t2 & 15] = ld1(Wm2 + t2); }
    if (tid < 64) Pb[tid >> 2][tid & 3] = ld1(Wpb + tid);
    __syncthreads();

    const int b = tid >> 7, a = tid & 127;
    const float* xa = x + ((size_t)b * NATOM + a) * CA;
    float u[16];
#pragma unroll
    for (int p = 0; p < 16; p++) u[p] = 0.f;
    for (int c = 0; c < 128; c++) {
        const float xv = xa[c];
#pragma unroll
        for (int p = 0; p < 16; p++) u[p] = fmaf(xv, Wsum[c][p], u[p]);
    }
    float r1[16];
#pragma unroll
    for (int p = 0; p < 16; p++) r1[p] = 0.f;
    for (int c = 0; c < 16; c++) {
        const float rv = fmaxf(u[c], 0.f);
#pragma unroll
        for (int p = 0; p < 16; p++) r1[p] = fmaf(rv, M1[c][p], r1[p]);
    }
    float r2[16];
#pragma unroll
    for (int p = 0; p < 16; p++) r2[p] = 0.f;
    for (int c = 0; c < 16; c++) {
        const float rv = fmaxf(r1[c], 0.f);
#pragma unroll
        for (int p = 0; p < 16; p++) r2[p] = fmaf(rv, M2[c][p], r2[p]);
    }
#pragma unroll
    for (int hh = 0; hh < 4; hh++) {
        float s = 0.f;
#pragma unroll
        for (int p = 0; p < 16; p++) s = fmaf(r2[p], Pb[p][hh], s);
        tb[(size_t)tid * 4 + hh] = s;
    }
}

// =====================================================================
// Windowed attention via MFMA (verified round 1): one block per (b, w).
// =====================================================================
#define VTP 132   // V^T row stride in u16
#define PPS 68    // P row stride in u16

__global__ __launch_bounds__(256) void attn_kernel(
    const int* __restrict__ flag, int want,
    const u16* __restrict__ qg, const u16* __restrict__ kg,
    const u16* __restrict__ vg, const float* __restrict__ tb,
    u16* __restrict__ og)
{
    if (*flag != want) return;
    __shared__ __align__(16) u16 VT[128][VTP];    // V^T: [d][j]
    __shared__ __align__(16) u16 Pl[NH][32][PPS]; // per-head P half

    const int tid  = threadIdx.x;
    const int lane = tid & 63;
    const int h    = tid >> 6;             // wave id == head
    const int b    = blockIdx.x >> 9;
    const int w    = blockIdx.x & (NWIN - 1);
    const int row0 = w * NQ;
    const int kbase = row0 - PAD;          // first key atom (may be < 0)
    const int l15 = lane & 15;
    const int lg  = lane >> 4;

    // ---- stage V^T into LDS (all 256 threads; zero invalid rows) ----
    {
        const int j  = tid & 127;
        const int d0 = (tid >> 7) << 6;    // 0 or 64
        const int ga = kbase + j;
        const bool val = (ga >= 0) && (ga < NATOM);
        const u16* vrow = vg + ((long long)b * NATOM + ga) * CA + d0;
#pragma unroll
        for (int t2 = 0; t2 < 8; t2++) {
            union { uint4 q; u16 s[8]; } u;
            if (val) u.q = *(const uint4*)(vrow + t2 * 8);
            else     u.q = make_uint4(0u, 0u, 0u, 0u);
#pragma unroll
            for (int e = 0; e < 8; e++) VT[d0 + t2 * 8 + e][j] = u.s[e];
        }
    }

    // ---- QK^T: S[32][128] per head, frags direct from global ----
    const long long qoff = ((long long)b * NATOM + row0) * CA + h * DH;
    const long long koff = ((long long)b * NATOM + kbase) * CA + h * DH;
    bf16x8 aq0 = *(const bf16x8*)(qg + qoff + (long long)l15 * CA + lg * 8);
    bf16x8 aq1 = *(const bf16x8*)(qg + qoff + (long long)(l15 + 16) * CA + lg * 8);

    f32x4 acc[2][8];
    {
        f32x4 z = {0.f, 0.f, 0.f, 0.f};
#pragma unroll
        for (int m = 0; m < 2; m++)
#pragma unroll
            for (int n = 0; n < 8; n++) acc[m][n] = z;
    }
#pragma unroll
    for (int n = 0; n < 8; n++) {
        bf16x8 bk = *(const bf16x8*)(kg + koff + (long long)(n * 16 + l15) * CA + lg * 8);
        acc[0][n] = __builtin_amdgcn_mfma_f32_16x16x32_bf16(aq0, bk, acc[0][n], 0, 0, 0);
        acc[1][n] = __builtin_amdgcn_mfma_f32_16x16x32_bf16(aq1, bk, acc[1][n], 0, 0, 0);
    }

    // ---- bias + scale + mask ----
    const float scale = 0.17677669529663687f;  // 1/sqrt(32)
    float tj[8], ti[2][4];
#pragma unroll
    for (int n = 0; n < 8; n++)
        tj[n] = tb[((size_t)b * 128 + n * 16 + l15) * 4 + h];
#pragma unroll
    for (int m = 0; m < 2; m++)
#pragma unroll
        for (int r = 0; r < 4; r++)
            ti[m][r] = tb[((size_t)b * 128 + m * 16 + lg * 4 + r) * 4 + h];

#pragma unroll
    for (int n = 0; n < 8; n++) {
        const int ga = kbase + n * 16 + l15;
        const bool val = (ga >= 0) && (ga < NATOM);
#pragma unroll
        for (int m = 0; m < 2; m++)
#pragma unroll
            for (int r = 0; r < 4; r++) {
                const float s = acc[m][n][r] * scale + ti[m][r] + tj[n];
                acc[m][n][r] = val ? s : -1e9f;
            }
    }

    // ---- softmax ----
    float mx[2][4], inv[2][4];
#pragma unroll
    for (int m = 0; m < 2; m++)
#pragma unroll
        for (int r = 0; r < 4; r++) {
            float v = acc[m][0][r];
#pragma unroll
            for (int n = 1; n < 8; n++) v = fmaxf(v, acc[m][n][r]);
            v = fmaxf(v, __shfl_xor(v, 1, 64));
            v = fmaxf(v, __shfl_xor(v, 2, 64));
            v = fmaxf(v, __shfl_xor(v, 4, 64));
            v = fmaxf(v, __shfl_xor(v, 8, 64));
            mx[m][r] = v;
        }
#pragma unroll
    for (int m = 0; m < 2; m++)
#pragma unroll
        for (int n = 0; n < 8; n++)
#pragma unroll
            for (int r = 0; r < 4; r++)
                acc[m][n][r] = __expf(acc[m][n][r] - mx[m][r]);
#pragma unroll
    for (int m = 0; m < 2; m++)
#pragma unroll
        for (int r = 0; r < 4; r++) {
            float v = 0.f;
#pragma unroll
            for (int n = 0; n < 8; n++) v += acc[m][n][r];
            v += __shfl_xor(v, 1, 64);
            v += __shfl_xor(v, 2, 64);
            v += __shfl_xor(v, 4, 64);
            v += __shfl_xor(v, 8, 64);
            inv[m][r] = 1.0f / v;
        }

    __syncthreads();   // V^T staged

    // ---- PV ----
    f32x4 o[2][2];
    {
        f32x4 z = {0.f, 0.f, 0.f, 0.f};
        o[0][0] = z; o[0][1] = z; o[1][0] = z; o[1][1] = z;
    }
    union B8 { bf16x8 v; uint2 u[2]; };
#pragma unroll
    for (int half = 0; half < 2; half++) {
        asm volatile("s_waitcnt lgkmcnt(0)" ::: "memory");
#pragma unroll
        for (int m = 0; m < 2; m++)
#pragma unroll
            for (int nn = 0; nn < 4; nn++)
#pragma unroll
                for (int r = 0; r < 4; r++)
                    Pl[h][m * 16 + lg * 4 + r][nn * 16 + l15]
                        = f2bf(acc[m][half * 4 + nn][r]);
        asm volatile("s_waitcnt lgkmcnt(0)" ::: "memory");
#pragma unroll
        for (int ks2 = 0; ks2 < 2; ks2++) {
            const int jo = ks2 * 32 + lg * 8;
            const int jg = half * 64 + jo;
            B8 pa0, pa1, vb0, vb1;
            pa0.u[0] = *(const uint2*)&Pl[h][l15][jo];
            pa0.u[1] = *(const uint2*)&Pl[h][l15][jo + 4];
            pa1.u[0] = *(const uint2*)&Pl[h][l15 + 16][jo];
            pa1.u[1] = *(const uint2*)&Pl[h][l15 + 16][jo + 4];
            vb0.u[0] = *(const uint2*)&VT[h * DH + l15][jg];
            vb0.u[1] = *(const uint2*)&VT[h * DH + l15][jg + 4];
            vb1.u[0] = *(const uint2*)&VT[h * DH + 16 + l15][jg];
            vb1.u[1] = *(const uint2*)&VT[h * DH + 16 + l15][jg + 4];
            o[0][0] = __builtin_amdgcn_mfma_f32_16x16x32_bf16(pa0.v, vb0.v, o[0][0], 0, 0, 0);
            o[0][1] = __builtin_amdgcn_mfma_f32_16x16x32_bf16(pa0.v, vb1.v, o[0][1], 0, 0, 0);
            o[1][0] = __builtin_amdgcn_mfma_f32_16x16x32_bf16(pa1.v, vb0.v, o[1][0], 0, 0, 0);
            o[1][1] = __builtin_amdgcn_mfma_f32_16x16x32_bf16(pa1.v, vb1.v, o[1][1], 0, 0, 0);
        }
    }

#pragma unroll
    for (int m = 0; m < 2; m++)
#pragma unroll
        for (int n = 0; n < 2; n++)
#pragma unroll
            for (int r = 0; r < 4; r++)
                og[((long long)b * NATOM + row0 + m * 16 + lg * 4 + r) * CA
                   + h * DH + n * 16 + l15]
                    = f2bf(o[m][n][r] * inv[m][r]);
}

// =====================================================================
// Final selector: write d_out as bf16 (flag=1) or f32 (flag=0)
// =====================================================================
__global__ __launch_bounds__(256) void select_kernel(
    const int* __restrict__ flag,
    const u16* __restrict__ outA, const u16* __restrict__ outB,
    void* __restrict__ d_out)
{
    const size_t i = (size_t)blockIdx.x * 256 + threadIdx.x;
    if (*flag) ((u16*)d_out)[i]   = outA[i];
    else       ((float*)d_out)[i] = bf2f(outB[i]);
}

// =====================================================================
// One full pipeline pass, templated on input storage type, gated on flag
// =====================================================================
template<typename TIN>
static void run_pass(void* const* d_in,
                     float* x, u16* h, u16* qb, u16* kb, u16* vb, u16* ob,
                     float* atok, u16* wt, float* tbv, u16* outbuf,
                     const int* flag, int want, hipStream_t stream)
{
    constexpr int NS = (sizeof(TIN) == 2) ? 1 : 2;

    const TIN* a    = (const TIN*)d_in[0];
    const int* idx  = (const int*)d_in[2];
    const TIN* W_a  = (const TIN*)d_in[3];
    const TIN* W_o  = (const TIN*)d_in[4];
    const TIN* Wcl  = (const TIN*)d_in[5];
    const TIN* Wcm  = (const TIN*)d_in[6];
    const TIN* Wm1  = (const TIN*)d_in[7];
    const TIN* Wm2  = (const TIN*)d_in[8];
    const TIN* Wpb  = (const TIN*)d_in[9];
    const TIN* Wq   = (const TIN*)d_in[10];
    const TIN* Wk   = (const TIN*)d_in[11];
    const TIN* Wv   = (const TIN*)d_in[12];
    const TIN* Wo   = (const TIN*)d_in[13];
    const TIN* ln1g = (const TIN*)d_in[14];
    const TIN* ln1b = (const TIN*)d_in[15];
    const TIN* Wt1  = (const TIN*)d_in[16];
    const TIN* Wt2  = (const TIN*)d_in[17];
    const TIN* ln2g = (const TIN*)d_in[18];
    const TIN* ln2b = (const TIN*)d_in[19];

    const size_t NEL = (size_t)BB * NATOM * CA;

    // 0) transpose (+split) all weights into WT workspace
    wtrans_kernel<TIN, NS><<<40, 256, 0, stream>>>(
        flag, want, W_a, Wq, Wk, Wv, Wo, Wt1, Wt2, W_o, wt);

    // 1) token projection [8192 x 384] @ [384 x 128] -> f32 atok
    if constexpr (NS == 1)
        mgemm<1, CTOK, false, false><<<BB * NTOK / 128, 512, 0, stream>>>(
            flag, want, (const u16*)a, CTOK, wt + WT_WA, CTOK, atok, CA);
    else
        msgemm<2, CTOK, false><<<BB * NTOK / 128, 512, 0, stream>>>(
            flag, want, (const float*)a, CTOK, wt + WT_WA, CTOK, atok, CA);

    gather_kernel<<<(unsigned)(NEL / 256), 256, 0, stream>>>(flag, want, atok, idx, x);
    bias_kernel<TIN><<<1, 512, 0, stream>>>(flag, want, x, Wcl, Wcm, Wm1, Wm2, Wpb, tbv);

    for (int l = 0; l < 3; l++) {
        u16* wl = wt + WT_L0 + (size_t)l * WT_LSZ;
        ln_kernel<TIN><<<BB * NATOM / 4, 256, 0, stream>>>(flag, want, x, ln1g + l * CA, ln1b + l * CA, h);
        mgemm<NS, CA, true, false><<<512, 512, 0, stream>>>(flag, want, h, CA, wl,          CA, qb, CA);
        mgemm<NS, CA, true, false><<<512, 512, 0, stream>>>(flag, want, h, CA, wl + 32768,  CA, kb, CA);
        mgemm<NS, CA, true, false><<<512, 512, 0, stream>>>(flag, want, h, CA, wl + 65536,  CA, vb, CA);
        attn_kernel<<<BB * NWIN, 256, 0, stream>>>(flag, want, qb, kb, vb, tbv, ob);
        mgemm<NS, CA, false, true><<<512, 512, 0, stream>>>(flag, want, ob, CA, wl + 98304, CA, x, CA);
        ln_kernel<TIN><<<BB * NATOM / 4, 256, 0, stream>>>(flag, want, x, ln2g + l * CA, ln2b + l * CA, h);
        mlp_fused<NS><<<512, 512, 0, stream>>>(flag, want, h, wl + 131072, wl + 262144, x);
    }
    // out = x @ W_out -> bf16 outbuf (A is f32 residual: in-kernel split)
    msgemm<NS, CA, true><<<512, 512, 0, stream>>>(
        flag, want, x, CA, wt + WT_WO, CA, outbuf, CA);
}

// =====================================================================
// Launch
// =====================================================================
extern "C" void kernel_launch(void* const* d_in, const int* in_sizes, int n_in,
                              void* d_out, int out_size, void* d_ws, size_t ws_size,
                              hipStream_t stream)
{
    (void)in_sizes; (void)n_in; (void)out_size;
    const size_t NEL = (size_t)BB * NATOM * CA;   // 8388608

    char* p = (char*)d_ws;
    float* x    = (float*)p;  p += NEL * 4;
    u16*   h    = (u16*)p;    p += NEL * 2;
    u16*   qb   = (u16*)p;    p += NEL * 2;
    u16*   kb   = (u16*)p;    p += NEL * 2;
    u16*   vb   = (u16*)p;    p += NEL * 2;
    u16*   ob   = (u16*)p;    p += NEL * 2;
    float* atok = (float*)p;  p += (size_t)BB * NTOK * CA * 4;
    float* tbv  = (float*)p;  p += 8192;
    u16*   outA = (u16*)p;    p += NEL * 2;
    u16*   outB = (u16*)p;    p += NEL * 2;
    int*   flag = (int*)p;    p += 256;
    u16*   wt   = (u16*)p;    p += (size_t)WT_TOT * 2;
    if ((size_t)(p - (char*)d_ws) > ws_size) return;  // workspace too small

    // 1) detect input storage dtype (writes flag: 1=bf16, 0=f32)
    detect_kernel<<<1, 256, 0, stream>>>((const u32*)d_in[3], flag);
    // 2) bf16-interpretation pass (runs only if flag==1)
    run_pass<u16>(d_in, x, h, qb, kb, vb, ob, atok, wt, tbv, outA, flag, 1, stream);
    // 3) f32-interpretation pass (runs only if flag==0)
    run_pass<float>(d_in, x, h, qb, kb, vb, ob, atok, wt, tbv, outB, flag, 0, stream);
    // 4) write d_out in the detected output format
    select_kernel<<<(unsigned)(NEL / 256), 256, 0, stream>>>(flag, outA, outB, d_out);
}

// Round 5
// 788.072 us; speedup vs baseline: 2.1198x; 2.1198x over previous
//
#include <hip/hip_runtime.h>

typedef unsigned short u16;
typedef unsigned int   u32;

typedef __attribute__((ext_vector_type(8))) __bf16 bf16x8;
typedef __attribute__((ext_vector_type(4))) float  f32x4;

// ---------- scalar/vec conversion helpers ----------
__device__ __forceinline__ float bf2f(u16 v) {
    return __uint_as_float(((u32)v) << 16);
}
__device__ __forceinline__ u16 f2bf(float f) {
    u32 u = __float_as_uint(f);
    u32 r = (u + 0x7fffu + ((u >> 16) & 1u)) >> 16;  // round-to-nearest-even
    return (u16)r;
}
__device__ __forceinline__ float ld1(const u16* p)   { return bf2f(*p); }
__device__ __forceinline__ float ld1(const float* p) { return *p; }

// ---------- problem constants ----------
#define BB 4
#define NTOK 2048
#define NATOM 16384
#define CTOK 384
#define CA 128
#define NQ 32
#define NK 128
#define NH 4
#define DH 32
#define NWIN 512
#define PAD 48

// Transposed-weight workspace layout (u16 elements).
// Each matrix stored as [N][K] hi-plane, then lo-plane (f32 path only).
#define WT_WA   0          // [128][384], lo plane at +49152
#define WT_L0   98304      // per-layer block start
#define WT_LSZ  393216     // Q 0 | K 32768 | V 65536 | O 98304 | T1 131072 | T2 262144
#define WT_WO   1277952    // [128][128], lo plane at +16384
#define WT_TOT  1310720

// =====================================================================
// dtype detector: look at low u16 of 1024 words of W_a.
// flag = 1 (bf16 inputs) or 0 (f32 inputs)
// =====================================================================
__global__ __launch_bounds__(256) void detect_kernel(const u32* __restrict__ wa,
                                                     int* __restrict__ flag)
{
    __shared__ int cnt;
    if (threadIdx.x == 0) cnt = 0;
    __syncthreads();
    int local = 0;
#pragma unroll
    for (int i = 0; i < 4; i++) {
        u32 w = wa[threadIdx.x * 4 + i];
        u32 e = (w >> 7) & 0xFFu;   // exponent field of the LOW u16 as bf16
        if (e >= 95u && e <= 135u) local++;
    }
    atomicAdd(&cnt, local);
    __syncthreads();
    if (threadIdx.x == 0) *flag = (cnt >= 614) ? 1 : 0;
}

// =====================================================================
// Weight transpose (+ bf16 split for f32 inputs) into WT workspace.
// 40 tiles of 128x128: Wa(3) | Wq/k/v/o x3 (12) | Wt1 (12) | Wt2 (12) | Wout(1)
// dst[n][k] = src[k][n]; f32 path: hi = bf16(w), lo = bf16(w - hi).
// =====================================================================
template<typename TIN, int SPLIT>
__global__ __launch_bounds__(256) void wtrans_kernel(
    const int* __restrict__ flag, int want,
    const TIN* __restrict__ Wa, const TIN* __restrict__ Wq,
    const TIN* __restrict__ Wk, const TIN* __restrict__ Wv,
    const TIN* __restrict__ Wo, const TIN* __restrict__ Wt1,
    const TIN* __restrict__ Wt2, const TIN* __restrict__ Wout,
    u16* __restrict__ WT)
{
    if (*flag != want) return;
    const int t = blockIdx.x;
    const TIN* S; int sld; u16* D; int dld; int plane;
    if (t < 3) {                                     // W_a [384][128]
        S = Wa + t * 128 * 128; sld = 128;
        D = WT + WT_WA + t * 128; dld = 384; plane = 49152;
    } else if (t < 15) {                             // Wq/k/v/o [128][128]
        const int i = t - 3, l = i >> 2, m = i & 3;
        const TIN* ms = (m == 0) ? Wq : (m == 1) ? Wk : (m == 2) ? Wv : Wo;
        S = ms + l * 16384; sld = 128;
        D = WT + WT_L0 + l * WT_LSZ + m * 32768; dld = 128; plane = 16384;
    } else if (t < 27) {                             // Wt1 [128][512] col-chunk c
        const int i = t - 15, l = i >> 2, c = i & 3;
        S = Wt1 + l * 65536 + c * 128; sld = 512;
        D = WT + WT_L0 + l * WT_LSZ + 131072 + c * 128 * 128; dld = 128; plane = 65536;
    } else if (t < 39) {                             // Wt2 [512][128] row-chunk c
        const int i = t - 27, l = i >> 2, c = i & 3;
        S = Wt2 + l * 65536 + c * 128 * 128; sld = 128;
        D = WT + WT_L0 + l * WT_LSZ + 262144 + c * 128; dld = 512; plane = 65536;
    } else {                                         // W_out [128][128]
        S = Wout; sld = 128;
        D = WT + WT_WO; dld = 128; plane = 16384;
    }
    const int tid = threadIdx.x;
    for (int id = tid; id < 2048; id += 256) {
        const int n = id >> 4, k0 = (id & 15) << 3;
        union { u16 s[8]; uint4 v; } hi, lo;
#pragma unroll
        for (int j = 0; j < 8; j++) {
            if constexpr (sizeof(TIN) == 2) {
                hi.s[j] = ((const u16*)(const void*)S)[(k0 + j) * sld + n];
                lo.s[j] = 0;
            } else {
                const float v = ((const float*)(const void*)S)[(k0 + j) * sld + n];
                const u16 hv = f2bf(v);
                hi.s[j] = hv;
                lo.s[j] = f2bf(v - bf2f(hv));
            }
        }
        *(uint4*)(D + n * dld + k0) = hi.v;
        if (SPLIT == 2) *(uint4*)(D + plane + n * dld + k0) = lo.v;
    }
}

// =====================================================================
// LDS weight-panel staging + swizzled access (shared by GEMM kernels).
// Panel = 128 n-rows x 128 k-cols u16 per plane (32 KB); hi then lo.
// XOR swizzle: byte ^= ((row&7)<<4), applied on BOTH write and read.
// 512 threads copy 8 KB per round; 4 rounds per plane.
// =====================================================================
template<int PLANES>
__device__ __forceinline__ void stage_panel(u16* lds, const u16* srcHi,
                                            const u16* srcLo, int strideU16,
                                            int tid)
{
#pragma unroll
    for (int i = 0; i < PLANES * 4; i++) {
        const int plane = i >> 2;
        const int off   = ((i & 3) << 13) | (tid << 4);   // byte within plane
        const int row   = off >> 8;
        const int colB  = off & 255;
        const u16* s = (plane ? srcLo : srcHi) + row * strideU16 + (colB >> 1);
        const uint4 v = *(const uint4*)s;
        *(uint4*)((char*)lds + plane * 32768 + (off ^ ((row & 7) << 4))) = v;
    }
}

__device__ __forceinline__ bf16x8 ld_w(const u16* lds, int plane, int row, int kbyte)
{
    union { uint4 q; bf16x8 v; } u;
    u.q = *(const uint4*)((const char*)lds + plane * 32768 + row * 256
                          + (kbyte ^ ((row & 7) << 4)));
    return u.v;
}

// MFMA over one staged panel: acc[2][8] += a{0,1}[kk] @ W(+lo)
template<int NS>
__device__ __forceinline__ void mfma_panel(const u16* Wbuf, const bf16x8* a0,
                                           const bf16x8* a1, int l15, int lg,
                                           f32x4 acc[][8])
{
#pragma unroll
    for (int kk = 0; kk < 4; kk++)
#pragma unroll
        for (int n = 0; n < 8; n++) {
            const int rw = n * 16 + l15, kb = kk * 64 + lg * 16;
            const bf16x8 b = ld_w(Wbuf, 0, rw, kb);
            acc[0][n] = __builtin_amdgcn_mfma_f32_16x16x32_bf16(a0[kk], b, acc[0][n], 0, 0, 0);
            acc[1][n] = __builtin_amdgcn_mfma_f32_16x16x32_bf16(a1[kk], b, acc[1][n], 0, 0, 0);
            if (NS == 2) {
                const bf16x8 bl = ld_w(Wbuf, 1, rw, kb);
                acc[0][n] = __builtin_amdgcn_mfma_f32_16x16x32_bf16(a0[kk], bl, acc[0][n], 0, 0, 0);
                acc[1][n] = __builtin_amdgcn_mfma_f32_16x16x32_bf16(a1[kk], bl, acc[1][n], 0, 0, 0);
            }
        }
}

// Split-A variant: acc += ah@W + al@W (+ ah@Wlo when NS==2)
template<int NS>
__device__ __forceinline__ void mfma_panel_split(const u16* Wbuf,
    const bf16x8* a0h, const bf16x8* a0l, const bf16x8* a1h, const bf16x8* a1l,
    int l15, int lg, f32x4 acc[][8])
{
#pragma unroll
    for (int kk = 0; kk < 4; kk++)
#pragma unroll
        for (int n = 0; n < 8; n++) {
            const int rw = n * 16 + l15, kb = kk * 64 + lg * 16;
            const bf16x8 b = ld_w(Wbuf, 0, rw, kb);
            acc[0][n] = __builtin_amdgcn_mfma_f32_16x16x32_bf16(a0h[kk], b, acc[0][n], 0, 0, 0);
            acc[0][n] = __builtin_amdgcn_mfma_f32_16x16x32_bf16(a0l[kk], b, acc[0][n], 0, 0, 0);
            acc[1][n] = __builtin_amdgcn_mfma_f32_16x16x32_bf16(a1h[kk], b, acc[1][n], 0, 0, 0);
            acc[1][n] = __builtin_amdgcn_mfma_f32_16x16x32_bf16(a1l[kk], b, acc[1][n], 0, 0, 0);
            if (NS == 2) {
                const bf16x8 bl = ld_w(Wbuf, 1, rw, kb);
                acc[0][n] = __builtin_amdgcn_mfma_f32_16x16x32_bf16(a0h[kk], bl, acc[0][n], 0, 0, 0);
                acc[1][n] = __builtin_amdgcn_mfma_f32_16x16x32_bf16(a1h[kk], bl, acc[1][n], 0, 0, 0);
            }
        }
}

__device__ __forceinline__ void splitf8(const float* p, bf16x8* hi, bf16x8* lo)
{
    const float4 f0 = *(const float4*)p;
    const float4 f1 = *(const float4*)(p + 4);
    const float f[8] = {f0.x, f0.y, f0.z, f0.w, f1.x, f1.y, f1.z, f1.w};
    union { u16 s[8]; bf16x8 v; } H, L;
#pragma unroll
    for (int j = 0; j < 8; j++) {
        const u16 hv = f2bf(f[j]);
        H.s[j] = hv;
        L.s[j] = f2bf(f[j] - bf2f(hv));
    }
    *hi = H.v; *lo = L.v;
}

// =====================================================================
// Staged-weight MFMA GEMM (bf16 A): C[M x 128] = A[M x K] @ W.
// 256-row blocks, 8 waves x 32 rows; weights LDS-staged per 128-K-chunk.
// =====================================================================
template<int NS, int KCH, bool OUT_BF16, bool ADD>
__global__ __launch_bounds__(512, 2) void sgemm_bf(
    const int* __restrict__ flag, int want,
    const u16* __restrict__ A, int lda,
    const u16* __restrict__ WHi, const u16* __restrict__ WLo,
    int wstride, int wcstep,
    void* __restrict__ Cv, int ldc)
{
    if (*flag != want) return;
    __shared__ __align__(16) u16 Wbuf[NS * 16384];
    const int tid = threadIdx.x;
    const int lane = tid & 63, wv = tid >> 6;
    const int l15 = lane & 15, lg = lane >> 4;
    const long long row0 = (long long)blockIdx.x * 256 + wv * 32;

    f32x4 acc[2][8];
    {
        f32x4 z = {0.f, 0.f, 0.f, 0.f};
#pragma unroll
        for (int m = 0; m < 2; m++)
#pragma unroll
            for (int n = 0; n < 8; n++) acc[m][n] = z;
    }

    const u16* A0 = A + (row0 + l15) * (long long)lda + lg * 8;
    const u16* A1 = A0 + 16LL * lda;

    for (int ks = 0; ks < KCH; ks++) {
        if (ks) __syncthreads();   // prior chunk's LDS reads done
        stage_panel<NS>(Wbuf, WHi + ks * wcstep, WLo + ks * wcstep, wstride, tid);
        bf16x8 a0[4], a1[4];
#pragma unroll
        for (int kk = 0; kk < 4; kk++) {
            a0[kk] = *(const bf16x8*)(A0 + ks * 128 + kk * 32);
            a1[kk] = *(const bf16x8*)(A1 + ks * 128 + kk * 32);
        }
        __syncthreads();           // panel staged
        mfma_panel<NS>(Wbuf, a0, a1, l15, lg, acc);
    }

#pragma unroll
    for (int m = 0; m < 2; m++)
#pragma unroll
        for (int r = 0; r < 4; r++) {
            const long long row = row0 + m * 16 + lg * 4 + r;
            if (OUT_BF16) {
                u16* C = (u16*)Cv + row * ldc;
#pragma unroll
                for (int n = 0; n < 8; n++) C[n * 16 + l15] = f2bf(acc[m][n][r]);
            } else {
                float* C = (float*)Cv + row * ldc;
#pragma unroll
                for (int n = 0; n < 8; n++) {
                    float v = acc[m][n][r];
                    if (ADD) v += C[n * 16 + l15];
                    C[n * 16 + l15] = v;
                }
            }
        }
}

// =====================================================================
// Staged-weight MFMA GEMM (f32 A, split in-kernel into hi+lo bf16).
// =====================================================================
template<int NS, int KCH, bool OUT_BF16, bool ADD>
__global__ __launch_bounds__(512, 2) void sgemm_f32(
    const int* __restrict__ flag, int want,
    const float* __restrict__ A, int lda,
    const u16* __restrict__ WHi, const u16* __restrict__ WLo,
    int wstride, int wcstep,
    void* __restrict__ Cv, int ldc)
{
    if (*flag != want) return;
    __shared__ __align__(16) u16 Wbuf[NS * 16384];
    const int tid = threadIdx.x;
    const int lane = tid & 63, wv = tid >> 6;
    const int l15 = lane & 15, lg = lane >> 4;
    const long long row0 = (long long)blockIdx.x * 256 + wv * 32;

    f32x4 acc[2][8];
    {
        f32x4 z = {0.f, 0.f, 0.f, 0.f};
#pragma unroll
        for (int m = 0; m < 2; m++)
#pragma unroll
            for (int n = 0; n < 8; n++) acc[m][n] = z;
    }

    const float* A0 = A + (row0 + l15) * (long long)lda + lg * 8;
    const float* A1 = A0 + 16LL * lda;

    for (int ks = 0; ks < KCH; ks++) {
        if (ks) __syncthreads();
        stage_panel<NS>(Wbuf, WHi + ks * wcstep, WLo + ks * wcstep, wstride, tid);
        bf16x8 a0h[4], a0l[4], a1h[4], a1l[4];
#pragma unroll
        for (int kk = 0; kk < 4; kk++) {
            splitf8(A0 + ks * 128 + kk * 32, &a0h[kk], &a0l[kk]);
            splitf8(A1 + ks * 128 + kk * 32, &a1h[kk], &a1l[kk]);
        }
        __syncthreads();
        mfma_panel_split<NS>(Wbuf, a0h, a0l, a1h, a1l, l15, lg, acc);
    }

#pragma unroll
    for (int m = 0; m < 2; m++)
#pragma unroll
        for (int r = 0; r < 4; r++) {
            const long long row = row0 + m * 16 + lg * 4 + r;
            if (OUT_BF16) {
                u16* C = (u16*)Cv + row * ldc;
#pragma unroll
                for (int n = 0; n < 8; n++) C[n * 16 + l15] = f2bf(acc[m][n][r]);
            } else {
                float* C = (float*)Cv + row * ldc;
#pragma unroll
                for (int n = 0; n < 8; n++) {
                    float v = acc[m][n][r];
                    if (ADD) v += C[n * 16 + l15];
                    C[n * 16 + l15] = v;
                }
            }
        }
}

// =====================================================================
// Fused QKV: A (=h) loaded once; Wq, Wk, Wv staged sequentially.
// =====================================================================
template<int NS>
__global__ __launch_bounds__(512, 2) void qkv_fused(
    const int* __restrict__ flag, int want,
    const u16* __restrict__ h, const u16* __restrict__ wl,
    u16* __restrict__ qb, u16* __restrict__ kb, u16* __restrict__ vb)
{
    if (*flag != want) return;
    __shared__ __align__(16) u16 Wbuf[NS * 16384];
    const int tid = threadIdx.x;
    const int lane = tid & 63, wv = tid >> 6;
    const int l15 = lane & 15, lg = lane >> 4;
    const long long row0 = (long long)blockIdx.x * 256 + wv * 32;

    bf16x8 a0[4], a1[4];
#pragma unroll
    for (int kk = 0; kk < 4; kk++) {
        a0[kk] = *(const bf16x8*)(h + (row0 + l15) * 128 + kk * 32 + lg * 8);
        a1[kk] = *(const bf16x8*)(h + (row0 + 16 + l15) * 128 + kk * 32 + lg * 8);
    }

    for (int m = 0; m < 3; m++) {
        if (m) __syncthreads();    // prior panel's reads done (also drains stores)
        stage_panel<NS>(Wbuf, wl + m * 32768, wl + m * 32768 + 16384, 128, tid);
        __syncthreads();
        f32x4 acc[2][8];
        {
            f32x4 z = {0.f, 0.f, 0.f, 0.f};
#pragma unroll
            for (int i = 0; i < 2; i++)
#pragma unroll
                for (int n = 0; n < 8; n++) acc[i][n] = z;
        }
        mfma_panel<NS>(Wbuf, a0, a1, l15, lg, acc);
        u16* out = (m == 0) ? qb : (m == 1) ? kb : vb;
#pragma unroll
        for (int i = 0; i < 2; i++)
#pragma unroll
            for (int r = 0; r < 4; r++) {
                u16* C = out + (row0 + i * 16 + lg * 4 + r) * CA;
#pragma unroll
                for (int n = 0; n < 8; n++) C[n * 16 + l15] = f2bf(acc[i][n][r]);
            }
    }
}

// =====================================================================
// Fused MLP v3: x += relu(h @ Wt1) @ Wt2.  Per chunk c:
//   stage W1c -> MFMA -> barrier -> stage W2c (same buffer) + hidden->Pl
//   -> barrier -> MFMA.  Hidden transposed via swizzled per-wave Pl.
// LDS: 64 KB Wbuf + 64 KB Pl = 128 KB.
// =====================================================================
template<int NS>
__global__ __launch_bounds__(512, 2) void mlp_fused(
    const int* __restrict__ flag, int want,
    const u16* __restrict__ h,
    const u16* __restrict__ W1T, const u16* __restrict__ W2T,
    float* __restrict__ x)
{
    if (*flag != want) return;
    __shared__ __align__(16) u16 Wbuf[NS * 16384];
    __shared__ __align__(16) u16 Pl[8 * 4096];     // per-wave 32 rows x 256 B
    const int tid = threadIdx.x;
    const int lane = tid & 63, wv = tid >> 6;
    const int l15 = lane & 15, lg = lane >> 4;
    const long long row0 = (long long)blockIdx.x * 256 + wv * 32;
    char* pw = (char*)(Pl + wv * 4096);

    bf16x8 ah0[4], ah1[4];
#pragma unroll
    for (int kk = 0; kk < 4; kk++) {
        ah0[kk] = *(const bf16x8*)(h + (row0 + l15) * 128 + kk * 32 + lg * 8);
        ah1[kk] = *(const bf16x8*)(h + (row0 + 16 + l15) * 128 + kk * 32 + lg * 8);
    }

    f32x4 xacc[2][8];
    {
        f32x4 z = {0.f, 0.f, 0.f, 0.f};
#pragma unroll
        for (int m = 0; m < 2; m++)
#pragma unroll
            for (int n = 0; n < 8; n++) xacc[m][n] = z;
    }

    for (int c = 0; c < 4; c++) {
        if (c) __syncthreads();    // prior chunk's W2 + Pl reads done
        stage_panel<NS>(Wbuf, W1T + c * 16384, W1T + 65536 + c * 16384, 128, tid);
        __syncthreads();           // W1c staged
        f32x4 hacc[2][8];
        {
            f32x4 z = {0.f, 0.f, 0.f, 0.f};
#pragma unroll
            for (int m = 0; m < 2; m++)
#pragma unroll
                for (int n = 0; n < 8; n++) hacc[m][n] = z;
        }
        mfma_panel<NS>(Wbuf, ah0, ah1, l15, lg, hacc);
        __syncthreads();           // all waves done reading W1c
        stage_panel<NS>(Wbuf, W2T + c * 128, W2T + 65536 + c * 128, 512, tid);
        // relu + bf16 hidden -> own Pl region (swizzled, row=out-row, col=hidden)
#pragma unroll
        for (int m = 0; m < 2; m++)
#pragma unroll
            for (int n = 0; n < 8; n++)
#pragma unroll
                for (int r = 0; r < 4; r++) {
                    const int row = m * 16 + lg * 4 + r;
                    const int cb  = (n * 32 + l15 * 2) ^ ((row & 7) << 4);
                    *(u16*)(pw + row * 256 + cb) = f2bf(fmaxf(hacc[m][n][r], 0.f));
                }
        __syncthreads();           // W2c staged; Pl writes drained
        bf16x8 a20[4], a21[4];
#pragma unroll
        for (int kk = 0; kk < 4; kk++) {
            const int kb = (kk * 64 + lg * 16) ^ ((l15 & 7) << 4);
            a20[kk] = *(const bf16x8*)(pw + l15 * 256 + kb);
            a21[kk] = *(const bf16x8*)(pw + (l15 + 16) * 256 + kb);
        }
        mfma_panel<NS>(Wbuf, a20, a21, l15, lg, xacc);
    }

#pragma unroll
    for (int m = 0; m < 2; m++)
#pragma unroll
        for (int r = 0; r < 4; r++) {
            float* X = x + (row0 + m * 16 + lg * 4 + r) * 128;
#pragma unroll
            for (int n = 0; n < 8; n++) X[n * 16 + l15] += xacc[m][n][r];
        }
}

// =====================================================================
// Gather: x[b,n,:] = a_tok[b, idx[b,n], :]   (f32 -> f32)
// =====================================================================
__global__ __launch_bounds__(256) void gather_kernel(
    const int* __restrict__ flag, int want,
    const float* __restrict__ a_tok, const int* __restrict__ idx,
    float* __restrict__ x)
{
    if (*flag != want) return;
    const size_t i = (size_t)blockIdx.x * 256 + threadIdx.x;  // B*N*128 total
    const int c = (int)(i & 127);
    const size_t an = i >> 7;
    const int b = (int)(an >> 14);
    const int n = (int)(an & (NATOM - 1));
    const int t = idx[b * NATOM + n];
    x[i] = a_tok[(((size_t)b * NTOK) + t) * CA + c];
}

// =====================================================================
// LayerNorm: h = (x-m)*rsqrt(var+1e-5)*g + b   (f32 in, bf16 out)
// =====================================================================
template<typename TW>
__global__ __launch_bounds__(256) void ln_kernel(
    const int* __restrict__ flag, int want,
    const float* __restrict__ x, const TW* __restrict__ g,
    const TW* __restrict__ b, u16* __restrict__ h)
{
    if (*flag != want) return;
    const int lane = threadIdx.x & 63;
    const int wv   = threadIdx.x >> 6;
    const size_t atom = (size_t)blockIdx.x * 4 + wv;
    const float* xr = x + atom * CA;
    const float v0 = xr[lane], v1 = xr[lane + 64];
    float s  = v0 + v1;
    float sq = v0 * v0 + v1 * v1;
#pragma unroll
    for (int off = 32; off > 0; off >>= 1) {
        s  += __shfl_xor(s,  off, 64);
        sq += __shfl_xor(sq, off, 64);
    }
    const float mean = s * 0.0078125f;
    const float var  = sq * 0.0078125f - mean * mean;
    const float inv  = rsqrtf(var + 1e-5f);
    u16* hr = h + atom * CA;
    hr[lane]      = f2bf((v0 - mean) * inv * ld1(g + lane)      + ld1(b + lane));
    hr[lane + 64] = f2bf((v1 - mean) * inv * ld1(g + lane + 64) + ld1(b + lane + 64));
}

// =====================================================================
// Bias: t[b,a,h] for a < 128 from the pair-MLP; single block, 512 threads
// =====================================================================
template<typename TW>
__global__ __launch_bounds__(512) void bias_kernel(
    const int* __restrict__ flag, int want,
    const float* __restrict__ x,
    const TW* __restrict__ Wcl, const TW* __restrict__ Wcm,
    const TW* __restrict__ Wm1, const TW* __restrict__ Wm2,
    const TW* __restrict__ Wpb, float* __restrict__ tb)
{
    if (*flag != want) return;
    __shared__ float Wsum[128][16];
    __shared__ float M1[16][16];
    __shared__ float M2[16][16];
    __shared__ float Pb[16][4];
    const int tid = threadIdx.x;
    for (int i = tid; i < 128 * 16; i += 512)
        Wsum[i >> 4][i & 15] = ld1(Wcl + i) + ld1(Wcm + i);
    if (tid < 256) M1[tid >> 4][tid & 15] = ld1(Wm1 + tid);
    if (tid >= 256 && tid < 512) { int t2 = tid - 256; M2[t2 >> 4][t2 & 15] = ld1(Wm2 + t2); }
    if (tid < 64) Pb[tid >> 2][tid & 3] = ld1(Wpb + tid);
    __syncthreads();

    const int b = tid >> 7, a = tid & 127;
    const float* xa = x + ((size_t)b * NATOM + a) * CA;
    float u[16];
#pragma unroll
    for (int p = 0; p < 16; p++) u[p] = 0.f;
    for (int c = 0; c < 128; c++) {
        const float xv = xa[c];
#pragma unroll
        for (int p = 0; p < 16; p++) u[p] = fmaf(xv, Wsum[c][p], u[p]);
    }
    float r1[16];
#pragma unroll
    for (int p = 0; p < 16; p++) r1[p] = 0.f;
    for (int c = 0; c < 16; c++) {
        const float rv = fmaxf(u[c], 0.f);
#pragma unroll
        for (int p = 0; p < 16; p++) r1[p] = fmaf(rv, M1[c][p], r1[p]);
    }
    float r2[16];
#pragma unroll
    for (int p = 0; p < 16; p++) r2[p] = 0.f;
    for (int c = 0; c < 16; c++) {
        const float rv = fmaxf(r1[c], 0.f);
#pragma unroll
        for (int p = 0; p < 16; p++) r2[p] = fmaf(rv, M2[c][p], r2[p]);
    }
#pragma unroll
    for (int hh = 0; hh < 4; hh++) {
        float s = 0.f;
#pragma unroll
        for (int p = 0; p < 16; p++) s = fmaf(r2[p], Pb[p][hh], s);
        tb[(size_t)tid * 4 + hh] = s;
    }
}

// =====================================================================
// Windowed attention via MFMA (verified round 1): one block per (b, w).
// =====================================================================
#define VTP 132   // V^T row stride in u16
#define PPS 68    // P row stride in u16

__global__ __launch_bounds__(256) void attn_kernel(
    const int* __restrict__ flag, int want,
    const u16* __restrict__ qg, const u16* __restrict__ kg,
    const u16* __restrict__ vg, const float* __restrict__ tb,
    u16* __restrict__ og)
{
    if (*flag != want) return;
    __shared__ __align__(16) u16 VT[128][VTP];    // V^T: [d][j]
    __shared__ __align__(16) u16 Pl[NH][32][PPS]; // per-head P half

    const int tid  = threadIdx.x;
    const int lane = tid & 63;
    const int h    = tid >> 6;             // wave id == head
    const int b    = blockIdx.x >> 9;
    const int w    = blockIdx.x & (NWIN - 1);
    const int row0 = w * NQ;
    const int kbase = row0 - PAD;          // first key atom (may be < 0)
    const int l15 = lane & 15;
    const int lg  = lane >> 4;

    // ---- stage V^T into LDS (all 256 threads; zero invalid rows) ----
    {
        const int j  = tid & 127;
        const int d0 = (tid >> 7) << 6;    // 0 or 64
        const int ga = kbase + j;
        const bool val = (ga >= 0) && (ga < NATOM);
        const u16* vrow = vg + ((long long)b * NATOM + ga) * CA + d0;
#pragma unroll
        for (int t2 = 0; t2 < 8; t2++) {
            union { uint4 q; u16 s[8]; } u;
            if (val) u.q = *(const uint4*)(vrow + t2 * 8);
            else     u.q = make_uint4(0u, 0u, 0u, 0u);
#pragma unroll
            for (int e = 0; e < 8; e++) VT[d0 + t2 * 8 + e][j] = u.s[e];
        }
    }

    // ---- QK^T: S[32][128] per head, frags direct from global ----
    const long long qoff = ((long long)b * NATOM + row0) * CA + h * DH;
    const long long koff = ((long long)b * NATOM + kbase) * CA + h * DH;
    bf16x8 aq0 = *(const bf16x8*)(qg + qoff + (long long)l15 * CA + lg * 8);
    bf16x8 aq1 = *(const bf16x8*)(qg + qoff + (long long)(l15 + 16) * CA + lg * 8);

    f32x4 acc[2][8];
    {
        f32x4 z = {0.f, 0.f, 0.f, 0.f};
#pragma unroll
        for (int m = 0; m < 2; m++)
#pragma unroll
            for (int n = 0; n < 8; n++) acc[m][n] = z;
    }
#pragma unroll
    for (int n = 0; n < 8; n++) {
        bf16x8 bk = *(const bf16x8*)(kg + koff + (long long)(n * 16 + l15) * CA + lg * 8);
        acc[0][n] = __builtin_amdgcn_mfma_f32_16x16x32_bf16(aq0, bk, acc[0][n], 0, 0, 0);
        acc[1][n] = __builtin_amdgcn_mfma_f32_16x16x32_bf16(aq1, bk, acc[1][n], 0, 0, 0);
    }

    // ---- bias + scale + mask ----
    const float scale = 0.17677669529663687f;  // 1/sqrt(32)
    float tj[8], ti[2][4];
#pragma unroll
    for (int n = 0; n < 8; n++)
        tj[n] = tb[((size_t)b * 128 + n * 16 + l15) * 4 + h];
#pragma unroll
    for (int m = 0; m < 2; m++)
#pragma unroll
        for (int r = 0; r < 4; r++)
            ti[m][r] = tb[((size_t)b * 128 + m * 16 + lg * 4 + r) * 4 + h];

#pragma unroll
    for (int n = 0; n < 8; n++) {
        const int ga = kbase + n * 16 + l15;
        const bool val = (ga >= 0) && (ga < NATOM);
#pragma unroll
        for (int m = 0; m < 2; m++)
#pragma unroll
            for (int r = 0; r < 4; r++) {
                const float s = acc[m][n][r] * scale + ti[m][r] + tj[n];
                acc[m][n][r] = val ? s : -1e9f;
            }
    }

    // ---- softmax ----
    float mx[2][4], inv[2][4];
#pragma unroll
    for (int m = 0; m < 2; m++)
#pragma unroll
        for (int r = 0; r < 4; r++) {
            float v = acc[m][0][r];
#pragma unroll
            for (int n = 1; n < 8; n++) v = fmaxf(v, acc[m][n][r]);
            v = fmaxf(v, __shfl_xor(v, 1, 64));
            v = fmaxf(v, __shfl_xor(v, 2, 64));
            v = fmaxf(v, __shfl_xor(v, 4, 64));
            v = fmaxf(v, __shfl_xor(v, 8, 64));
            mx[m][r] = v;
        }
#pragma unroll
    for (int m = 0; m < 2; m++)
#pragma unroll
        for (int n = 0; n < 8; n++)
#pragma unroll
            for (int r = 0; r < 4; r++)
                acc[m][n][r] = __expf(acc[m][n][r] - mx[m][r]);
#pragma unroll
    for (int m = 0; m < 2; m++)
#pragma unroll
        for (int r = 0; r < 4; r++) {
            float v = 0.f;
#pragma unroll
            for (int n = 0; n < 8; n++) v += acc[m][n][r];
            v += __shfl_xor(v, 1, 64);
            v += __shfl_xor(v, 2, 64);
            v += __shfl_xor(v, 4, 64);
            v += __shfl_xor(v, 8, 64);
            inv[m][r] = 1.0f / v;
        }

    __syncthreads();   // V^T staged

    // ---- PV ----
    f32x4 o[2][2];
    {
        f32x4 z = {0.f, 0.f, 0.f, 0.f};
        o[0][0] = z; o[0][1] = z; o[1][0] = z; o[1][1] = z;
    }
    union B8 { bf16x8 v; uint2 u[2]; };
#pragma unroll
    for (int half = 0; half < 2; half++) {
        asm volatile("s_waitcnt lgkmcnt(0)" ::: "memory");
#pragma unroll
        for (int m = 0; m < 2; m++)
#pragma unroll
            for (int nn = 0; nn < 4; nn++)
#pragma unroll
                for (int r = 0; r < 4; r++)
                    Pl[h][m * 16 + lg * 4 + r][nn * 16 + l15]
                        = f2bf(acc[m][half * 4 + nn][r]);
        asm volatile("s_waitcnt lgkmcnt(0)" ::: "memory");
#pragma unroll
        for (int ks2 = 0; ks2 < 2; ks2++) {
            const int jo = ks2 * 32 + lg * 8;
            const int jg = half * 64 + jo;
            B8 pa0, pa1, vb0, vb1;
            pa0.u[0] = *(const uint2*)&Pl[h][l15][jo];
            pa0.u[1] = *(const uint2*)&Pl[h][l15][jo + 4];
            pa1.u[0] = *(const uint2*)&Pl[h][l15 + 16][jo];
            pa1.u[1] = *(const uint2*)&Pl[h][l15 + 16][jo + 4];
            vb0.u[0] = *(const uint2*)&VT[h * DH + l15][jg];
            vb0.u[1] = *(const uint2*)&VT[h * DH + l15][jg + 4];
            vb1.u[0] = *(const uint2*)&VT[h * DH + 16 + l15][jg];
            vb1.u[1] = *(const uint2*)&VT[h * DH + 16 + l15][jg + 4];
            o[0][0] = __builtin_amdgcn_mfma_f32_16x16x32_bf16(pa0.v, vb0.v, o[0][0], 0, 0, 0);
            o[0][1] = __builtin_amdgcn_mfma_f32_16x16x32_bf16(pa0.v, vb1.v, o[0][1], 0, 0, 0);
            o[1][0] = __builtin_amdgcn_mfma_f32_16x16x32_bf16(pa1.v, vb0.v, o[1][0], 0, 0, 0);
            o[1][1] = __builtin_amdgcn_mfma_f32_16x16x32_bf16(pa1.v, vb1.v, o[1][1], 0, 0, 0);
        }
    }

#pragma unroll
    for (int m = 0; m < 2; m++)
#pragma unroll
        for (int n = 0; n < 2; n++)
#pragma unroll
            for (int r = 0; r < 4; r++)
                og[((long long)b * NATOM + row0 + m * 16 + lg * 4 + r) * CA
                   + h * DH + n * 16 + l15]
                    = f2bf(o[m][n][r] * inv[m][r]);
}

// =====================================================================
// Final selector: write d_out as bf16 (flag=1) or f32 (flag=0)
// =====================================================================
__global__ __launch_bounds__(256) void select_kernel(
    const int* __restrict__ flag,
    const u16* __restrict__ outA, const u16* __restrict__ outB,
    void* __restrict__ d_out)
{
    const size_t i = (size_t)blockIdx.x * 256 + threadIdx.x;
    if (*flag) ((u16*)d_out)[i]   = outA[i];
    else       ((float*)d_out)[i] = bf2f(outB[i]);
}

// =====================================================================
// One full pipeline pass, templated on input storage type, gated on flag
// =====================================================================
template<typename TIN>
static void run_pass(void* const* d_in,
                     float* x, u16* h, u16* qb, u16* kb, u16* vb, u16* ob,
                     float* atok, u16* wt, float* tbv, u16* outbuf,
                     const int* flag, int want, hipStream_t stream)
{
    constexpr int NS = (sizeof(TIN) == 2) ? 1 : 2;

    const TIN* a    = (const TIN*)d_in[0];
    const int* idx  = (const int*)d_in[2];
    const TIN* W_a  = (const TIN*)d_in[3];
    const TIN* W_o  = (const TIN*)d_in[4];
    const TIN* Wcl  = (const TIN*)d_in[5];
    const TIN* Wcm  = (const TIN*)d_in[6];
    const TIN* Wm1  = (const TIN*)d_in[7];
    const TIN* Wm2  = (const TIN*)d_in[8];
    const TIN* Wpb  = (const TIN*)d_in[9];
    const TIN* Wq   = (const TIN*)d_in[10];
    const TIN* Wk   = (const TIN*)d_in[11];
    const TIN* Wv   = (const TIN*)d_in[12];
    const TIN* Wo   = (const TIN*)d_in[13];
    const TIN* ln1g = (const TIN*)d_in[14];
    const TIN* ln1b = (const TIN*)d_in[15];
    const TIN* Wt1  = (const TIN*)d_in[16];
    const TIN* Wt2  = (const TIN*)d_in[17];
    const TIN* ln2g = (const TIN*)d_in[18];
    const TIN* ln2b = (const TIN*)d_in[19];

    const size_t NEL = (size_t)BB * NATOM * CA;

    // 0) transpose (+split) all weights into WT workspace
    wtrans_kernel<TIN, NS><<<40, 256, 0, stream>>>(
        flag, want, W_a, Wq, Wk, Wv, Wo, Wt1, Wt2, W_o, wt);

    // 1) token projection [8192 x 384] @ [384 x 128] -> f32 atok
    if constexpr (NS == 1)
        sgemm_bf<1, 3, false, false><<<BB * NTOK / 256, 512, 0, stream>>>(
            flag, want, (const u16*)a, CTOK, wt + WT_WA, wt + WT_WA + 49152,
            CTOK, 128, atok, CA);
    else
        sgemm_f32<2, 3, false, false><<<BB * NTOK / 256, 512, 0, stream>>>(
            flag, want, (const float*)a, CTOK, wt + WT_WA, wt + WT_WA + 49152,
            CTOK, 128, atok, CA);

    gather_kernel<<<(unsigned)(NEL / 256), 256, 0, stream>>>(flag, want, atok, idx, x);
    bias_kernel<TIN><<<1, 512, 0, stream>>>(flag, want, x, Wcl, Wcm, Wm1, Wm2, Wpb, tbv);

    for (int l = 0; l < 3; l++) {
        u16* wl = wt + WT_L0 + (size_t)l * WT_LSZ;
        ln_kernel<TIN><<<BB * NATOM / 4, 256, 0, stream>>>(flag, want, x, ln1g + l * CA, ln1b + l * CA, h);
        qkv_fused<NS><<<256, 512, 0, stream>>>(flag, want, h, wl, qb, kb, vb);
        attn_kernel<<<BB * NWIN, 256, 0, stream>>>(flag, want, qb, kb, vb, tbv, ob);
        sgemm_bf<NS, 1, false, true><<<256, 512, 0, stream>>>(
            flag, want, ob, CA, wl + 98304, wl + 98304 + 16384, CA, 0, x, CA);
        ln_kernel<TIN><<<BB * NATOM / 4, 256, 0, stream>>>(flag, want, x, ln2g + l * CA, ln2b + l * CA, h);
        mlp_fused<NS><<<256, 512, 0, stream>>>(flag, want, h, wl + 131072, wl + 262144, x);
    }
    // out = x @ W_out -> bf16 outbuf (A is f32 residual: in-kernel split)
    sgemm_f32<NS, 1, true, false><<<256, 512, 0, stream>>>(
        flag, want, x, CA, wt + WT_WO, wt + WT_WO + 16384, CA, 0, outbuf, CA);
}

// =====================================================================
// Launch
// =====================================================================
extern "C" void kernel_launch(void* const* d_in, const int* in_sizes, int n_in,
                              void* d_out, int out_size, void* d_ws, size_t ws_size,
                              hipStream_t stream)
{
    (void)in_sizes; (void)n_in; (void)out_size;
    const size_t NEL = (size_t)BB * NATOM * CA;   // 8388608

    char* p = (char*)d_ws;
    float* x    = (float*)p;  p += NEL * 4;
    u16*   h    = (u16*)p;    p += NEL * 2;
    u16*   qb   = (u16*)p;    p += NEL * 2;
    u16*   kb   = (u16*)p;    p += NEL * 2;
    u16*   vb   = (u16*)p;    p += NEL * 2;
    u16*   ob   = (u16*)p;    p += NEL * 2;
    float* atok = (float*)p;  p += (size_t)BB * NTOK * CA * 4;
    float* tbv  = (float*)p;  p += 8192;
    u16*   outA = (u16*)p;    p += NEL * 2;
    u16*   outB = (u16*)p;    p += NEL * 2;
    int*   flag = (int*)p;    p += 256;
    u16*   wt   = (u16*)p;    p += (size_t)WT_TOT * 2;
    if ((size_t)(p - (char*)d_ws) > ws_size) return;  // workspace too small

    // 1) detect input storage dtype (writes flag: 1=bf16, 0=f32)
    detect_kernel<<<1, 256, 0, stream>>>((const u32*)d_in[3], flag);
    // 2) bf16-interpretation pass (runs only if flag==1)
    run_pass<u16>(d_in, x, h, qb, kb, vb, ob, atok, wt, tbv, outA, flag, 1, stream);
    // 3) f32-interpretation pass (runs only if flag==0)
    run_pass<float>(d_in, x, h, qb, kb, vb, ob, atok, wt, tbv, outB, flag, 0, stream);
    // 4) write d_out in the detected output format
    select_kernel<<<(unsigned)(NEL / 256), 256, 0, stream>>>(flag, outA, outB, d_out);
}

// Round 6
// 777.719 us; speedup vs baseline: 2.1480x; 1.0133x over previous
//
#include <hip/hip_runtime.h>

typedef unsigned short u16;
typedef unsigned int   u32;

typedef __attribute__((ext_vector_type(8))) __bf16 bf16x8;
typedef __attribute__((ext_vector_type(4))) float  f32x4;

// ---------- scalar/vec conversion helpers ----------
__device__ __forceinline__ float bf2f(u16 v) {
    return __uint_as_float(((u32)v) << 16);
}
__device__ __forceinline__ u16 f2bf(float f) {
    u32 u = __float_as_uint(f);
    u32 r = (u + 0x7fffu + ((u >> 16) & 1u)) >> 16;  // round-to-nearest-even
    return (u16)r;
}
__device__ __forceinline__ float ld1(const u16* p)   { return bf2f(*p); }
__device__ __forceinline__ float ld1(const float* p) { return *p; }

// ---------- problem constants ----------
#define BB 4
#define NTOK 2048
#define NATOM 16384
#define CTOK 384
#define CA 128
#define NQ 32
#define NK 128
#define NH 4
#define DH 32
#define NWIN 512
#define PAD 48

// Transposed-weight workspace layout (u16 elements).
// Each matrix stored as [N][K] hi-plane, then lo-plane (f32 path only).
#define WT_WA   0          // [128][384], lo plane at +49152
#define WT_L0   98304      // per-layer block start
#define WT_LSZ  393216     // Q 0 | K 32768 | V 65536 | O 98304 | T1 131072 | T2 262144
#define WT_WO   1277952    // [128][128], lo plane at +16384
#define WT_TOT  1310720

// =====================================================================
// dtype detector: look at low u16 of 1024 words of W_a.
// flag = 1 (bf16 inputs) or 0 (f32 inputs)
// =====================================================================
__global__ __launch_bounds__(256) void detect_kernel(const u32* __restrict__ wa,
                                                     int* __restrict__ flag)
{
    __shared__ int cnt;
    if (threadIdx.x == 0) cnt = 0;
    __syncthreads();
    int local = 0;
#pragma unroll
    for (int i = 0; i < 4; i++) {
        u32 w = wa[threadIdx.x * 4 + i];
        u32 e = (w >> 7) & 0xFFu;   // exponent field of the LOW u16 as bf16
        if (e >= 95u && e <= 135u) local++;
    }
    atomicAdd(&cnt, local);
    __syncthreads();
    if (threadIdx.x == 0) *flag = (cnt >= 614) ? 1 : 0;
}

// =====================================================================
// Weight transpose (+ bf16 split for f32 inputs) into WT workspace.
// 40 tiles of 128x128: Wa(3) | Wq/k/v/o x3 (12) | Wt1 (12) | Wt2 (12) | Wout(1)
// dst[n][k] = src[k][n]; f32 path: hi = bf16(w), lo = bf16(w - hi).
// =====================================================================
template<typename TIN, int SPLIT>
__global__ __launch_bounds__(256) void wtrans_kernel(
    const int* __restrict__ flag, int want,
    const TIN* __restrict__ Wa, const TIN* __restrict__ Wq,
    const TIN* __restrict__ Wk, const TIN* __restrict__ Wv,
    const TIN* __restrict__ Wo, const TIN* __restrict__ Wt1,
    const TIN* __restrict__ Wt2, const TIN* __restrict__ Wout,
    u16* __restrict__ WT)
{
    if (*flag != want) return;
    const int t = blockIdx.x;
    const TIN* S; int sld; u16* D; int dld; int plane;
    if (t < 3) {                                     // W_a [384][128]
        S = Wa + t * 128 * 128; sld = 128;
        D = WT + WT_WA + t * 128; dld = 384; plane = 49152;
    } else if (t < 15) {                             // Wq/k/v/o [128][128]
        const int i = t - 3, l = i >> 2, m = i & 3;
        const TIN* ms = (m == 0) ? Wq : (m == 1) ? Wk : (m == 2) ? Wv : Wo;
        S = ms + l * 16384; sld = 128;
        D = WT + WT_L0 + l * WT_LSZ + m * 32768; dld = 128; plane = 16384;
    } else if (t < 27) {                             // Wt1 [128][512] col-chunk c
        const int i = t - 15, l = i >> 2, c = i & 3;
        S = Wt1 + l * 65536 + c * 128; sld = 512;
        D = WT + WT_L0 + l * WT_LSZ + 131072 + c * 128 * 128; dld = 128; plane = 65536;
    } else if (t < 39) {                             // Wt2 [512][128] row-chunk c
        const int i = t - 27, l = i >> 2, c = i & 3;
        S = Wt2 + l * 65536 + c * 128 * 128; sld = 128;
        D = WT + WT_L0 + l * WT_LSZ + 262144 + c * 128; dld = 512; plane = 65536;
    } else {                                         // W_out [128][128]
        S = Wout; sld = 128;
        D = WT + WT_WO; dld = 128; plane = 16384;
    }
    const int tid = threadIdx.x;
    for (int id = tid; id < 2048; id += 256) {
        const int n = id >> 4, k0 = (id & 15) << 3;
        union { u16 s[8]; uint4 v; } hi, lo;
#pragma unroll
        for (int j = 0; j < 8; j++) {
            if constexpr (sizeof(TIN) == 2) {
                hi.s[j] = ((const u16*)(const void*)S)[(k0 + j) * sld + n];
                lo.s[j] = 0;
            } else {
                const float v = ((const float*)(const void*)S)[(k0 + j) * sld + n];
                const u16 hv = f2bf(v);
                hi.s[j] = hv;
                lo.s[j] = f2bf(v - bf2f(hv));
            }
        }
        *(uint4*)(D + n * dld + k0) = hi.v;
        if (SPLIT == 2) *(uint4*)(D + plane + n * dld + k0) = lo.v;
    }
}

// =====================================================================
// LDS weight-panel staging, split into load(global->reg) / store(reg->LDS)
// so the global latency hides under MFMA (T14 async-STAGE split).
// Panel = 128 n-rows x 128 k-cols u16 per plane (32 KB); hi then lo.
// XOR swizzle: byte ^= ((row&7)<<4), applied on BOTH write and read.
// =====================================================================
template<int NS, int NTHR>
struct SReg { uint4 v[NS * 32768 / (NTHR * 16)]; };

template<int NS, int NTHR>
__device__ __forceinline__ void stage_load(SReg<NS, NTHR>& R, const u16* srcHi,
                                           const u16* srcLo, int strideU16, int tid)
{
    constexpr int ROUNDS = NS * 32768 / (NTHR * 16);
#pragma unroll
    for (int i = 0; i < ROUNDS; i++) {
        const int off   = i * NTHR * 16 + tid * 16;   // byte offset in image
        const int plane = off >> 15;
        const int po    = off & 32767;
        const int row   = po >> 8;
        const int colB  = po & 255;
        const u16* s = (plane ? srcLo : srcHi) + row * strideU16 + (colB >> 1);
        R.v[i] = *(const uint4*)s;
    }
}

template<int NS, int NTHR>
__device__ __forceinline__ void stage_store(u16* lds, const SReg<NS, NTHR>& R, int tid)
{
    constexpr int ROUNDS = NS * 32768 / (NTHR * 16);
#pragma unroll
    for (int i = 0; i < ROUNDS; i++) {
        const int off   = i * NTHR * 16 + tid * 16;
        const int plane = off >> 15;
        const int po    = off & 32767;
        const int row   = po >> 8;
        *(uint4*)((char*)lds + (plane << 15) + (po ^ ((row & 7) << 4))) = R.v[i];
    }
}

__device__ __forceinline__ bf16x8 ld_w(const u16* lds, int plane, int row, int kbyte)
{
    union { uint4 q; bf16x8 v; } u;
    u.q = *(const uint4*)((const char*)lds + plane * 32768 + row * 256
                          + (kbyte ^ ((row & 7) << 4)));
    return u.v;
}

// MFMA over one staged panel: acc[2][8] += a{0,1}[kk] @ W(+lo)
template<int NS>
__device__ __forceinline__ void mfma_panel(const u16* Wbuf, const bf16x8* a0,
                                           const bf16x8* a1, int l15, int lg,
                                           f32x4 acc[][8])
{
#pragma unroll
    for (int kk = 0; kk < 4; kk++)
#pragma unroll
        for (int n = 0; n < 8; n++) {
            const int rw = n * 16 + l15, kb = kk * 64 + lg * 16;
            const bf16x8 b = ld_w(Wbuf, 0, rw, kb);
            acc[0][n] = __builtin_amdgcn_mfma_f32_16x16x32_bf16(a0[kk], b, acc[0][n], 0, 0, 0);
            acc[1][n] = __builtin_amdgcn_mfma_f32_16x16x32_bf16(a1[kk], b, acc[1][n], 0, 0, 0);
            if (NS == 2) {
                const bf16x8 bl = ld_w(Wbuf, 1, rw, kb);
                acc[0][n] = __builtin_amdgcn_mfma_f32_16x16x32_bf16(a0[kk], bl, acc[0][n], 0, 0, 0);
                acc[1][n] = __builtin_amdgcn_mfma_f32_16x16x32_bf16(a1[kk], bl, acc[1][n], 0, 0, 0);
            }
        }
}

// Split-A variant: acc += ah@W + al@W (+ ah@Wlo when NS==2)
template<int NS>
__device__ __forceinline__ void mfma_panel_split(const u16* Wbuf,
    const bf16x8* a0h, const bf16x8* a0l, const bf16x8* a1h, const bf16x8* a1l,
    int l15, int lg, f32x4 acc[][8])
{
#pragma unroll
    for (int kk = 0; kk < 4; kk++)
#pragma unroll
        for (int n = 0; n < 8; n++) {
            const int rw = n * 16 + l15, kb = kk * 64 + lg * 16;
            const bf16x8 b = ld_w(Wbuf, 0, rw, kb);
            acc[0][n] = __builtin_amdgcn_mfma_f32_16x16x32_bf16(a0h[kk], b, acc[0][n], 0, 0, 0);
            acc[0][n] = __builtin_amdgcn_mfma_f32_16x16x32_bf16(a0l[kk], b, acc[0][n], 0, 0, 0);
            acc[1][n] = __builtin_amdgcn_mfma_f32_16x16x32_bf16(a1h[kk], b, acc[1][n], 0, 0, 0);
            acc[1][n] = __builtin_amdgcn_mfma_f32_16x16x32_bf16(a1l[kk], b, acc[1][n], 0, 0, 0);
            if (NS == 2) {
                const bf16x8 bl = ld_w(Wbuf, 1, rw, kb);
                acc[0][n] = __builtin_amdgcn_mfma_f32_16x16x32_bf16(a0h[kk], bl, acc[0][n], 0, 0, 0);
                acc[1][n] = __builtin_amdgcn_mfma_f32_16x16x32_bf16(a1h[kk], bl, acc[1][n], 0, 0, 0);
            }
        }
}

__device__ __forceinline__ void splitf8(const float* p, bf16x8* hi, bf16x8* lo)
{
    const float4 f0 = *(const float4*)p;
    const float4 f1 = *(const float4*)(p + 4);
    const float f[8] = {f0.x, f0.y, f0.z, f0.w, f1.x, f1.y, f1.z, f1.w};
    union { u16 s[8]; bf16x8 v; } H, L;
#pragma unroll
    for (int j = 0; j < 8; j++) {
        const u16 hv = f2bf(f[j]);
        H.s[j] = hv;
        L.s[j] = f2bf(f[j] - bf2f(hv));
    }
    *hi = H.v; *lo = L.v;
}

// =====================================================================
// Staged-weight MFMA GEMM (bf16 A): C[M x 128] = A[M x K] @ W.
// 128-row blocks, 256 threads, 4 waves x 32 rows, 2 blocks/CU (64KB LDS).
// Multi-chunk: next chunk's global loads issue under current MFMA.
// =====================================================================
template<int NS, int KCH, bool OUT_BF16, bool ADD>
__global__ __launch_bounds__(256, 2) void sgemm_bf(
    const int* __restrict__ flag, int want,
    const u16* __restrict__ A, int lda,
    const u16* __restrict__ WHi, const u16* __restrict__ WLo,
    int wstride, int wcstep,
    void* __restrict__ Cv, int ldc)
{
    if (*flag != want) return;
    __shared__ __align__(16) u16 Wbuf[NS * 16384];
    const int tid = threadIdx.x;
    const int lane = tid & 63, wv = tid >> 6;
    const int l15 = lane & 15, lg = lane >> 4;
    const long long row0 = (long long)blockIdx.x * 128 + wv * 32;

    f32x4 acc[2][8];
    {
        f32x4 z = {0.f, 0.f, 0.f, 0.f};
#pragma unroll
        for (int m = 0; m < 2; m++)
#pragma unroll
            for (int n = 0; n < 8; n++) acc[m][n] = z;
    }

    const u16* A0 = A + (row0 + l15) * (long long)lda + lg * 8;
    const u16* A1 = A0 + 16LL * lda;

    SReg<NS, 256> R;
    stage_load<NS, 256>(R, WHi, WLo, wstride, tid);
    for (int ks = 0; ks < KCH; ks++) {
        stage_store<NS, 256>(Wbuf, R, tid);
        __syncthreads();                       // panel staged
        if (ks + 1 < KCH)
            stage_load<NS, 256>(R, WHi + (ks + 1) * wcstep, WLo + (ks + 1) * wcstep,
                                wstride, tid); // prefetch under MFMA
        bf16x8 a0[4], a1[4];
#pragma unroll
        for (int kk = 0; kk < 4; kk++) {
            a0[kk] = *(const bf16x8*)(A0 + ks * 128 + kk * 32);
            a1[kk] = *(const bf16x8*)(A1 + ks * 128 + kk * 32);
        }
        mfma_panel<NS>(Wbuf, a0, a1, l15, lg, acc);
        if (ks + 1 < KCH) __syncthreads();     // panel reads done before re-store
    }

#pragma unroll
    for (int m = 0; m < 2; m++)
#pragma unroll
        for (int r = 0; r < 4; r++) {
            const long long row = row0 + m * 16 + lg * 4 + r;
            if (OUT_BF16) {
                u16* C = (u16*)Cv + row * ldc;
#pragma unroll
                for (int n = 0; n < 8; n++) C[n * 16 + l15] = f2bf(acc[m][n][r]);
            } else {
                float* C = (float*)Cv + row * ldc;
#pragma unroll
                for (int n = 0; n < 8; n++) {
                    float v = acc[m][n][r];
                    if (ADD) v += C[n * 16 + l15];
                    C[n * 16 + l15] = v;
                }
            }
        }
}

// =====================================================================
// Staged-weight MFMA GEMM (f32 A, split in-kernel into hi+lo bf16).
// =====================================================================
template<int NS, int KCH, bool OUT_BF16, bool ADD>
__global__ __launch_bounds__(256, 2) void sgemm_f32(
    const int* __restrict__ flag, int want,
    const float* __restrict__ A, int lda,
    const u16* __restrict__ WHi, const u16* __restrict__ WLo,
    int wstride, int wcstep,
    void* __restrict__ Cv, int ldc)
{
    if (*flag != want) return;
    __shared__ __align__(16) u16 Wbuf[NS * 16384];
    const int tid = threadIdx.x;
    const int lane = tid & 63, wv = tid >> 6;
    const int l15 = lane & 15, lg = lane >> 4;
    const long long row0 = (long long)blockIdx.x * 128 + wv * 32;

    f32x4 acc[2][8];
    {
        f32x4 z = {0.f, 0.f, 0.f, 0.f};
#pragma unroll
        for (int m = 0; m < 2; m++)
#pragma unroll
            for (int n = 0; n < 8; n++) acc[m][n] = z;
    }

    const float* A0 = A + (row0 + l15) * (long long)lda + lg * 8;
    const float* A1 = A0 + 16LL * lda;

    SReg<NS, 256> R;
    stage_load<NS, 256>(R, WHi, WLo, wstride, tid);
    for (int ks = 0; ks < KCH; ks++) {
        stage_store<NS, 256>(Wbuf, R, tid);
        __syncthreads();
        if (ks + 1 < KCH)
            stage_load<NS, 256>(R, WHi + (ks + 1) * wcstep, WLo + (ks + 1) * wcstep,
                                wstride, tid);
        bf16x8 a0h[4], a0l[4], a1h[4], a1l[4];
#pragma unroll
        for (int kk = 0; kk < 4; kk++) {
            splitf8(A0 + ks * 128 + kk * 32, &a0h[kk], &a0l[kk]);
            splitf8(A1 + ks * 128 + kk * 32, &a1h[kk], &a1l[kk]);
        }
        mfma_panel_split<NS>(Wbuf, a0h, a0l, a1h, a1l, l15, lg, acc);
        if (ks + 1 < KCH) __syncthreads();
    }

#pragma unroll
    for (int m = 0; m < 2; m++)
#pragma unroll
        for (int r = 0; r < 4; r++) {
            const long long row = row0 + m * 16 + lg * 4 + r;
            if (OUT_BF16) {
                u16* C = (u16*)Cv + row * ldc;
#pragma unroll
                for (int n = 0; n < 8; n++) C[n * 16 + l15] = f2bf(acc[m][n][r]);
            } else {
                float* C = (float*)Cv + row * ldc;
#pragma unroll
                for (int n = 0; n < 8; n++) {
                    float v = acc[m][n][r];
                    if (ADD) v += C[n * 16 + l15];
                    C[n * 16 + l15] = v;
                }
            }
        }
}

// =====================================================================
// Fused QKV (512 thr, 256 rows/block): ping-pong two panel buffers so
// each panel's global loads hide under the previous panel's MFMA.
// =====================================================================
template<int NS>
__global__ __launch_bounds__(512, 2) void qkv_fused(
    const int* __restrict__ flag, int want,
    const u16* __restrict__ h, const u16* __restrict__ wl,
    u16* __restrict__ qb, u16* __restrict__ kb, u16* __restrict__ vb)
{
    if (*flag != want) return;
    __shared__ __align__(16) u16 bufA[NS * 16384];
    __shared__ __align__(16) u16 bufB[NS * 16384];
    const int tid = threadIdx.x;
    const int lane = tid & 63, wv = tid >> 6;
    const int l15 = lane & 15, lg = lane >> 4;
    const long long row0 = (long long)blockIdx.x * 256 + wv * 32;

    bf16x8 a0[4], a1[4];
#pragma unroll
    for (int kk = 0; kk < 4; kk++) {
        a0[kk] = *(const bf16x8*)(h + (row0 + l15) * 128 + kk * 32 + lg * 8);
        a1[kk] = *(const bf16x8*)(h + (row0 + 16 + l15) * 128 + kk * 32 + lg * 8);
    }

    SReg<NS, 512> R;
    stage_load<NS, 512>(R, wl, wl + 16384, 128, tid);              // Q
    stage_store<NS, 512>(bufA, R, tid);
    __syncthreads();

#pragma unroll
    for (int m = 0; m < 3; m++) {
        if (m < 2)   // prefetch next panel under this panel's MFMA
            stage_load<NS, 512>(R, wl + (m + 1) * 32768,
                                wl + (m + 1) * 32768 + 16384, 128, tid);
        f32x4 acc[2][8];
        {
            f32x4 z = {0.f, 0.f, 0.f, 0.f};
#pragma unroll
            for (int i = 0; i < 2; i++)
#pragma unroll
                for (int n = 0; n < 8; n++) acc[i][n] = z;
        }
        const u16* cur = (m == 1) ? bufB : bufA;   // Q:A, K:B, V:A
        mfma_panel<NS>(cur, a0, a1, l15, lg, acc);
        u16* out = (m == 0) ? qb : (m == 1) ? kb : vb;
#pragma unroll
        for (int i = 0; i < 2; i++)
#pragma unroll
            for (int r = 0; r < 4; r++) {
                u16* C = out + (row0 + i * 16 + lg * 4 + r) * CA;
#pragma unroll
                for (int n = 0; n < 8; n++) C[n * 16 + l15] = f2bf(acc[i][n][r]);
            }
        if (m < 2) {
            stage_store<NS, 512>((m == 0) ? bufB : bufA, R, tid);
            __syncthreads();   // next panel staged; (for m=1: bufA reads done 1 bar ago)
        }
    }
}

// =====================================================================
// Fused MLP v4 (512 thr, 256 rows/block): x += relu(h @ Wt1) @ Wt2.
// Two weight buffers; every stage's global latency hides under MFMA:
//   loadR(W2c) | MFMA W1c -> storeR(W2buf), bar
//   loadR(W1c+1) | hidden-quarters + MFMA W2c -> storeR(W1buf), bar
// Hidden transpose via per-wave 32x80B quarter buffer (wave-local waits).
// LDS: 64 + 64 + 20 = 148 KB.
// =====================================================================
template<int NS>
__global__ __launch_bounds__(512, 2) void mlp_fused(
    const int* __restrict__ flag, int want,
    const u16* __restrict__ h,
    const u16* __restrict__ W1T, const u16* __restrict__ W2T,
    float* __restrict__ x)
{
    if (*flag != want) return;
    __shared__ __align__(16) u16 W1buf[NS * 16384];
    __shared__ __align__(16) u16 W2buf[NS * 16384];
    __shared__ __align__(16) u16 Plq[8][32][40];   // per-wave 32 rows x 80 B
    const int tid = threadIdx.x;
    const int lane = tid & 63, wv = tid >> 6;
    const int l15 = lane & 15, lg = lane >> 4;
    const long long row0 = (long long)blockIdx.x * 256 + wv * 32;
    u16* pw = &Plq[wv][0][0];

    bf16x8 ah0[4], ah1[4];
#pragma unroll
    for (int kk = 0; kk < 4; kk++) {
        ah0[kk] = *(const bf16x8*)(h + (row0 + l15) * 128 + kk * 32 + lg * 8);
        ah1[kk] = *(const bf16x8*)(h + (row0 + 16 + l15) * 128 + kk * 32 + lg * 8);
    }

    f32x4 xacc[2][8];
    {
        f32x4 z = {0.f, 0.f, 0.f, 0.f};
#pragma unroll
        for (int m = 0; m < 2; m++)
#pragma unroll
            for (int n = 0; n < 8; n++) xacc[m][n] = z;
    }

    SReg<NS, 512> R;
    stage_load<NS, 512>(R, W1T, W1T + 65536, 128, tid);
    stage_store<NS, 512>(W1buf, R, tid);
    __syncthreads();

    for (int c = 0; c < 4; c++) {
        // ---- W1 phase: issue W2 loads, MFMA W1, then store W2buf ----
        stage_load<NS, 512>(R, W2T + c * 128, W2T + 65536 + c * 128, 512, tid);
        f32x4 hacc[2][8];
        {
            f32x4 z = {0.f, 0.f, 0.f, 0.f};
#pragma unroll
            for (int m = 0; m < 2; m++)
#pragma unroll
                for (int n = 0; n < 8; n++) hacc[m][n] = z;
        }
        mfma_panel<NS>(W1buf, ah0, ah1, l15, lg, hacc);
        stage_store<NS, 512>(W2buf, R, tid);
        __syncthreads();                 // W2buf staged; all waves done W1 reads

        // ---- W2 phase: issue W1(c+1) loads, quarters, store W1buf ----
        if (c < 3)
            stage_load<NS, 512>(R, W1T + (c + 1) * 16384,
                                W1T + 65536 + (c + 1) * 16384, 128, tid);
#pragma unroll
        for (int q = 0; q < 4; q++) {
            // prior quarter's (or chunk's) Pl reads done before overwrite
            asm volatile("s_waitcnt lgkmcnt(0)" ::: "memory");
#pragma unroll
            for (int m = 0; m < 2; m++)
#pragma unroll
                for (int j = 0; j < 2; j++)
#pragma unroll
                    for (int r = 0; r < 4; r++)
                        pw[(m * 16 + lg * 4 + r) * 40 + j * 16 + l15]
                            = f2bf(fmaxf(hacc[m][2 * q + j][r], 0.f));
            asm volatile("s_waitcnt lgkmcnt(0)" ::: "memory");
            union { uint4 v; bf16x8 b; } t0, t1;
            t0.v = *(const uint4*)(pw + l15 * 40 + lg * 8);
            t1.v = *(const uint4*)(pw + (16 + l15) * 40 + lg * 8);
#pragma unroll
            for (int n = 0; n < 8; n++) {
                const int rw = n * 16 + l15, kb = q * 64 + lg * 16;
                const bf16x8 b = ld_w(W2buf, 0, rw, kb);
                xacc[0][n] = __builtin_amdgcn_mfma_f32_16x16x32_bf16(t0.b, b, xacc[0][n], 0, 0, 0);
                xacc[1][n] = __builtin_amdgcn_mfma_f32_16x16x32_bf16(t1.b, b, xacc[1][n], 0, 0, 0);
                if (NS == 2) {
                    const bf16x8 bl = ld_w(W2buf, 1, rw, kb);
                    xacc[0][n] = __builtin_amdgcn_mfma_f32_16x16x32_bf16(t0.b, bl, xacc[0][n], 0, 0, 0);
                    xacc[1][n] = __builtin_amdgcn_mfma_f32_16x16x32_bf16(t1.b, bl, xacc[1][n], 0, 0, 0);
                }
            }
        }
        if (c < 3) {
            stage_store<NS, 512>(W1buf, R, tid);
            __syncthreads();             // W1buf(c+1) staged; W2buf reads done
        }
    }

#pragma unroll
    for (int m = 0; m < 2; m++)
#pragma unroll
        for (int r = 0; r < 4; r++) {
            float* X = x + (row0 + m * 16 + lg * 4 + r) * 128;
#pragma unroll
            for (int n = 0; n < 8; n++) X[n * 16 + l15] += xacc[m][n][r];
        }
}

// =====================================================================
// Gather: x[b,n,:] = a_tok[b, idx[b,n], :]   (f32 -> f32)
// =====================================================================
__global__ __launch_bounds__(256) void gather_kernel(
    const int* __restrict__ flag, int want,
    const float* __restrict__ a_tok, const int* __restrict__ idx,
    float* __restrict__ x)
{
    if (*flag != want) return;
    const size_t i = (size_t)blockIdx.x * 256 + threadIdx.x;  // B*N*128 total
    const int c = (int)(i & 127);
    const size_t an = i >> 7;
    const int b = (int)(an >> 14);
    const int n = (int)(an & (NATOM - 1));
    const int t = idx[b * NATOM + n];
    x[i] = a_tok[(((size_t)b * NTOK) + t) * CA + c];
}

// =====================================================================
// LayerNorm: h = (x-m)*rsqrt(var+1e-5)*g + b   (f32 in, bf16 out)
// =====================================================================
template<typename TW>
__global__ __launch_bounds__(256) void ln_kernel(
    const int* __restrict__ flag, int want,
    const float* __restrict__ x, const TW* __restrict__ g,
    const TW* __restrict__ b, u16* __restrict__ h)
{
    if (*flag != want) return;
    const int lane = threadIdx.x & 63;
    const int wv   = threadIdx.x >> 6;
    const size_t atom = (size_t)blockIdx.x * 4 + wv;
    const float* xr = x + atom * CA;
    const float v0 = xr[lane], v1 = xr[lane + 64];
    float s  = v0 + v1;
    float sq = v0 * v0 + v1 * v1;
#pragma unroll
    for (int off = 32; off > 0; off >>= 1) {
        s  += __shfl_xor(s,  off, 64);
        sq += __shfl_xor(sq, off, 64);
    }
    const float mean = s * 0.0078125f;
    const float var  = sq * 0.0078125f - mean * mean;
    const float inv  = rsqrtf(var + 1e-5f);
    u16* hr = h + atom * CA;
    hr[lane]      = f2bf((v0 - mean) * inv * ld1(g + lane)      + ld1(b + lane));
    hr[lane + 64] = f2bf((v1 - mean) * inv * ld1(g + lane + 64) + ld1(b + lane + 64));
}

// =====================================================================
// Bias: t[b,a,h] for a < 128 from the pair-MLP; single block, 512 threads
// =====================================================================
template<typename TW>
__global__ __launch_bounds__(512) void bias_kernel(
    const int* __restrict__ flag, int want,
    const float* __restrict__ x,
    const TW* __restrict__ Wcl, const TW* __restrict__ Wcm,
    const TW* __restrict__ Wm1, const TW* __restrict__ Wm2,
    const TW* __restrict__ Wpb, float* __restrict__ tb)
{
    if (*flag != want) return;
    __shared__ float Wsum[128][16];
    __shared__ float M1[16][16];
    __shared__ float M2[16][16];
    __shared__ float Pb[16][4];
    const int tid = threadIdx.x;
    for (int i = tid; i < 128 * 16; i += 512)
        Wsum[i >> 4][i & 15] = ld1(Wcl + i) + ld1(Wcm + i);
    if (tid < 256) M1[tid >> 4][tid & 15] = ld1(Wm1 + tid);
    if (tid >= 256 && tid < 512) { int t2 = tid - 256; M2[t2 >> 4][t2 & 15] = ld1(Wm2 + t2); }
    if (tid < 64) Pb[tid >> 2][tid & 3] = ld1(Wpb + tid);
    __syncthreads();

    const int b = tid >> 7, a = tid & 127;
    const float* xa = x + ((size_t)b * NATOM + a) * CA;
    float u[16];
#pragma unroll
    for (int p = 0; p < 16; p++) u[p] = 0.f;
    for (int c = 0; c < 128; c++) {
        const float xv = xa[c];
#pragma unroll
        for (int p = 0; p < 16; p++) u[p] = fmaf(xv, Wsum[c][p], u[p]);
    }
    float r1[16];
#pragma unroll
    for (int p = 0; p < 16; p++) r1[p] = 0.f;
    for (int c = 0; c < 16; c++) {
        const float rv = fmaxf(u[c], 0.f);
#pragma unroll
        for (int p = 0; p < 16; p++) r1[p] = fmaf(rv, M1[c][p], r1[p]);
    }
    float r2[16];
#pragma unroll
    for (int p = 0; p < 16; p++) r2[p] = 0.f;
    for (int c = 0; c < 16; c++) {
        const float rv = fmaxf(r1[c], 0.f);
#pragma unroll
        for (int p = 0; p < 16; p++) r2[p] = fmaf(rv, M2[c][p], r2[p]);
    }
#pragma unroll
    for (int hh = 0; hh < 4; hh++) {
        float s = 0.f;
#pragma unroll
        for (int p = 0; p < 16; p++) s = fmaf(r2[p], Pb[p][hh], s);
        tb[(size_t)tid * 4 + hh] = s;
    }
}

// =====================================================================
// Windowed attention via MFMA (verified round 1): one block per (b, w).
// =====================================================================
#define VTP 132   // V^T row stride in u16
#define PPS 68    // P row stride in u16

__global__ __launch_bounds__(256) void attn_kernel(
    const int* __restrict__ flag, int want,
    const u16* __restrict__ qg, const u16* __restrict__ kg,
    const u16* __restrict__ vg, const float* __restrict__ tb,
    u16* __restrict__ og)
{
    if (*flag != want) return;
    __shared__ __align__(16) u16 VT[128][VTP];    // V^T: [d][j]
    __shared__ __align__(16) u16 Pl[NH][32][PPS]; // per-head P half

    const int tid  = threadIdx.x;
    const int lane = tid & 63;
    const int h    = tid >> 6;             // wave id == head
    const int b    = blockIdx.x >> 9;
    const int w    = blockIdx.x & (NWIN - 1);
    const int row0 = w * NQ;
    const int kbase = row0 - PAD;          // first key atom (may be < 0)
    const int l15 = lane & 15;
    const int lg  = lane >> 4;

    // ---- stage V^T into LDS (all 256 threads; zero invalid rows) ----
    {
        const int j  = tid & 127;
        const int d0 = (tid >> 7) << 6;    // 0 or 64
        const int ga = kbase + j;
        const bool val = (ga >= 0) && (ga < NATOM);
        const u16* vrow = vg + ((long long)b * NATOM + ga) * CA + d0;
#pragma unroll
        for (int t2 = 0; t2 < 8; t2++) {
            union { uint4 q; u16 s[8]; } u;
            if (val) u.q = *(const uint4*)(vrow + t2 * 8);
            else     u.q = make_uint4(0u, 0u, 0u, 0u);
#pragma unroll
            for (int e = 0; e < 8; e++) VT[d0 + t2 * 8 + e][j] = u.s[e];
        }
    }

    // ---- QK^T: S[32][128] per head, frags direct from global ----
    const long long qoff = ((long long)b * NATOM + row0) * CA + h * DH;
    const long long koff = ((long long)b * NATOM + kbase) * CA + h * DH;
    bf16x8 aq0 = *(const bf16x8*)(qg + qoff + (long long)l15 * CA + lg * 8);
    bf16x8 aq1 = *(const bf16x8*)(qg + qoff + (long long)(l15 + 16) * CA + lg * 8);

    f32x4 acc[2][8];
    {
        f32x4 z = {0.f, 0.f, 0.f, 0.f};
#pragma unroll
        for (int m = 0; m < 2; m++)
#pragma unroll
            for (int n = 0; n < 8; n++) acc[m][n] = z;
    }
#pragma unroll
    for (int n = 0; n < 8; n++) {
        bf16x8 bk = *(const bf16x8*)(kg + koff + (long long)(n * 16 + l15) * CA + lg * 8);
        acc[0][n] = __builtin_amdgcn_mfma_f32_16x16x32_bf16(aq0, bk, acc[0][n], 0, 0, 0);
        acc[1][n] = __builtin_amdgcn_mfma_f32_16x16x32_bf16(aq1, bk, acc[1][n], 0, 0, 0);
    }

    // ---- bias + scale + mask ----
    const float scale = 0.17677669529663687f;  // 1/sqrt(32)
    float tj[8], ti[2][4];
#pragma unroll
    for (int n = 0; n < 8; n++)
        tj[n] = tb[((size_t)b * 128 + n * 16 + l15) * 4 + h];
#pragma unroll
    for (int m = 0; m < 2; m++)
#pragma unroll
        for (int r = 0; r < 4; r++)
            ti[m][r] = tb[((size_t)b * 128 + m * 16 + lg * 4 + r) * 4 + h];

#pragma unroll
    for (int n = 0; n < 8; n++) {
        const int ga = kbase + n * 16 + l15;
        const bool val = (ga >= 0) && (ga < NATOM);
#pragma unroll
        for (int m = 0; m < 2; m++)
#pragma unroll
            for (int r = 0; r < 4; r++) {
                const float s = acc[m][n][r] * scale + ti[m][r] + tj[n];
                acc[m][n][r] = val ? s : -1e9f;
            }
    }

    // ---- softmax ----
    float mx[2][4], inv[2][4];
#pragma unroll
    for (int m = 0; m < 2; m++)
#pragma unroll
        for (int r = 0; r < 4; r++) {
            float v = acc[m][0][r];
#pragma unroll
            for (int n = 1; n < 8; n++) v = fmaxf(v, acc[m][n][r]);
            v = fmaxf(v, __shfl_xor(v, 1, 64));
            v = fmaxf(v, __shfl_xor(v, 2, 64));
            v = fmaxf(v, __shfl_xor(v, 4, 64));
            v = fmaxf(v, __shfl_xor(v, 8, 64));
            mx[m][r] = v;
        }
#pragma unroll
    for (int m = 0; m < 2; m++)
#pragma unroll
        for (int n = 0; n < 8; n++)
#pragma unroll
            for (int r = 0; r < 4; r++)
                acc[m][n][r] = __expf(acc[m][n][r] - mx[m][r]);
#pragma unroll
    for (int m = 0; m < 2; m++)
#pragma unroll
        for (int r = 0; r < 4; r++) {
            float v = 0.f;
#pragma unroll
            for (int n = 0; n < 8; n++) v += acc[m][n][r];
            v += __shfl_xor(v, 1, 64);
            v += __shfl_xor(v, 2, 64);
            v += __shfl_xor(v, 4, 64);
            v += __shfl_xor(v, 8, 64);
            inv[m][r] = 1.0f / v;
        }

    __syncthreads();   // V^T staged

    // ---- PV ----
    f32x4 o[2][2];
    {
        f32x4 z = {0.f, 0.f, 0.f, 0.f};
        o[0][0] = z; o[0][1] = z; o[1][0] = z; o[1][1] = z;
    }
    union B8 { bf16x8 v; uint2 u[2]; };
#pragma unroll
    for (int half = 0; half < 2; half++) {
        asm volatile("s_waitcnt lgkmcnt(0)" ::: "memory");
#pragma unroll
        for (int m = 0; m < 2; m++)
#pragma unroll
            for (int nn = 0; nn < 4; nn++)
#pragma unroll
                for (int r = 0; r < 4; r++)
                    Pl[h][m * 16 + lg * 4 + r][nn * 16 + l15]
                        = f2bf(acc[m][half * 4 + nn][r]);
        asm volatile("s_waitcnt lgkmcnt(0)" ::: "memory");
#pragma unroll
        for (int ks2 = 0; ks2 < 2; ks2++) {
            const int jo = ks2 * 32 + lg * 8;
            const int jg = half * 64 + jo;
            B8 pa0, pa1, vb0, vb1;
            pa0.u[0] = *(const uint2*)&Pl[h][l15][jo];
            pa0.u[1] = *(const uint2*)&Pl[h][l15][jo + 4];
            pa1.u[0] = *(const uint2*)&Pl[h][l15 + 16][jo];
            pa1.u[1] = *(const uint2*)&Pl[h][l15 + 16][jo + 4];
            vb0.u[0] = *(const uint2*)&VT[h * DH + l15][jg];
            vb0.u[1] = *(const uint2*)&VT[h * DH + l15][jg + 4];
            vb1.u[0] = *(const uint2*)&VT[h * DH + 16 + l15][jg];
            vb1.u[1] = *(const uint2*)&VT[h * DH + 16 + l15][jg + 4];
            o[0][0] = __builtin_amdgcn_mfma_f32_16x16x32_bf16(pa0.v, vb0.v, o[0][0], 0, 0, 0);
            o[0][1] = __builtin_amdgcn_mfma_f32_16x16x32_bf16(pa0.v, vb1.v, o[0][1], 0, 0, 0);
            o[1][0] = __builtin_amdgcn_mfma_f32_16x16x32_bf16(pa1.v, vb0.v, o[1][0], 0, 0, 0);
            o[1][1] = __builtin_amdgcn_mfma_f32_16x16x32_bf16(pa1.v, vb1.v, o[1][1], 0, 0, 0);
        }
    }

#pragma unroll
    for (int m = 0; m < 2; m++)
#pragma unroll
        for (int n = 0; n < 2; n++)
#pragma unroll
            for (int r = 0; r < 4; r++)
                og[((long long)b * NATOM + row0 + m * 16 + lg * 4 + r) * CA
                   + h * DH + n * 16 + l15]
                    = f2bf(o[m][n][r] * inv[m][r]);
}

// =====================================================================
// Final selector: write d_out as bf16 (flag=1) or f32 (flag=0)
// =====================================================================
__global__ __launch_bounds__(256) void select_kernel(
    const int* __restrict__ flag,
    const u16* __restrict__ outA, const u16* __restrict__ outB,
    void* __restrict__ d_out)
{
    const size_t i = (size_t)blockIdx.x * 256 + threadIdx.x;
    if (*flag) ((u16*)d_out)[i]   = outA[i];
    else       ((float*)d_out)[i] = bf2f(outB[i]);
}

// =====================================================================
// One full pipeline pass, templated on input storage type, gated on flag
// =====================================================================
template<typename TIN>
static void run_pass(void* const* d_in,
                     float* x, u16* h, u16* qb, u16* kb, u16* vb, u16* ob,
                     float* atok, u16* wt, float* tbv, u16* outbuf,
                     const int* flag, int want, hipStream_t stream)
{
    constexpr int NS = (sizeof(TIN) == 2) ? 1 : 2;

    const TIN* a    = (const TIN*)d_in[0];
    const int* idx  = (const int*)d_in[2];
    const TIN* W_a  = (const TIN*)d_in[3];
    const TIN* W_o  = (const TIN*)d_in[4];
    const TIN* Wcl  = (const TIN*)d_in[5];
    const TIN* Wcm  = (const TIN*)d_in[6];
    const TIN* Wm1  = (const TIN*)d_in[7];
    const TIN* Wm2  = (const TIN*)d_in[8];
    const TIN* Wpb  = (const TIN*)d_in[9];
    const TIN* Wq   = (const TIN*)d_in[10];
    const TIN* Wk   = (const TIN*)d_in[11];
    const TIN* Wv   = (const TIN*)d_in[12];
    const TIN* Wo   = (const TIN*)d_in[13];
    const TIN* ln1g = (const TIN*)d_in[14];
    const TIN* ln1b = (const TIN*)d_in[15];
    const TIN* Wt1  = (const TIN*)d_in[16];
    const TIN* Wt2  = (const TIN*)d_in[17];
    const TIN* ln2g = (const TIN*)d_in[18];
    const TIN* ln2b = (const TIN*)d_in[19];

    const size_t NEL = (size_t)BB * NATOM * CA;

    // 0) transpose (+split) all weights into WT workspace
    wtrans_kernel<TIN, NS><<<40, 256, 0, stream>>>(
        flag, want, W_a, Wq, Wk, Wv, Wo, Wt1, Wt2, W_o, wt);

    // 1) token projection [8192 x 384] @ [384 x 128] -> f32 atok
    if constexpr (NS == 1)
        sgemm_bf<1, 3, false, false><<<BB * NTOK / 128, 256, 0, stream>>>(
            flag, want, (const u16*)a, CTOK, wt + WT_WA, wt + WT_WA + 49152,
            CTOK, 128, atok, CA);
    else
        sgemm_f32<2, 3, false, false><<<BB * NTOK / 128, 256, 0, stream>>>(
            flag, want, (const float*)a, CTOK, wt + WT_WA, wt + WT_WA + 49152,
            CTOK, 128, atok, CA);

    gather_kernel<<<(unsigned)(NEL / 256), 256, 0, stream>>>(flag, want, atok, idx, x);
    bias_kernel<TIN><<<1, 512, 0, stream>>>(flag, want, x, Wcl, Wcm, Wm1, Wm2, Wpb, tbv);

    for (int l = 0; l < 3; l++) {
        u16* wl = wt + WT_L0 + (size_t)l * WT_LSZ;
        ln_kernel<TIN><<<BB * NATOM / 4, 256, 0, stream>>>(flag, want, x, ln1g + l * CA, ln1b + l * CA, h);
        qkv_fused<NS><<<256, 512, 0, stream>>>(flag, want, h, wl, qb, kb, vb);
        attn_kernel<<<BB * NWIN, 256, 0, stream>>>(flag, want, qb, kb, vb, tbv, ob);
        sgemm_bf<NS, 1, false, true><<<512, 256, 0, stream>>>(
            flag, want, ob, CA, wl + 98304, wl + 98304 + 16384, CA, 0, x, CA);
        ln_kernel<TIN><<<BB * NATOM / 4, 256, 0, stream>>>(flag, want, x, ln2g + l * CA, ln2b + l * CA, h);
        mlp_fused<NS><<<256, 512, 0, stream>>>(flag, want, h, wl + 131072, wl + 262144, x);
    }
    // out = x @ W_out -> bf16 outbuf (A is f32 residual: in-kernel split)
    sgemm_f32<NS, 1, true, false><<<512, 256, 0, stream>>>(
        flag, want, x, CA, wt + WT_WO, wt + WT_WO + 16384, CA, 0, outbuf, CA);
}

// =====================================================================
// Launch
// =====================================================================
extern "C" void kernel_launch(void* const* d_in, const int* in_sizes, int n_in,
                              void* d_out, int out_size, void* d_ws, size_t ws_size,
                              hipStream_t stream)
{
    (void)in_sizes; (void)n_in; (void)out_size;
    const size_t NEL = (size_t)BB * NATOM * CA;   // 8388608

    char* p = (char*)d_ws;
    float* x    = (float*)p;  p += NEL * 4;
    u16*   h    = (u16*)p;    p += NEL * 2;
    u16*   qb   = (u16*)p;    p += NEL * 2;
    u16*   kb   = (u16*)p;    p += NEL * 2;
    u16*   vb   = (u16*)p;    p += NEL * 2;
    u16*   ob   = (u16*)p;    p += NEL * 2;
    float* atok = (float*)p;  p += (size_t)BB * NTOK * CA * 4;
    float* tbv  = (float*)p;  p += 8192;
    u16*   outA = (u16*)p;    p += NEL * 2;
    u16*   outB = (u16*)p;    p += NEL * 2;
    int*   flag = (int*)p;    p += 256;
    u16*   wt   = (u16*)p;    p += (size_t)WT_TOT * 2;
    if ((size_t)(p - (char*)d_ws) > ws_size) return;  // workspace too small

    // 1) detect input storage dtype (writes flag: 1=bf16, 0=f32)
    detect_kernel<<<1, 256, 0, stream>>>((const u32*)d_in[3], flag);
    // 2) bf16-interpretation pass (runs only if flag==1)
    run_pass<u16>(d_in, x, h, qb, kb, vb, ob, atok, wt, tbv, outA, flag, 1, stream);
    // 3) f32-interpretation pass (runs only if flag==0)
    run_pass<float>(d_in, x, h, qb, kb, vb, ob, atok, wt, tbv, outB, flag, 0, stream);
    // 4) write d_out in the detected output format
    select_kernel<<<(unsigned)(NEL / 256), 256, 0, stream>>>(flag, outA, outB, d_out);
}

// Round 7
// 695.059 us; speedup vs baseline: 2.4034x; 1.1189x over previous
//
#include <hip/hip_runtime.h>

typedef unsigned short u16;
typedef unsigned int   u32;

typedef __attribute__((ext_vector_type(8))) __bf16 bf16x8;
typedef __attribute__((ext_vector_type(4))) float  f32x4;

// ---------- scalar/vec conversion helpers ----------
__device__ __forceinline__ float bf2f(u16 v) {
    return __uint_as_float(((u32)v) << 16);
}
__device__ __forceinline__ u16 f2bf(float f) {
    u32 u = __float_as_uint(f);
    u32 r = (u + 0x7fffu + ((u >> 16) & 1u)) >> 16;  // round-to-nearest-even
    return (u16)r;
}
__device__ __forceinline__ float ld1(const u16* p)   { return bf2f(*p); }
__device__ __forceinline__ float ld1(const float* p) { return *p; }

// ---------- problem constants ----------
#define BB 4
#define NTOK 2048
#define NATOM 16384
#define CTOK 384
#define CA 128
#define NQ 32
#define NK 128
#define NH 4
#define DH 32
#define NWIN 512
#define PAD 48

// Transposed-weight workspace layout (u16 elements).
// Each matrix stored as [N][K] hi-plane, then lo-plane (f32 path only).
#define WT_WA   0          // [128][384], lo plane at +49152
#define WT_L0   98304      // per-layer block start
#define WT_LSZ  393216     // Q 0 | K 32768 | V 65536 | O 98304 | T1 131072 | T2 262144
#define WT_WO   1277952    // [128][128], lo plane at +16384
#define WT_TOT  1310720

// =====================================================================
// dtype detector: look at low u16 of 1024 words of W_a.
// flag = 1 (bf16 inputs) or 0 (f32 inputs)
// =====================================================================
__global__ __launch_bounds__(256) void detect_kernel(const u32* __restrict__ wa,
                                                     int* __restrict__ flag)
{
    __shared__ int cnt;
    if (threadIdx.x == 0) cnt = 0;
    __syncthreads();
    int local = 0;
#pragma unroll
    for (int i = 0; i < 4; i++) {
        u32 w = wa[threadIdx.x * 4 + i];
        u32 e = (w >> 7) & 0xFFu;   // exponent field of the LOW u16 as bf16
        if (e >= 95u && e <= 135u) local++;
    }
    atomicAdd(&cnt, local);
    __syncthreads();
    if (threadIdx.x == 0) *flag = (cnt >= 614) ? 1 : 0;
}

// =====================================================================
// Weight transpose (+ bf16 split for f32 inputs) into WT workspace.
// 40 tiles of 128x128: Wa(3) | Wq/k/v/o x3 (12) | Wt1 (12) | Wt2 (12) | Wout(1)
// dst[n][k] = src[k][n]; f32 path: hi = bf16(w), lo = bf16(w - hi).
// =====================================================================
template<typename TIN, int SPLIT>
__global__ __launch_bounds__(256) void wtrans_kernel(
    const int* __restrict__ flag, int want,
    const TIN* __restrict__ Wa, const TIN* __restrict__ Wq,
    const TIN* __restrict__ Wk, const TIN* __restrict__ Wv,
    const TIN* __restrict__ Wo, const TIN* __restrict__ Wt1,
    const TIN* __restrict__ Wt2, const TIN* __restrict__ Wout,
    u16* __restrict__ WT)
{
    if (*flag != want) return;
    const int t = blockIdx.x;
    const TIN* S; int sld; u16* D; int dld; int plane;
    if (t < 3) {                                     // W_a [384][128]
        S = Wa + t * 128 * 128; sld = 128;
        D = WT + WT_WA + t * 128; dld = 384; plane = 49152;
    } else if (t < 15) {                             // Wq/k/v/o [128][128]
        const int i = t - 3, l = i >> 2, m = i & 3;
        const TIN* ms = (m == 0) ? Wq : (m == 1) ? Wk : (m == 2) ? Wv : Wo;
        S = ms + l * 16384; sld = 128;
        D = WT + WT_L0 + l * WT_LSZ + m * 32768; dld = 128; plane = 16384;
    } else if (t < 27) {                             // Wt1 [128][512] col-chunk c
        const int i = t - 15, l = i >> 2, c = i & 3;
        S = Wt1 + l * 65536 + c * 128; sld = 512;
        D = WT + WT_L0 + l * WT_LSZ + 131072 + c * 128 * 128; dld = 128; plane = 65536;
    } else if (t < 39) {                             // Wt2 [512][128] row-chunk c
        const int i = t - 27, l = i >> 2, c = i & 3;
        S = Wt2 + l * 65536 + c * 128 * 128; sld = 128;
        D = WT + WT_L0 + l * WT_LSZ + 262144 + c * 128; dld = 512; plane = 65536;
    } else {                                         // W_out [128][128]
        S = Wout; sld = 128;
        D = WT + WT_WO; dld = 128; plane = 16384;
    }
    const int tid = threadIdx.x;
    for (int id = tid; id < 2048; id += 256) {
        const int n = id >> 4, k0 = (id & 15) << 3;
        union { u16 s[8]; uint4 v; } hi, lo;
#pragma unroll
        for (int j = 0; j < 8; j++) {
            if constexpr (sizeof(TIN) == 2) {
                hi.s[j] = ((const u16*)(const void*)S)[(k0 + j) * sld + n];
                lo.s[j] = 0;
            } else {
                const float v = ((const float*)(const void*)S)[(k0 + j) * sld + n];
                const u16 hv = f2bf(v);
                hi.s[j] = hv;
                lo.s[j] = f2bf(v - bf2f(hv));
            }
        }
        *(uint4*)(D + n * dld + k0) = hi.v;
        if (SPLIT == 2) *(uint4*)(D + plane + n * dld + k0) = lo.v;
    }
}

// =====================================================================
// Async weight-panel staging via global_load_lds (no staging VGPRs).
// LDS image: [plane][128 rows][256 B] LINEAR in segment order; the XOR
// swizzle byte^((row&7)<<4) is applied to the per-lane GLOBAL source
// (inverse-swz source + swz read = both-sides rule). Each wave stages
// contiguous 1 KB segments: dest = wave-uniform base + lane*16.
// __syncthreads() drains vmcnt -> panel visible to all waves.
// =====================================================================
__device__ __forceinline__ void gld16(const void* g, void* l)
{
    __builtin_amdgcn_global_load_lds(
        (const __attribute__((address_space(1))) void*)g,
        (__attribute__((address_space(3))) void*)l, 16, 0, 0);
}

template<int NS, int NTHR>
__device__ __forceinline__ void stage_async(u16* lds, const u16* srcHi,
                                            const u16* srcLo, int strideU16, int tid)
{
    constexpr int NWAVE = NTHR / 64;
    constexpr int NSEG  = NS * 32768 / (NWAVE * 1024);
    const int lane = tid & 63;
    const int wv   = tid >> 6;
#pragma unroll
    for (int i = 0; i < NSEG; i++) {
        const int segoff  = (wv * NSEG + i) << 10;      // byte, wave-uniform
        const int po_full = segoff + lane * 16;
        const int plane   = po_full >> 15;
        const int po      = po_full & 32767;
        const int row     = po >> 8;
        const int colB    = (po & 255) ^ ((row & 7) << 4);
        const u16* g = (plane ? srcLo : srcHi) + row * strideU16 + (colB >> 1);
        gld16(g, (char*)lds + segoff);
    }
}

__device__ __forceinline__ bf16x8 ld_w(const u16* lds, int plane, int row, int kbyte)
{
    union { uint4 q; bf16x8 v; } u;
    u.q = *(const uint4*)((const char*)lds + plane * 32768 + row * 256
                          + (kbyte ^ ((row & 7) << 4)));
    return u.v;
}

// MFMA over one staged panel: acc[2][8] += a{0,1}[kk] @ W(+lo)
template<int NS>
__device__ __forceinline__ void mfma_panel(const u16* Wbuf, const bf16x8* a0,
                                           const bf16x8* a1, int l15, int lg,
                                           f32x4 acc[][8])
{
#pragma unroll
    for (int kk = 0; kk < 4; kk++)
#pragma unroll
        for (int n = 0; n < 8; n++) {
            const int rw = n * 16 + l15, kb = kk * 64 + lg * 16;
            const bf16x8 b = ld_w(Wbuf, 0, rw, kb);
            acc[0][n] = __builtin_amdgcn_mfma_f32_16x16x32_bf16(a0[kk], b, acc[0][n], 0, 0, 0);
            acc[1][n] = __builtin_amdgcn_mfma_f32_16x16x32_bf16(a1[kk], b, acc[1][n], 0, 0, 0);
            if (NS == 2) {
                const bf16x8 bl = ld_w(Wbuf, 1, rw, kb);
                acc[0][n] = __builtin_amdgcn_mfma_f32_16x16x32_bf16(a0[kk], bl, acc[0][n], 0, 0, 0);
                acc[1][n] = __builtin_amdgcn_mfma_f32_16x16x32_bf16(a1[kk], bl, acc[1][n], 0, 0, 0);
            }
        }
}

// Split-A variant: acc += ah@W + al@W (+ ah@Wlo when NS==2)
template<int NS>
__device__ __forceinline__ void mfma_panel_split(const u16* Wbuf,
    const bf16x8* a0h, const bf16x8* a0l, const bf16x8* a1h, const bf16x8* a1l,
    int l15, int lg, f32x4 acc[][8])
{
#pragma unroll
    for (int kk = 0; kk < 4; kk++)
#pragma unroll
        for (int n = 0; n < 8; n++) {
            const int rw = n * 16 + l15, kb = kk * 64 + lg * 16;
            const bf16x8 b = ld_w(Wbuf, 0, rw, kb);
            acc[0][n] = __builtin_amdgcn_mfma_f32_16x16x32_bf16(a0h[kk], b, acc[0][n], 0, 0, 0);
            acc[0][n] = __builtin_amdgcn_mfma_f32_16x16x32_bf16(a0l[kk], b, acc[0][n], 0, 0, 0);
            acc[1][n] = __builtin_amdgcn_mfma_f32_16x16x32_bf16(a1h[kk], b, acc[1][n], 0, 0, 0);
            acc[1][n] = __builtin_amdgcn_mfma_f32_16x16x32_bf16(a1l[kk], b, acc[1][n], 0, 0, 0);
            if (NS == 2) {
                const bf16x8 bl = ld_w(Wbuf, 1, rw, kb);
                acc[0][n] = __builtin_amdgcn_mfma_f32_16x16x32_bf16(a0h[kk], bl, acc[0][n], 0, 0, 0);
                acc[1][n] = __builtin_amdgcn_mfma_f32_16x16x32_bf16(a1h[kk], bl, acc[1][n], 0, 0, 0);
            }
        }
}

__device__ __forceinline__ void splitf8(const float* p, bf16x8* hi, bf16x8* lo)
{
    const float4 f0 = *(const float4*)p;
    const float4 f1 = *(const float4*)(p + 4);
    const float f[8] = {f0.x, f0.y, f0.z, f0.w, f1.x, f1.y, f1.z, f1.w};
    union { u16 s[8]; bf16x8 v; } H, L;
#pragma unroll
    for (int j = 0; j < 8; j++) {
        const u16 hv = f2bf(f[j]);
        H.s[j] = hv;
        L.s[j] = f2bf(f[j] - bf2f(hv));
    }
    *hi = H.v; *lo = L.v;
}

// =====================================================================
// Staged-weight MFMA GEMM (bf16 A): C[M x 128] = A[M x K] @ W.
// 128-row blocks, 256 threads, 4 waves x 32 rows, 2 blocks/CU.
// =====================================================================
template<int NS, int KCH, bool OUT_BF16, bool ADD>
__global__ __launch_bounds__(256, 2) void sgemm_bf(
    const int* __restrict__ flag, int want,
    const u16* __restrict__ A, int lda,
    const u16* __restrict__ WHi, const u16* __restrict__ WLo,
    int wstride, int wcstep,
    void* __restrict__ Cv, int ldc)
{
    if (*flag != want) return;
    __shared__ __align__(16) u16 Wbuf[NS * 16384];
    const int tid = threadIdx.x;
    const int lane = tid & 63, wv = tid >> 6;
    const int l15 = lane & 15, lg = lane >> 4;
    const long long row0 = (long long)blockIdx.x * 128 + wv * 32;

    f32x4 acc[2][8];
    {
        f32x4 z = {0.f, 0.f, 0.f, 0.f};
#pragma unroll
        for (int m = 0; m < 2; m++)
#pragma unroll
            for (int n = 0; n < 8; n++) acc[m][n] = z;
    }

    const u16* A0 = A + (row0 + l15) * (long long)lda + lg * 8;
    const u16* A1 = A0 + 16LL * lda;

    stage_async<NS, 256>(Wbuf, WHi, WLo, wstride, tid);
    for (int ks = 0; ks < KCH; ks++) {
        bf16x8 a0[4], a1[4];
#pragma unroll
        for (int kk = 0; kk < 4; kk++) {
            a0[kk] = *(const bf16x8*)(A0 + ks * 128 + kk * 32);
            a1[kk] = *(const bf16x8*)(A1 + ks * 128 + kk * 32);
        }
        __syncthreads();                       // panel staged (vmcnt drained)
        mfma_panel<NS>(Wbuf, a0, a1, l15, lg, acc);
        if (ks + 1 < KCH) {
            __syncthreads();                   // panel reads done before restage
            stage_async<NS, 256>(Wbuf, WHi + (ks + 1) * wcstep,
                                 WLo + (ks + 1) * wcstep, wstride, tid);
        }
    }

#pragma unroll
    for (int m = 0; m < 2; m++)
#pragma unroll
        for (int r = 0; r < 4; r++) {
            const long long row = row0 + m * 16 + lg * 4 + r;
            if (OUT_BF16) {
                u16* C = (u16*)Cv + row * ldc;
#pragma unroll
                for (int n = 0; n < 8; n++) C[n * 16 + l15] = f2bf(acc[m][n][r]);
            } else {
                float* C = (float*)Cv + row * ldc;
#pragma unroll
                for (int n = 0; n < 8; n++) {
                    float v = acc[m][n][r];
                    if (ADD) v += C[n * 16 + l15];
                    C[n * 16 + l15] = v;
                }
            }
        }
}

// =====================================================================
// Staged-weight MFMA GEMM (f32 A, split in-kernel into hi+lo bf16).
// =====================================================================
template<int NS, int KCH, bool OUT_BF16, bool ADD>
__global__ __launch_bounds__(256, 2) void sgemm_f32(
    const int* __restrict__ flag, int want,
    const float* __restrict__ A, int lda,
    const u16* __restrict__ WHi, const u16* __restrict__ WLo,
    int wstride, int wcstep,
    void* __restrict__ Cv, int ldc)
{
    if (*flag != want) return;
    __shared__ __align__(16) u16 Wbuf[NS * 16384];
    const int tid = threadIdx.x;
    const int lane = tid & 63, wv = tid >> 6;
    const int l15 = lane & 15, lg = lane >> 4;
    const long long row0 = (long long)blockIdx.x * 128 + wv * 32;

    f32x4 acc[2][8];
    {
        f32x4 z = {0.f, 0.f, 0.f, 0.f};
#pragma unroll
        for (int m = 0; m < 2; m++)
#pragma unroll
            for (int n = 0; n < 8; n++) acc[m][n] = z;
    }

    const float* A0 = A + (row0 + l15) * (long long)lda + lg * 8;
    const float* A1 = A0 + 16LL * lda;

    stage_async<NS, 256>(Wbuf, WHi, WLo, wstride, tid);
    for (int ks = 0; ks < KCH; ks++) {
        bf16x8 a0h[4], a0l[4], a1h[4], a1l[4];
#pragma unroll
        for (int kk = 0; kk < 4; kk++) {
            splitf8(A0 + ks * 128 + kk * 32, &a0h[kk], &a0l[kk]);
            splitf8(A1 + ks * 128 + kk * 32, &a1h[kk], &a1l[kk]);
        }
        __syncthreads();
        mfma_panel_split<NS>(Wbuf, a0h, a0l, a1h, a1l, l15, lg, acc);
        if (ks + 1 < KCH) {
            __syncthreads();
            stage_async<NS, 256>(Wbuf, WHi + (ks + 1) * wcstep,
                                 WLo + (ks + 1) * wcstep, wstride, tid);
        }
    }

#pragma unroll
    for (int m = 0; m < 2; m++)
#pragma unroll
        for (int r = 0; r < 4; r++) {
            const long long row = row0 + m * 16 + lg * 4 + r;
            if (OUT_BF16) {
                u16* C = (u16*)Cv + row * ldc;
#pragma unroll
                for (int n = 0; n < 8; n++) C[n * 16 + l15] = f2bf(acc[m][n][r]);
            } else {
                float* C = (float*)Cv + row * ldc;
#pragma unroll
                for (int n = 0; n < 8; n++) {
                    float v = acc[m][n][r];
                    if (ADD) v += C[n * 16 + l15];
                    C[n * 16 + l15] = v;
                }
            }
        }
}

// =====================================================================
// Fused QKV (512 thr, 256 rows/block): ping-pong two panel buffers;
// next panel's async loads issue before this panel's MFMA, and the
// end-of-iteration barrier drains them. No staging registers.
// =====================================================================
template<int NS>
__global__ __launch_bounds__(512, 1) void qkv_fused(
    const int* __restrict__ flag, int want,
    const u16* __restrict__ h, const u16* __restrict__ wl,
    u16* __restrict__ qb, u16* __restrict__ kb, u16* __restrict__ vb)
{
    if (*flag != want) return;
    __shared__ __align__(16) u16 bufA[NS * 16384];
    __shared__ __align__(16) u16 bufB[NS * 16384];
    const int tid = threadIdx.x;
    const int lane = tid & 63, wv = tid >> 6;
    const int l15 = lane & 15, lg = lane >> 4;
    const long long row0 = (long long)blockIdx.x * 256 + wv * 32;

    bf16x8 a0[4], a1[4];
#pragma unroll
    for (int kk = 0; kk < 4; kk++) {
        a0[kk] = *(const bf16x8*)(h + (row0 + l15) * 128 + kk * 32 + lg * 8);
        a1[kk] = *(const bf16x8*)(h + (row0 + 16 + l15) * 128 + kk * 32 + lg * 8);
    }

    stage_async<NS, 512>(bufA, wl, wl + 16384, 128, tid);          // Q
    __syncthreads();

#pragma unroll
    for (int m = 0; m < 3; m++) {
        if (m < 2)   // prefetch next panel; safe: target buffer's readers done
            stage_async<NS, 512>((m == 0) ? bufB : bufA,
                                 wl + (m + 1) * 32768,
                                 wl + (m + 1) * 32768 + 16384, 128, tid);
        f32x4 acc[2][8];
        {
            f32x4 z = {0.f, 0.f, 0.f, 0.f};
#pragma unroll
            for (int i = 0; i < 2; i++)
#pragma unroll
                for (int n = 0; n < 8; n++) acc[i][n] = z;
        }
        const u16* cur = (m == 1) ? bufB : bufA;   // Q:A, K:B, V:A
        mfma_panel<NS>(cur, a0, a1, l15, lg, acc);
        u16* out = (m == 0) ? qb : (m == 1) ? kb : vb;
#pragma unroll
        for (int i = 0; i < 2; i++)
#pragma unroll
            for (int r = 0; r < 4; r++) {
                u16* C = out + (row0 + i * 16 + lg * 4 + r) * CA;
#pragma unroll
                for (int n = 0; n < 8; n++) C[n * 16 + l15] = f2bf(acc[i][n][r]);
            }
        if (m < 2) __syncthreads();   // drains prefetch; all waves done cur reads
    }
}

// =====================================================================
// Fused MLP v5 (512 thr, 256 rows/block): x += relu(h @ Wt1) @ Wt2.
// Two weight buffers, async gload_lds staging:
//   issue(W2c) | MFMA W1 | bar | issue(W1c+1) | quarters+MFMA W2 | bar
// Hidden transpose via per-wave 32x80B quarter buffer (wave-local waits).
// LDS: 64 + 64 + 20 = 148 KB; (512,1) so the allocator avoids spills.
// =====================================================================
template<int NS>
__global__ __launch_bounds__(512, 1) void mlp_fused(
    const int* __restrict__ flag, int want,
    const u16* __restrict__ h,
    const u16* __restrict__ W1T, const u16* __restrict__ W2T,
    float* __restrict__ x)
{
    if (*flag != want) return;
    __shared__ __align__(16) u16 W1buf[NS * 16384];
    __shared__ __align__(16) u16 W2buf[NS * 16384];
    __shared__ __align__(16) u16 Plq[8][32][40];   // per-wave 32 rows x 80 B
    const int tid = threadIdx.x;
    const int lane = tid & 63, wv = tid >> 6;
    const int l15 = lane & 15, lg = lane >> 4;
    const long long row0 = (long long)blockIdx.x * 256 + wv * 32;
    u16* pw = &Plq[wv][0][0];

    bf16x8 ah0[4], ah1[4];
#pragma unroll
    for (int kk = 0; kk < 4; kk++) {
        ah0[kk] = *(const bf16x8*)(h + (row0 + l15) * 128 + kk * 32 + lg * 8);
        ah1[kk] = *(const bf16x8*)(h + (row0 + 16 + l15) * 128 + kk * 32 + lg * 8);
    }

    f32x4 xacc[2][8];
    {
        f32x4 z = {0.f, 0.f, 0.f, 0.f};
#pragma unroll
        for (int m = 0; m < 2; m++)
#pragma unroll
            for (int n = 0; n < 8; n++) xacc[m][n] = z;
    }

    stage_async<NS, 512>(W1buf, W1T, W1T + 65536, 128, tid);
    __syncthreads();

    for (int c = 0; c < 4; c++) {
        // ---- W1 phase: issue W2c loads, MFMA W1 under them ----
        stage_async<NS, 512>(W2buf, W2T + c * 128, W2T + 65536 + c * 128, 512, tid);
        f32x4 hacc[2][8];
        {
            f32x4 z = {0.f, 0.f, 0.f, 0.f};
#pragma unroll
            for (int m = 0; m < 2; m++)
#pragma unroll
                for (int n = 0; n < 8; n++) hacc[m][n] = z;
        }
        mfma_panel<NS>(W1buf, ah0, ah1, l15, lg, hacc);
        __syncthreads();                 // W2buf staged; all waves done W1 reads

        // ---- W2 phase: issue W1(c+1) loads, quarters + MFMA W2 ----
        if (c < 3)
            stage_async<NS, 512>(W1buf, W1T + (c + 1) * 16384,
                                 W1T + 65536 + (c + 1) * 16384, 128, tid);
#pragma unroll
        for (int q = 0; q < 4; q++) {
            // prior quarter's Pl reads done before overwrite (wave-local)
            asm volatile("s_waitcnt lgkmcnt(0)" ::: "memory");
#pragma unroll
            for (int m = 0; m < 2; m++)
#pragma unroll
                for (int j = 0; j < 2; j++)
#pragma unroll
                    for (int r = 0; r < 4; r++)
                        pw[(m * 16 + lg * 4 + r) * 40 + j * 16 + l15]
                            = f2bf(fmaxf(hacc[m][2 * q + j][r], 0.f));
            asm volatile("s_waitcnt lgkmcnt(0)" ::: "memory");
            union { uint4 v; bf16x8 b; } t0, t1;
            t0.v = *(const uint4*)(pw + l15 * 40 + lg * 8);
            t1.v = *(const uint4*)(pw + (16 + l15) * 40 + lg * 8);
#pragma unroll
            for (int n = 0; n < 8; n++) {
                const int rw = n * 16 + l15, kb = q * 64 + lg * 16;
                const bf16x8 b = ld_w(W2buf, 0, rw, kb);
                xacc[0][n] = __builtin_amdgcn_mfma_f32_16x16x32_bf16(t0.b, b, xacc[0][n], 0, 0, 0);
                xacc[1][n] = __builtin_amdgcn_mfma_f32_16x16x32_bf16(t1.b, b, xacc[1][n], 0, 0, 0);
                if (NS == 2) {
                    const bf16x8 bl = ld_w(W2buf, 1, rw, kb);
                    xacc[0][n] = __builtin_amdgcn_mfma_f32_16x16x32_bf16(t0.b, bl, xacc[0][n], 0, 0, 0);
                    xacc[1][n] = __builtin_amdgcn_mfma_f32_16x16x32_bf16(t1.b, bl, xacc[1][n], 0, 0, 0);
                }
            }
        }
        if (c < 3) __syncthreads();      // W1buf(c+1) staged; W2buf reads done
    }

#pragma unroll
    for (int m = 0; m < 2; m++)
#pragma unroll
        for (int r = 0; r < 4; r++) {
            float* X = x + (row0 + m * 16 + lg * 4 + r) * 128;
#pragma unroll
            for (int n = 0; n < 8; n++) X[n * 16 + l15] += xacc[m][n][r];
        }
}

// =====================================================================
// Gather: x[b,n,:] = a_tok[b, idx[b,n], :]   (f32 -> f32)
// =====================================================================
__global__ __launch_bounds__(256) void gather_kernel(
    const int* __restrict__ flag, int want,
    const float* __restrict__ a_tok, const int* __restrict__ idx,
    float* __restrict__ x)
{
    if (*flag != want) return;
    const size_t i = (size_t)blockIdx.x * 256 + threadIdx.x;  // B*N*128 total
    const int c = (int)(i & 127);
    const size_t an = i >> 7;
    const int b = (int)(an >> 14);
    const int n = (int)(an & (NATOM - 1));
    const int t = idx[b * NATOM + n];
    x[i] = a_tok[(((size_t)b * NTOK) + t) * CA + c];
}

// =====================================================================
// LayerNorm: h = (x-m)*rsqrt(var+1e-5)*g + b   (f32 in, bf16 out)
// =====================================================================
template<typename TW>
__global__ __launch_bounds__(256) void ln_kernel(
    const int* __restrict__ flag, int want,
    const float* __restrict__ x, const TW* __restrict__ g,
    const TW* __restrict__ b, u16* __restrict__ h)
{
    if (*flag != want) return;
    const int lane = threadIdx.x & 63;
    const int wv   = threadIdx.x >> 6;
    const size_t atom = (size_t)blockIdx.x * 4 + wv;
    const float* xr = x + atom * CA;
    const float v0 = xr[lane], v1 = xr[lane + 64];
    float s  = v0 + v1;
    float sq = v0 * v0 + v1 * v1;
#pragma unroll
    for (int off = 32; off > 0; off >>= 1) {
        s  += __shfl_xor(s,  off, 64);
        sq += __shfl_xor(sq, off, 64);
    }
    const float mean = s * 0.0078125f;
    const float var  = sq * 0.0078125f - mean * mean;
    const float inv  = rsqrtf(var + 1e-5f);
    u16* hr = h + atom * CA;
    hr[lane]      = f2bf((v0 - mean) * inv * ld1(g + lane)      + ld1(b + lane));
    hr[lane + 64] = f2bf((v1 - mean) * inv * ld1(g + lane + 64) + ld1(b + lane + 64));
}

// =====================================================================
// Bias: t[b,a,h] for a < 128 from the pair-MLP; single block, 512 threads
// =====================================================================
template<typename TW>
__global__ __launch_bounds__(512) void bias_kernel(
    const int* __restrict__ flag, int want,
    const float* __restrict__ x,
    const TW* __restrict__ Wcl, const TW* __restrict__ Wcm,
    const TW* __restrict__ Wm1, const TW* __restrict__ Wm2,
    const TW* __restrict__ Wpb, float* __restrict__ tb)
{
    if (*flag != want) return;
    __shared__ float Wsum[128][16];
    __shared__ float M1[16][16];
    __shared__ float M2[16][16];
    __shared__ float Pb[16][4];
    const int tid = threadIdx.x;
    for (int i = tid; i < 128 * 16; i += 512)
        Wsum[i >> 4][i & 15] = ld1(Wcl + i) + ld1(Wcm + i);
    if (tid < 256) M1[tid >> 4][tid & 15] = ld1(Wm1 + tid);
    if (tid >= 256 && tid < 512) { int t2 = tid - 256; M2[t2 >> 4][t2 & 15] = ld1(Wm2 + t2); }
    if (tid < 64) Pb[tid >> 2][tid & 3] = ld1(Wpb + tid);
    __syncthreads();

    const int b = tid >> 7, a = tid & 127;
    const float* xa = x + ((size_t)b * NATOM + a) * CA;
    float u[16];
#pragma unroll
    for (int p = 0; p < 16; p++) u[p] = 0.f;
    for (int c = 0; c < 128; c++) {
        const float xv = xa[c];
#pragma unroll
        for (int p = 0; p < 16; p++) u[p] = fmaf(xv, Wsum[c][p], u[p]);
    }
    float r1[16];
#pragma unroll
    for (int p = 0; p < 16; p++) r1[p] = 0.f;
    for (int c = 0; c < 16; c++) {
        const float rv = fmaxf(u[c], 0.f);
#pragma unroll
        for (int p = 0; p < 16; p++) r1[p] = fmaf(rv, M1[c][p], r1[p]);
    }
    float r2[16];
#pragma unroll
    for (int p = 0; p < 16; p++) r2[p] = 0.f;
    for (int c = 0; c < 16; c++) {
        const float rv = fmaxf(r1[c], 0.f);
#pragma unroll
        for (int p = 0; p < 16; p++) r2[p] = fmaf(rv, M2[c][p], r2[p]);
    }
#pragma unroll
    for (int hh = 0; hh < 4; hh++) {
        float s = 0.f;
#pragma unroll
        for (int p = 0; p < 16; p++) s = fmaf(r2[p], Pb[p][hh], s);
        tb[(size_t)tid * 4 + hh] = s;
    }
}

// =====================================================================
// Windowed attention via MFMA (verified round 1): one block per (b, w).
// =====================================================================
#define VTP 132   // V^T row stride in u16
#define PPS 68    // P row stride in u16

__global__ __launch_bounds__(256) void attn_kernel(
    const int* __restrict__ flag, int want,
    const u16* __restrict__ qg, const u16* __restrict__ kg,
    const u16* __restrict__ vg, const float* __restrict__ tb,
    u16* __restrict__ og)
{
    if (*flag != want) return;
    __shared__ __align__(16) u16 VT[128][VTP];    // V^T: [d][j]
    __shared__ __align__(16) u16 Pl[NH][32][PPS]; // per-head P half

    const int tid  = threadIdx.x;
    const int lane = tid & 63;
    const int h    = tid >> 6;             // wave id == head
    const int b    = blockIdx.x >> 9;
    const int w    = blockIdx.x & (NWIN - 1);
    const int row0 = w * NQ;
    const int kbase = row0 - PAD;          // first key atom (may be < 0)
    const int l15 = lane & 15;
    const int lg  = lane >> 4;

    // ---- stage V^T into LDS (all 256 threads; zero invalid rows) ----
    {
        const int j  = tid & 127;
        const int d0 = (tid >> 7) << 6;    // 0 or 64
        const int ga = kbase + j;
        const bool val = (ga >= 0) && (ga < NATOM);
        const u16* vrow = vg + ((long long)b * NATOM + ga) * CA + d0;
#pragma unroll
        for (int t2 = 0; t2 < 8; t2++) {
            union { uint4 q; u16 s[8]; } u;
            if (val) u.q = *(const uint4*)(vrow + t2 * 8);
            else     u.q = make_uint4(0u, 0u, 0u, 0u);
#pragma unroll
            for (int e = 0; e < 8; e++) VT[d0 + t2 * 8 + e][j] = u.s[e];
        }
    }

    // ---- QK^T: S[32][128] per head, frags direct from global ----
    const long long qoff = ((long long)b * NATOM + row0) * CA + h * DH;
    const long long koff = ((long long)b * NATOM + kbase) * CA + h * DH;
    bf16x8 aq0 = *(const bf16x8*)(qg + qoff + (long long)l15 * CA + lg * 8);
    bf16x8 aq1 = *(const bf16x8*)(qg + qoff + (long long)(l15 + 16) * CA + lg * 8);

    f32x4 acc[2][8];
    {
        f32x4 z = {0.f, 0.f, 0.f, 0.f};
#pragma unroll
        for (int m = 0; m < 2; m++)
#pragma unroll
            for (int n = 0; n < 8; n++) acc[m][n] = z;
    }
#pragma unroll
    for (int n = 0; n < 8; n++) {
        bf16x8 bk = *(const bf16x8*)(kg + koff + (long long)(n * 16 + l15) * CA + lg * 8);
        acc[0][n] = __builtin_amdgcn_mfma_f32_16x16x32_bf16(aq0, bk, acc[0][n], 0, 0, 0);
        acc[1][n] = __builtin_amdgcn_mfma_f32_16x16x32_bf16(aq1, bk, acc[1][n], 0, 0, 0);
    }

    // ---- bias + scale + mask ----
    const float scale = 0.17677669529663687f;  // 1/sqrt(32)
    float tj[8], ti[2][4];
#pragma unroll
    for (int n = 0; n < 8; n++)
        tj[n] = tb[((size_t)b * 128 + n * 16 + l15) * 4 + h];
#pragma unroll
    for (int m = 0; m < 2; m++)
#pragma unroll
        for (int r = 0; r < 4; r++)
            ti[m][r] = tb[((size_t)b * 128 + m * 16 + lg * 4 + r) * 4 + h];

#pragma unroll
    for (int n = 0; n < 8; n++) {
        const int ga = kbase + n * 16 + l15;
        const bool val = (ga >= 0) && (ga < NATOM);
#pragma unroll
        for (int m = 0; m < 2; m++)
#pragma unroll
            for (int r = 0; r < 4; r++) {
                const float s = acc[m][n][r] * scale + ti[m][r] + tj[n];
                acc[m][n][r] = val ? s : -1e9f;
            }
    }

    // ---- softmax ----
    float mx[2][4], inv[2][4];
#pragma unroll
    for (int m = 0; m < 2; m++)
#pragma unroll
        for (int r = 0; r < 4; r++) {
            float v = acc[m][0][r];
#pragma unroll
            for (int n = 1; n < 8; n++) v = fmaxf(v, acc[m][n][r]);
            v = fmaxf(v, __shfl_xor(v, 1, 64));
            v = fmaxf(v, __shfl_xor(v, 2, 64));
            v = fmaxf(v, __shfl_xor(v, 4, 64));
            v = fmaxf(v, __shfl_xor(v, 8, 64));
            mx[m][r] = v;
        }
#pragma unroll
    for (int m = 0; m < 2; m++)
#pragma unroll
        for (int n = 0; n < 8; n++)
#pragma unroll
            for (int r = 0; r < 4; r++)
                acc[m][n][r] = __expf(acc[m][n][r] - mx[m][r]);
#pragma unroll
    for (int m = 0; m < 2; m++)
#pragma unroll
        for (int r = 0; r < 4; r++) {
            float v = 0.f;
#pragma unroll
            for (int n = 0; n < 8; n++) v += acc[m][n][r];
            v += __shfl_xor(v, 1, 64);
            v += __shfl_xor(v, 2, 64);
            v += __shfl_xor(v, 4, 64);
            v += __shfl_xor(v, 8, 64);
            inv[m][r] = 1.0f / v;
        }

    __syncthreads();   // V^T staged

    // ---- PV ----
    f32x4 o[2][2];
    {
        f32x4 z = {0.f, 0.f, 0.f, 0.f};
        o[0][0] = z; o[0][1] = z; o[1][0] = z; o[1][1] = z;
    }
    union B8 { bf16x8 v; uint2 u[2]; };
#pragma unroll
    for (int half = 0; half < 2; half++) {
        asm volatile("s_waitcnt lgkmcnt(0)" ::: "memory");
#pragma unroll
        for (int m = 0; m < 2; m++)
#pragma unroll
            for (int nn = 0; nn < 4; nn++)
#pragma unroll
                for (int r = 0; r < 4; r++)
                    Pl[h][m * 16 + lg * 4 + r][nn * 16 + l15]
                        = f2bf(acc[m][half * 4 + nn][r]);
        asm volatile("s_waitcnt lgkmcnt(0)" ::: "memory");
#pragma unroll
        for (int ks2 = 0; ks2 < 2; ks2++) {
            const int jo = ks2 * 32 + lg * 8;
            const int jg = half * 64 + jo;
            B8 pa0, pa1, vb0, vb1;
            pa0.u[0] = *(const uint2*)&Pl[h][l15][jo];
            pa0.u[1] = *(const uint2*)&Pl[h][l15][jo + 4];
            pa1.u[0] = *(const uint2*)&Pl[h][l15 + 16][jo];
            pa1.u[1] = *(const uint2*)&Pl[h][l15 + 16][jo + 4];
            vb0.u[0] = *(const uint2*)&VT[h * DH + l15][jg];
            vb0.u[1] = *(const uint2*)&VT[h * DH + l15][jg + 4];
            vb1.u[0] = *(const uint2*)&VT[h * DH + 16 + l15][jg];
            vb1.u[1] = *(const uint2*)&VT[h * DH + 16 + l15][jg + 4];
            o[0][0] = __builtin_amdgcn_mfma_f32_16x16x32_bf16(pa0.v, vb0.v, o[0][0], 0, 0, 0);
            o[0][1] = __builtin_amdgcn_mfma_f32_16x16x32_bf16(pa0.v, vb1.v, o[0][1], 0, 0, 0);
            o[1][0] = __builtin_amdgcn_mfma_f32_16x16x32_bf16(pa1.v, vb0.v, o[1][0], 0, 0, 0);
            o[1][1] = __builtin_amdgcn_mfma_f32_16x16x32_bf16(pa1.v, vb1.v, o[1][1], 0, 0, 0);
        }
    }

#pragma unroll
    for (int m = 0; m < 2; m++)
#pragma unroll
        for (int n = 0; n < 2; n++)
#pragma unroll
            for (int r = 0; r < 4; r++)
                og[((long long)b * NATOM + row0 + m * 16 + lg * 4 + r) * CA
                   + h * DH + n * 16 + l15]
                    = f2bf(o[m][n][r] * inv[m][r]);
}

// =====================================================================
// Final selector: write d_out as bf16 (flag=1) or f32 (flag=0)
// =====================================================================
__global__ __launch_bounds__(256) void select_kernel(
    const int* __restrict__ flag,
    const u16* __restrict__ outA, const u16* __restrict__ outB,
    void* __restrict__ d_out)
{
    const size_t i = (size_t)blockIdx.x * 256 + threadIdx.x;
    if (*flag) ((u16*)d_out)[i]   = outA[i];
    else       ((float*)d_out)[i] = bf2f(outB[i]);
}

// =====================================================================
// One full pipeline pass, templated on input storage type, gated on flag
// =====================================================================
template<typename TIN>
static void run_pass(void* const* d_in,
                     float* x, u16* h, u16* qb, u16* kb, u16* vb, u16* ob,
                     float* atok, u16* wt, float* tbv, u16* outbuf,
                     const int* flag, int want, hipStream_t stream)
{
    constexpr int NS = (sizeof(TIN) == 2) ? 1 : 2;

    const TIN* a    = (const TIN*)d_in[0];
    const int* idx  = (const int*)d_in[2];
    const TIN* W_a  = (const TIN*)d_in[3];
    const TIN* W_o  = (const TIN*)d_in[4];
    const TIN* Wcl  = (const TIN*)d_in[5];
    const TIN* Wcm  = (const TIN*)d_in[6];
    const TIN* Wm1  = (const TIN*)d_in[7];
    const TIN* Wm2  = (const TIN*)d_in[8];
    const TIN* Wpb  = (const TIN*)d_in[9];
    const TIN* Wq   = (const TIN*)d_in[10];
    const TIN* Wk   = (const TIN*)d_in[11];
    const TIN* Wv   = (const TIN*)d_in[12];
    const TIN* Wo   = (const TIN*)d_in[13];
    const TIN* ln1g = (const TIN*)d_in[14];
    const TIN* ln1b = (const TIN*)d_in[15];
    const TIN* Wt1  = (const TIN*)d_in[16];
    const TIN* Wt2  = (const TIN*)d_in[17];
    const TIN* ln2g = (const TIN*)d_in[18];
    const TIN* ln2b = (const TIN*)d_in[19];

    const size_t NEL = (size_t)BB * NATOM * CA;

    // 0) transpose (+split) all weights into WT workspace
    wtrans_kernel<TIN, NS><<<40, 256, 0, stream>>>(
        flag, want, W_a, Wq, Wk, Wv, Wo, Wt1, Wt2, W_o, wt);

    // 1) token projection [8192 x 384] @ [384 x 128] -> f32 atok
    if constexpr (NS == 1)
        sgemm_bf<1, 3, false, false><<<BB * NTOK / 128, 256, 0, stream>>>(
            flag, want, (const u16*)a, CTOK, wt + WT_WA, wt + WT_WA + 49152,
            CTOK, 128, atok, CA);
    else
        sgemm_f32<2, 3, false, false><<<BB * NTOK / 128, 256, 0, stream>>>(
            flag, want, (const float*)a, CTOK, wt + WT_WA, wt + WT_WA + 49152,
            CTOK, 128, atok, CA);

    gather_kernel<<<(unsigned)(NEL / 256), 256, 0, stream>>>(flag, want, atok, idx, x);
    bias_kernel<TIN><<<1, 512, 0, stream>>>(flag, want, x, Wcl, Wcm, Wm1, Wm2, Wpb, tbv);

    for (int l = 0; l < 3; l++) {
        u16* wl = wt + WT_L0 + (size_t)l * WT_LSZ;
        ln_kernel<TIN><<<BB * NATOM / 4, 256, 0, stream>>>(flag, want, x, ln1g + l * CA, ln1b + l * CA, h);
        qkv_fused<NS><<<256, 512, 0, stream>>>(flag, want, h, wl, qb, kb, vb);
        attn_kernel<<<BB * NWIN, 256, 0, stream>>>(flag, want, qb, kb, vb, tbv, ob);
        sgemm_bf<NS, 1, false, true><<<512, 256, 0, stream>>>(
            flag, want, ob, CA, wl + 98304, wl + 98304 + 16384, CA, 0, x, CA);
        ln_kernel<TIN><<<BB * NATOM / 4, 256, 0, stream>>>(flag, want, x, ln2g + l * CA, ln2b + l * CA, h);
        mlp_fused<NS><<<256, 512, 0, stream>>>(flag, want, h, wl + 131072, wl + 262144, x);
    }
    // out = x @ W_out -> bf16 outbuf (A is f32 residual: in-kernel split)
    sgemm_f32<NS, 1, true, false><<<512, 256, 0, stream>>>(
        flag, want, x, CA, wt + WT_WO, wt + WT_WO + 16384, CA, 0, outbuf, CA);
}

// =====================================================================
// Launch
// =====================================================================
extern "C" void kernel_launch(void* const* d_in, const int* in_sizes, int n_in,
                              void* d_out, int out_size, void* d_ws, size_t ws_size,
                              hipStream_t stream)
{
    (void)in_sizes; (void)n_in; (void)out_size;
    const size_t NEL = (size_t)BB * NATOM * CA;   // 8388608

    char* p = (char*)d_ws;
    float* x    = (float*)p;  p += NEL * 4;
    u16*   h    = (u16*)p;    p += NEL * 2;
    u16*   qb   = (u16*)p;    p += NEL * 2;
    u16*   kb   = (u16*)p;    p += NEL * 2;
    u16*   vb   = (u16*)p;    p += NEL * 2;
    u16*   ob   = (u16*)p;    p += NEL * 2;
    float* atok = (float*)p;  p += (size_t)BB * NTOK * CA * 4;
    float* tbv  = (float*)p;  p += 8192;
    u16*   outA = (u16*)p;    p += NEL * 2;
    u16*   outB = (u16*)p;    p += NEL * 2;
    int*   flag = (int*)p;    p += 256;
    u16*   wt   = (u16*)p;    p += (size_t)WT_TOT * 2;
    if ((size_t)(p - (char*)d_ws) > ws_size) return;  // workspace too small

    // 1) detect input storage dtype (writes flag: 1=bf16, 0=f32)
    detect_kernel<<<1, 256, 0, stream>>>((const u32*)d_in[3], flag);
    // 2) bf16-interpretation pass (runs only if flag==1)
    run_pass<u16>(d_in, x, h, qb, kb, vb, ob, atok, wt, tbv, outA, flag, 1, stream);
    // 3) f32-interpretation pass (runs only if flag==0)
    run_pass<float>(d_in, x, h, qb, kb, vb, ob, atok, wt, tbv, outB, flag, 0, stream);
    // 4) write d_out in the detected output format
    select_kernel<<<(unsigned)(NEL / 256), 256, 0, stream>>>(flag, outA, outB, d_out);
}

// Round 8
// 565.228 us; speedup vs baseline: 2.9555x; 1.2297x over previous
//
#include <hip/hip_runtime.h>

typedef unsigned short u16;
typedef unsigned int   u32;

typedef __attribute__((ext_vector_type(8))) __bf16 bf16x8;
typedef __attribute__((ext_vector_type(4))) float  f32x4;

// ---------- scalar/vec conversion helpers ----------
__device__ __forceinline__ float bf2f(u16 v) {
    return __uint_as_float(((u32)v) << 16);
}
__device__ __forceinline__ u16 f2bf(float f) {
    u32 u = __float_as_uint(f);
    u32 r = (u + 0x7fffu + ((u >> 16) & 1u)) >> 16;  // round-to-nearest-even
    return (u16)r;
}
__device__ __forceinline__ float ld1(const u16* p)   { return bf2f(*p); }
__device__ __forceinline__ float ld1(const float* p) { return *p; }

// ---------- problem constants ----------
#define BB 4
#define NTOK 2048
#define NATOM 16384
#define CTOK 384
#define CA 128
#define NQ 32
#define NK 128
#define NH 4
#define DH 32
#define NWIN 512
#define PAD 48

// Transposed-weight workspace layout (u16 elements).
// Each matrix stored as [N][K] hi-plane, then lo-plane (lo = 0 for bf16 input).
#define WT_WA   0          // [128][384], lo plane at +49152
#define WT_L0   98304      // per-layer block start
#define WT_LSZ  393216     // Q 0 | K 32768 | V 65536 | O 98304 | T1 131072 | T2 262144
#define WT_WO   1277952    // [128][128], lo plane at +16384
#define WT_TOT  1310720

// Aux f32 scratch layout (floats)
#define AX_WCL  0
#define AX_WCM  2048
#define AX_WM1  4096
#define AX_WM2  4352
#define AX_WPB  4608
#define AX_L1G  4672
#define AX_L1B  5056
#define AX_L2G  5440
#define AX_L2B  5824
#define AX_TOT  6208

// =====================================================================
// dtype detector: look at low u16 of 1024 words of W_a.
// flag = 1 (bf16 inputs) or 0 (f32 inputs)
// =====================================================================
__global__ __launch_bounds__(256) void detect_kernel(const u32* __restrict__ wa,
                                                     int* __restrict__ flag)
{
    __shared__ int cnt;
    if (threadIdx.x == 0) cnt = 0;
    __syncthreads();
    int local = 0;
#pragma unroll
    for (int i = 0; i < 4; i++) {
        u32 w = wa[threadIdx.x * 4 + i];
        u32 e = (w >> 7) & 0xFFu;   // exponent field of the LOW u16 as bf16
        if (e >= 95u && e <= 135u) local++;
    }
    atomicAdd(&cnt, local);
    __syncthreads();
    if (threadIdx.x == 0) *flag = (cnt >= 614) ? 1 : 0;
}

// =====================================================================
// Weight transpose + bf16 hi/lo split into WT workspace, plus f32 aux
// conversion.  41 blocks: Wa(3) | Wq/k/v/o x3 (12) | Wt1 (12) | Wt2 (12)
// | Wout(1) | aux(1).  dst[n][k] = src[k][n]; hi = bf16(w),
// lo = bf16(w - hi) (lo = 0 for bf16 input).  Gated on dtype flag.
// =====================================================================
template<typename TIN>
__global__ __launch_bounds__(256) void wtrans_kernel(
    const int* __restrict__ flag, int want,
    const TIN* __restrict__ Wa, const TIN* __restrict__ Wq,
    const TIN* __restrict__ Wk, const TIN* __restrict__ Wv,
    const TIN* __restrict__ Wo, const TIN* __restrict__ Wt1,
    const TIN* __restrict__ Wt2, const TIN* __restrict__ Wout,
    const TIN* __restrict__ Wcl, const TIN* __restrict__ Wcm,
    const TIN* __restrict__ Wm1, const TIN* __restrict__ Wm2,
    const TIN* __restrict__ Wpb, const TIN* __restrict__ l1g,
    const TIN* __restrict__ l1b, const TIN* __restrict__ l2g,
    const TIN* __restrict__ l2b,
    u16* __restrict__ WT, float* __restrict__ AX)
{
    if (*flag != want) return;
    const int t = blockIdx.x;
    const int tid = threadIdx.x;
    if (t == 40) {   // aux f32 conversion
        for (int i = tid; i < 2048; i += 256) AX[AX_WCL + i] = ld1(Wcl + i);
        for (int i = tid; i < 2048; i += 256) AX[AX_WCM + i] = ld1(Wcm + i);
        AX[AX_WM1 + tid] = ld1(Wm1 + tid);
        AX[AX_WM2 + tid] = ld1(Wm2 + tid);
        if (tid < 64) AX[AX_WPB + tid] = ld1(Wpb + tid);
        for (int i = tid; i < 384; i += 256) {
            AX[AX_L1G + i] = ld1(l1g + i);
            AX[AX_L1B + i] = ld1(l1b + i);
            AX[AX_L2G + i] = ld1(l2g + i);
            AX[AX_L2B + i] = ld1(l2b + i);
        }
        return;
    }
    const TIN* S; int sld; u16* D; int dld; int plane;
    if (t < 3) {                                     // W_a [384][128]
        S = Wa + t * 128 * 128; sld = 128;
        D = WT + WT_WA + t * 128; dld = 384; plane = 49152;
    } else if (t < 15) {                             // Wq/k/v/o [128][128]
        const int i = t - 3, l = i >> 2, m = i & 3;
        const TIN* ms = (m == 0) ? Wq : (m == 1) ? Wk : (m == 2) ? Wv : Wo;
        S = ms + l * 16384; sld = 128;
        D = WT + WT_L0 + l * WT_LSZ + m * 32768; dld = 128; plane = 16384;
    } else if (t < 27) {                             // Wt1 [128][512] col-chunk c
        const int i = t - 15, l = i >> 2, c = i & 3;
        S = Wt1 + l * 65536 + c * 128; sld = 512;
        D = WT + WT_L0 + l * WT_LSZ + 131072 + c * 128 * 128; dld = 128; plane = 65536;
    } else if (t < 39) {                             // Wt2 [512][128] row-chunk c
        const int i = t - 27, l = i >> 2, c = i & 3;
        S = Wt2 + l * 65536 + c * 128 * 128; sld = 128;
        D = WT + WT_L0 + l * WT_LSZ + 262144 + c * 128; dld = 512; plane = 65536;
    } else {                                         // W_out [128][128]
        S = Wout; sld = 128;
        D = WT + WT_WO; dld = 128; plane = 16384;
    }
    for (int id = tid; id < 2048; id += 256) {
        const int n = id >> 4, k0 = (id & 15) << 3;
        union { u16 s[8]; uint4 v; } hi, lo;
#pragma unroll
        for (int j = 0; j < 8; j++) {
            if constexpr (sizeof(TIN) == 2) {
                hi.s[j] = ((const u16*)(const void*)S)[(k0 + j) * sld + n];
                lo.s[j] = 0;
            } else {
                const float v = ((const float*)(const void*)S)[(k0 + j) * sld + n];
                const u16 hv = f2bf(v);
                hi.s[j] = hv;
                lo.s[j] = f2bf(v - bf2f(hv));
            }
        }
        *(uint4*)(D + n * dld + k0) = hi.v;
        *(uint4*)(D + plane + n * dld + k0) = lo.v;
    }
}

// =====================================================================
// Async weight-panel staging via global_load_lds (no staging VGPRs).
// LDS image: [plane][128 rows][256 B] LINEAR in segment order; the XOR
// swizzle byte^((row&7)<<4) is applied to the per-lane GLOBAL source
// (inverse-swz source + swz read = both-sides rule).
// =====================================================================
__device__ __forceinline__ void gld16(const void* g, void* l)
{
    __builtin_amdgcn_global_load_lds(
        (const __attribute__((address_space(1))) void*)g,
        (__attribute__((address_space(3))) void*)l, 16, 0, 0);
}

template<int NS, int NTHR>
__device__ __forceinline__ void stage_async(u16* lds, const u16* srcHi,
                                            const u16* srcLo, int strideU16, int tid)
{
    constexpr int NWAVE = NTHR / 64;
    constexpr int NSEG  = NS * 32768 / (NWAVE * 1024);
    const int lane = tid & 63;
    const int wv   = tid >> 6;
#pragma unroll
    for (int i = 0; i < NSEG; i++) {
        const int segoff  = (wv * NSEG + i) << 10;      // byte, wave-uniform
        const int po_full = segoff + lane * 16;
        const int plane   = po_full >> 15;
        const int po      = po_full & 32767;
        const int row     = po >> 8;
        const int colB    = (po & 255) ^ ((row & 7) << 4);
        const u16* g = (plane ? srcLo : srcHi) + row * strideU16 + (colB >> 1);
        gld16(g, (char*)lds + segoff);
    }
}

__device__ __forceinline__ bf16x8 ld_w(const u16* lds, int plane, int row, int kbyte)
{
    union { uint4 q; bf16x8 v; } u;
    u.q = *(const uint4*)((const char*)lds + plane * 32768 + row * 256
                          + (kbyte ^ ((row & 7) << 4)));
    return u.v;
}

// MFMA over one staged panel: acc[2][8] += a{0,1}[kk] @ W(+lo)
template<int NS>
__device__ __forceinline__ void mfma_panel(const u16* Wbuf, const bf16x8* a0,
                                           const bf16x8* a1, int l15, int lg,
                                           f32x4 acc[][8])
{
#pragma unroll
    for (int kk = 0; kk < 4; kk++)
#pragma unroll
        for (int n = 0; n < 8; n++) {
            const int rw = n * 16 + l15, kb = kk * 64 + lg * 16;
            const bf16x8 b = ld_w(Wbuf, 0, rw, kb);
            acc[0][n] = __builtin_amdgcn_mfma_f32_16x16x32_bf16(a0[kk], b, acc[0][n], 0, 0, 0);
            acc[1][n] = __builtin_amdgcn_mfma_f32_16x16x32_bf16(a1[kk], b, acc[1][n], 0, 0, 0);
            if (NS == 2) {
                const bf16x8 bl = ld_w(Wbuf, 1, rw, kb);
                acc[0][n] = __builtin_amdgcn_mfma_f32_16x16x32_bf16(a0[kk], bl, acc[0][n], 0, 0, 0);
                acc[1][n] = __builtin_amdgcn_mfma_f32_16x16x32_bf16(a1[kk], bl, acc[1][n], 0, 0, 0);
            }
        }
}

// Split-A variant: acc += ah@W + al@W (+ ah@Wlo when NS==2)
template<int NS>
__device__ __forceinline__ void mfma_panel_split(const u16* Wbuf,
    const bf16x8* a0h, const bf16x8* a0l, const bf16x8* a1h, const bf16x8* a1l,
    int l15, int lg, f32x4 acc[][8])
{
#pragma unroll
    for (int kk = 0; kk < 4; kk++)
#pragma unroll
        for (int n = 0; n < 8; n++) {
            const int rw = n * 16 + l15, kb = kk * 64 + lg * 16;
            const bf16x8 b = ld_w(Wbuf, 0, rw, kb);
            acc[0][n] = __builtin_amdgcn_mfma_f32_16x16x32_bf16(a0h[kk], b, acc[0][n], 0, 0, 0);
            acc[0][n] = __builtin_amdgcn_mfma_f32_16x16x32_bf16(a0l[kk], b, acc[0][n], 0, 0, 0);
            acc[1][n] = __builtin_amdgcn_mfma_f32_16x16x32_bf16(a1h[kk], b, acc[1][n], 0, 0, 0);
            acc[1][n] = __builtin_amdgcn_mfma_f32_16x16x32_bf16(a1l[kk], b, acc[1][n], 0, 0, 0);
            if (NS == 2) {
                const bf16x8 bl = ld_w(Wbuf, 1, rw, kb);
                acc[0][n] = __builtin_amdgcn_mfma_f32_16x16x32_bf16(a0h[kk], bl, acc[0][n], 0, 0, 0);
                acc[1][n] = __builtin_amdgcn_mfma_f32_16x16x32_bf16(a1h[kk], bl, acc[1][n], 0, 0, 0);
            }
        }
}

__device__ __forceinline__ void splitf8(const float* p, bf16x8* hi, bf16x8* lo)
{
    const float4 f0 = *(const float4*)p;
    const float4 f1 = *(const float4*)(p + 4);
    const float f[8] = {f0.x, f0.y, f0.z, f0.w, f1.x, f1.y, f1.z, f1.w};
    union { u16 s[8]; bf16x8 v; } H, L;
#pragma unroll
    for (int j = 0; j < 8; j++) {
        const u16 hv = f2bf(f[j]);
        H.s[j] = hv;
        L.s[j] = f2bf(f[j] - bf2f(hv));
    }
    *hi = H.v; *lo = L.v;
}

// =====================================================================
// Staged-weight MFMA GEMM (bf16 A): C[M x 128] = A[M x K] @ W.
// 128-row blocks, 256 threads, 4 waves x 32 rows, 2 blocks/CU.
// want < 0: always run; else gated on dtype flag.
// =====================================================================
template<int NS, int KCH, bool OUT_BF16, bool ADD>
__global__ __launch_bounds__(256, 2) void sgemm_bf(
    const int* __restrict__ flag, int want,
    const u16* __restrict__ A, int lda,
    const u16* __restrict__ WHi, const u16* __restrict__ WLo,
    int wstride, int wcstep,
    void* __restrict__ Cv, int ldc)
{
    if (want >= 0 && *flag != want) return;
    __shared__ __align__(16) u16 Wbuf[NS * 16384];
    const int tid = threadIdx.x;
    const int lane = tid & 63, wv = tid >> 6;
    const int l15 = lane & 15, lg = lane >> 4;
    const long long row0 = (long long)blockIdx.x * 128 + wv * 32;

    f32x4 acc[2][8];
    {
        f32x4 z = {0.f, 0.f, 0.f, 0.f};
#pragma unroll
        for (int m = 0; m < 2; m++)
#pragma unroll
            for (int n = 0; n < 8; n++) acc[m][n] = z;
    }

    const u16* A0 = A + (row0 + l15) * (long long)lda + lg * 8;
    const u16* A1 = A0 + 16LL * lda;

    stage_async<NS, 256>(Wbuf, WHi, WLo, wstride, tid);
    for (int ks = 0; ks < KCH; ks++) {
        bf16x8 a0[4], a1[4];
#pragma unroll
        for (int kk = 0; kk < 4; kk++) {
            a0[kk] = *(const bf16x8*)(A0 + ks * 128 + kk * 32);
            a1[kk] = *(const bf16x8*)(A1 + ks * 128 + kk * 32);
        }
        __syncthreads();                       // panel staged (vmcnt drained)
        mfma_panel<NS>(Wbuf, a0, a1, l15, lg, acc);
        if (ks + 1 < KCH) {
            __syncthreads();                   // panel reads done before restage
            stage_async<NS, 256>(Wbuf, WHi + (ks + 1) * wcstep,
                                 WLo + (ks + 1) * wcstep, wstride, tid);
        }
    }

#pragma unroll
    for (int m = 0; m < 2; m++)
#pragma unroll
        for (int r = 0; r < 4; r++) {
            const long long row = row0 + m * 16 + lg * 4 + r;
            if (OUT_BF16) {
                u16* C = (u16*)Cv + row * ldc;
#pragma unroll
                for (int n = 0; n < 8; n++) C[n * 16 + l15] = f2bf(acc[m][n][r]);
            } else {
                float* C = (float*)Cv + row * ldc;
#pragma unroll
                for (int n = 0; n < 8; n++) {
                    float v = acc[m][n][r];
                    if (ADD) v += C[n * 16 + l15];
                    C[n * 16 + l15] = v;
                }
            }
        }
}

// =====================================================================
// Staged-weight MFMA GEMM (f32 A, split in-kernel into hi+lo bf16).
// =====================================================================
template<int NS, int KCH, bool OUT_BF16>
__global__ __launch_bounds__(256, 2) void sgemm_f32(
    const int* __restrict__ flag, int want,
    const float* __restrict__ A, int lda,
    const u16* __restrict__ WHi, const u16* __restrict__ WLo,
    int wstride, int wcstep,
    void* __restrict__ Cv, int ldc)
{
    if (want >= 0 && *flag != want) return;
    __shared__ __align__(16) u16 Wbuf[NS * 16384];
    const int tid = threadIdx.x;
    const int lane = tid & 63, wv = tid >> 6;
    const int l15 = lane & 15, lg = lane >> 4;
    const long long row0 = (long long)blockIdx.x * 128 + wv * 32;

    f32x4 acc[2][8];
    {
        f32x4 z = {0.f, 0.f, 0.f, 0.f};
#pragma unroll
        for (int m = 0; m < 2; m++)
#pragma unroll
            for (int n = 0; n < 8; n++) acc[m][n] = z;
    }

    const float* A0 = A + (row0 + l15) * (long long)lda + lg * 8;
    const float* A1 = A0 + 16LL * lda;

    stage_async<NS, 256>(Wbuf, WHi, WLo, wstride, tid);
    for (int ks = 0; ks < KCH; ks++) {
        bf16x8 a0h[4], a0l[4], a1h[4], a1l[4];
#pragma unroll
        for (int kk = 0; kk < 4; kk++) {
            splitf8(A0 + ks * 128 + kk * 32, &a0h[kk], &a0l[kk]);
            splitf8(A1 + ks * 128 + kk * 32, &a1h[kk], &a1l[kk]);
        }
        __syncthreads();
        mfma_panel_split<NS>(Wbuf, a0h, a0l, a1h, a1l, l15, lg, acc);
        if (ks + 1 < KCH) {
            __syncthreads();
            stage_async<NS, 256>(Wbuf, WHi + (ks + 1) * wcstep,
                                 WLo + (ks + 1) * wcstep, wstride, tid);
        }
    }

#pragma unroll
    for (int m = 0; m < 2; m++)
#pragma unroll
        for (int r = 0; r < 4; r++) {
            const long long row = row0 + m * 16 + lg * 4 + r;
            if (OUT_BF16) {
                u16* C = (u16*)Cv + row * ldc;
#pragma unroll
                for (int n = 0; n < 8; n++) C[n * 16 + l15] = f2bf(acc[m][n][r]);
            } else {
                float* C = (float*)Cv + row * ldc;
#pragma unroll
                for (int n = 0; n < 8; n++) C[n * 16 + l15] = acc[m][n][r];
            }
        }
}

// =====================================================================
// O-projection + residual + fused LN2: x += ob@Wo; h = LN(x)*g+b.
// 128-row blocks, 256 threads; each wave holds full 128-wide rows, so
// LN reduce = 8 local adds + shfl_xor(1,2,4,8) over the l15 group.
// =====================================================================
__global__ __launch_bounds__(256, 2) void sgemm_add_ln(
    const u16* __restrict__ A,
    const u16* __restrict__ WHi, const u16* __restrict__ WLo,
    float* __restrict__ x, const float* __restrict__ g,
    const float* __restrict__ bvec, u16* __restrict__ h)
{
    __shared__ __align__(16) u16 Wbuf[2 * 16384];
    const int tid = threadIdx.x;
    const int lane = tid & 63, wv = tid >> 6;
    const int l15 = lane & 15, lg = lane >> 4;
    const long long row0 = (long long)blockIdx.x * 128 + wv * 32;

    f32x4 acc[2][8];
    {
        f32x4 z = {0.f, 0.f, 0.f, 0.f};
#pragma unroll
        for (int m = 0; m < 2; m++)
#pragma unroll
            for (int n = 0; n < 8; n++) acc[m][n] = z;
    }

    const u16* A0 = A + (row0 + l15) * 128LL + lg * 8;
    const u16* A1 = A0 + 16LL * 128;

    stage_async<2, 256>(Wbuf, WHi, WLo, 128, tid);
    bf16x8 a0[4], a1[4];
#pragma unroll
    for (int kk = 0; kk < 4; kk++) {
        a0[kk] = *(const bf16x8*)(A0 + kk * 32);
        a1[kk] = *(const bf16x8*)(A1 + kk * 32);
    }
    __syncthreads();
    mfma_panel<2>(Wbuf, a0, a1, l15, lg, acc);

    float gv[8], bv[8];
#pragma unroll
    for (int n = 0; n < 8; n++) { gv[n] = g[n * 16 + l15]; bv[n] = bvec[n * 16 + l15]; }

#pragma unroll
    for (int m = 0; m < 2; m++)
#pragma unroll
        for (int r = 0; r < 4; r++) {
            const long long row = row0 + m * 16 + lg * 4 + r;
            float* X = x + row * CA;
            float v[8]; float s = 0.f, sq = 0.f;
#pragma unroll
            for (int n = 0; n < 8; n++) {
                v[n] = X[n * 16 + l15] + acc[m][n][r];
                X[n * 16 + l15] = v[n];
                s += v[n]; sq += v[n] * v[n];
            }
            s  += __shfl_xor(s, 1, 64);  s  += __shfl_xor(s, 2, 64);
            s  += __shfl_xor(s, 4, 64);  s  += __shfl_xor(s, 8, 64);
            sq += __shfl_xor(sq, 1, 64); sq += __shfl_xor(sq, 2, 64);
            sq += __shfl_xor(sq, 4, 64); sq += __shfl_xor(sq, 8, 64);
            const float mean = s * 0.0078125f;
            const float var  = sq * 0.0078125f - mean * mean;
            const float inv  = rsqrtf(var + 1e-5f);
            u16* H = h + row * CA;
#pragma unroll
            for (int n = 0; n < 8; n++)
                H[n * 16 + l15] = f2bf((v[n] - mean) * inv * gv[n] + bv[n]);
        }
}

// =====================================================================
// Fused QKV (512 thr, 256 rows/block): ping-pong two panel buffers;
// next panel's async loads issue before this panel's MFMA.
// =====================================================================
__global__ __launch_bounds__(512, 1) void qkv_fused(
    const u16* __restrict__ h, const u16* __restrict__ wl,
    u16* __restrict__ qb, u16* __restrict__ kb, u16* __restrict__ vb)
{
    __shared__ __align__(16) u16 bufA[2 * 16384];
    __shared__ __align__(16) u16 bufB[2 * 16384];
    const int tid = threadIdx.x;
    const int lane = tid & 63, wv = tid >> 6;
    const int l15 = lane & 15, lg = lane >> 4;
    const long long row0 = (long long)blockIdx.x * 256 + wv * 32;

    bf16x8 a0[4], a1[4];
#pragma unroll
    for (int kk = 0; kk < 4; kk++) {
        a0[kk] = *(const bf16x8*)(h + (row0 + l15) * 128 + kk * 32 + lg * 8);
        a1[kk] = *(const bf16x8*)(h + (row0 + 16 + l15) * 128 + kk * 32 + lg * 8);
    }

    stage_async<2, 512>(bufA, wl, wl + 16384, 128, tid);          // Q
    __syncthreads();

#pragma unroll
    for (int m = 0; m < 3; m++) {
        if (m < 2)   // prefetch next panel
            stage_async<2, 512>((m == 0) ? bufB : bufA,
                                wl + (m + 1) * 32768,
                                wl + (m + 1) * 32768 + 16384, 128, tid);
        f32x4 acc[2][8];
        {
            f32x4 z = {0.f, 0.f, 0.f, 0.f};
#pragma unroll
            for (int i = 0; i < 2; i++)
#pragma unroll
                for (int n = 0; n < 8; n++) acc[i][n] = z;
        }
        const u16* cur = (m == 1) ? bufB : bufA;   // Q:A, K:B, V:A
        mfma_panel<2>(cur, a0, a1, l15, lg, acc);
        u16* out = (m == 0) ? qb : (m == 1) ? kb : vb;
#pragma unroll
        for (int i = 0; i < 2; i++)
#pragma unroll
            for (int r = 0; r < 4; r++) {
                u16* C = out + (row0 + i * 16 + lg * 4 + r) * CA;
#pragma unroll
                for (int n = 0; n < 8; n++) C[n * 16 + l15] = f2bf(acc[i][n][r]);
            }
        if (m < 2) __syncthreads();   // drains prefetch; cur reads done
    }
}

// =====================================================================
// Fused MLP + residual + next-layer LN1 (512 thr, 256 rows/block):
// x += relu(h @ Wt1) @ Wt2; h_out = LN(x)*g+b (EMIT_H).
// Two weight buffers, async staging; hidden transpose via per-wave
// 32x80B quarter buffer (wave-local waits). LDS 148 KB.
// =====================================================================
template<bool EMIT_H>
__global__ __launch_bounds__(512, 1) void mlp_ln(
    const u16* __restrict__ h,
    const u16* __restrict__ W1T, const u16* __restrict__ W2T,
    float* __restrict__ x, const float* __restrict__ g,
    const float* __restrict__ bvec, u16* __restrict__ hout)
{
    __shared__ __align__(16) u16 W1buf[2 * 16384];
    __shared__ __align__(16) u16 W2buf[2 * 16384];
    __shared__ __align__(16) u16 Plq[8][32][40];   // per-wave 32 rows x 80 B
    const int tid = threadIdx.x;
    const int lane = tid & 63, wv = tid >> 6;
    const int l15 = lane & 15, lg = lane >> 4;
    const long long row0 = (long long)blockIdx.x * 256 + wv * 32;
    u16* pw = &Plq[wv][0][0];

    bf16x8 ah0[4], ah1[4];
#pragma unroll
    for (int kk = 0; kk < 4; kk++) {
        ah0[kk] = *(const bf16x8*)(h + (row0 + l15) * 128 + kk * 32 + lg * 8);
        ah1[kk] = *(const bf16x8*)(h + (row0 + 16 + l15) * 128 + kk * 32 + lg * 8);
    }

    f32x4 xacc[2][8];
    {
        f32x4 z = {0.f, 0.f, 0.f, 0.f};
#pragma unroll
        for (int m = 0; m < 2; m++)
#pragma unroll
            for (int n = 0; n < 8; n++) xacc[m][n] = z;
    }

    stage_async<2, 512>(W1buf, W1T, W1T + 65536, 128, tid);
    __syncthreads();

    for (int c = 0; c < 4; c++) {
        // ---- W1 phase: issue W2c loads, MFMA W1 under them ----
        stage_async<2, 512>(W2buf, W2T + c * 128, W2T + 65536 + c * 128, 512, tid);
        f32x4 hacc[2][8];
        {
            f32x4 z = {0.f, 0.f, 0.f, 0.f};
#pragma unroll
            for (int m = 0; m < 2; m++)
#pragma unroll
                for (int n = 0; n < 8; n++) hacc[m][n] = z;
        }
        mfma_panel<2>(W1buf, ah0, ah1, l15, lg, hacc);
        __syncthreads();                 // W2buf staged; all waves done W1 reads

        // ---- W2 phase: issue W1(c+1) loads, quarters + MFMA W2 ----
        if (c < 3)
            stage_async<2, 512>(W1buf, W1T + (c + 1) * 16384,
                                W1T + 65536 + (c + 1) * 16384, 128, tid);
#pragma unroll
        for (int q = 0; q < 4; q++) {
            asm volatile("s_waitcnt lgkmcnt(0)" ::: "memory");
#pragma unroll
            for (int m = 0; m < 2; m++)
#pragma unroll
                for (int j = 0; j < 2; j++)
#pragma unroll
                    for (int r = 0; r < 4; r++)
                        pw[(m * 16 + lg * 4 + r) * 40 + j * 16 + l15]
                            = f2bf(fmaxf(hacc[m][2 * q + j][r], 0.f));
            asm volatile("s_waitcnt lgkmcnt(0)" ::: "memory");
            union { uint4 v; bf16x8 b; } t0, t1;
            t0.v = *(const uint4*)(pw + l15 * 40 + lg * 8);
            t1.v = *(const uint4*)(pw + (16 + l15) * 40 + lg * 8);
#pragma unroll
            for (int n = 0; n < 8; n++) {
                const int rw = n * 16 + l15, kb = q * 64 + lg * 16;
                const bf16x8 b = ld_w(W2buf, 0, rw, kb);
                xacc[0][n] = __builtin_amdgcn_mfma_f32_16x16x32_bf16(t0.b, b, xacc[0][n], 0, 0, 0);
                xacc[1][n] = __builtin_amdgcn_mfma_f32_16x16x32_bf16(t1.b, b, xacc[1][n], 0, 0, 0);
                const bf16x8 bl = ld_w(W2buf, 1, rw, kb);
                xacc[0][n] = __builtin_amdgcn_mfma_f32_16x16x32_bf16(t0.b, bl, xacc[0][n], 0, 0, 0);
                xacc[1][n] = __builtin_amdgcn_mfma_f32_16x16x32_bf16(t1.b, bl, xacc[1][n], 0, 0, 0);
            }
        }
        if (c < 3) __syncthreads();      // W1buf(c+1) staged; W2buf reads done
    }

    float gv[8], bv[8];
    if (EMIT_H) {
#pragma unroll
        for (int n = 0; n < 8; n++) { gv[n] = g[n * 16 + l15]; bv[n] = bvec[n * 16 + l15]; }
    }

#pragma unroll
    for (int m = 0; m < 2; m++)
#pragma unroll
        for (int r = 0; r < 4; r++) {
            const long long row = row0 + m * 16 + lg * 4 + r;
            float* X = x + row * CA;
            float v[8]; float s = 0.f, sq = 0.f;
#pragma unroll
            for (int n = 0; n < 8; n++) {
                v[n] = X[n * 16 + l15] + xacc[m][n][r];
                X[n * 16 + l15] = v[n];
                s += v[n]; sq += v[n] * v[n];
            }
            if (EMIT_H) {
                s  += __shfl_xor(s, 1, 64);  s  += __shfl_xor(s, 2, 64);
                s  += __shfl_xor(s, 4, 64);  s  += __shfl_xor(s, 8, 64);
                sq += __shfl_xor(sq, 1, 64); sq += __shfl_xor(sq, 2, 64);
                sq += __shfl_xor(sq, 4, 64); sq += __shfl_xor(sq, 8, 64);
                const float mean = s * 0.0078125f;
                const float var  = sq * 0.0078125f - mean * mean;
                const float inv  = rsqrtf(var + 1e-5f);
                u16* H = hout + row * CA;
#pragma unroll
                for (int n = 0; n < 8; n++)
                    H[n * 16 + l15] = f2bf((v[n] - mean) * inv * gv[n] + bv[n]);
            }
        }
}

// =====================================================================
// Gather + LN1 of layer 0: one wave per atom row.
// x[b,n,:] = a_tok[b, idx[b,n], :]; h = LN(x)*g+b.
// =====================================================================
__global__ __launch_bounds__(256) void gather_ln_kernel(
    const float* __restrict__ atok, const int* __restrict__ idx,
    const float* __restrict__ g, const float* __restrict__ bvec,
    float* __restrict__ x, u16* __restrict__ h)
{
    const int lane = threadIdx.x & 63;
    const int wv   = threadIdx.x >> 6;
    const size_t an = (size_t)blockIdx.x * 4 + wv;
    const int b = (int)(an >> 14);
    const int n = (int)(an & (NATOM - 1));
    const int t = idx[b * NATOM + n];
    const float* src = atok + ((size_t)b * NTOK + t) * CA;
    const float v0 = src[lane], v1 = src[lane + 64];
    float* xr = x + an * CA;
    xr[lane] = v0; xr[lane + 64] = v1;
    float s  = v0 + v1;
    float sq = v0 * v0 + v1 * v1;
#pragma unroll
    for (int off = 32; off > 0; off >>= 1) {
        s  += __shfl_xor(s,  off, 64);
        sq += __shfl_xor(sq, off, 64);
    }
    const float mean = s * 0.0078125f;
    const float var  = sq * 0.0078125f - mean * mean;
    const float inv  = rsqrtf(var + 1e-5f);
    u16* hr = h + an * CA;
    hr[lane]      = f2bf((v0 - mean) * inv * g[lane]      + bvec[lane]);
    hr[lane + 64] = f2bf((v1 - mean) * inv * g[lane + 64] + bvec[lane + 64]);
}

// =====================================================================
// Bias: t[b,a,h] for a < 128 from the pair-MLP (f32 aux weights).
// =====================================================================
__global__ __launch_bounds__(512) void bias_kernel(
    const float* __restrict__ x, const float* __restrict__ AX,
    float* __restrict__ tb)
{
    __shared__ float Wsum[128][16];
    __shared__ float M1[16][16];
    __shared__ float M2[16][16];
    __shared__ float Pb[16][4];
    const int tid = threadIdx.x;
    for (int i = tid; i < 128 * 16; i += 512)
        Wsum[i >> 4][i & 15] = AX[AX_WCL + i] + AX[AX_WCM + i];
    if (tid < 256) M1[tid >> 4][tid & 15] = AX[AX_WM1 + tid];
    if (tid >= 256 && tid < 512) { int t2 = tid - 256; M2[t2 >> 4][t2 & 15] = AX[AX_WM2 + t2]; }
    if (tid < 64) Pb[tid >> 2][tid & 3] = AX[AX_WPB + tid];
    __syncthreads();

    const int b = tid >> 7, a = tid & 127;
    const float* xa = x + ((size_t)b * NATOM + a) * CA;
    float u[16];
#pragma unroll
    for (int p = 0; p < 16; p++) u[p] = 0.f;
    for (int c = 0; c < 128; c++) {
        const float xv = xa[c];
#pragma unroll
        for (int p = 0; p < 16; p++) u[p] = fmaf(xv, Wsum[c][p], u[p]);
    }
    float r1[16];
#pragma unroll
    for (int p = 0; p < 16; p++) r1[p] = 0.f;
    for (int c = 0; c < 16; c++) {
        const float rv = fmaxf(u[c], 0.f);
#pragma unroll
        for (int p = 0; p < 16; p++) r1[p] = fmaf(rv, M1[c][p], r1[p]);
    }
    float r2[16];
#pragma unroll
    for (int p = 0; p < 16; p++) r2[p] = 0.f;
    for (int c = 0; c < 16; c++) {
        const float rv = fmaxf(r1[c], 0.f);
#pragma unroll
        for (int p = 0; p < 16; p++) r2[p] = fmaf(rv, M2[c][p], r2[p]);
    }
#pragma unroll
    for (int hh = 0; hh < 4; hh++) {
        float s = 0.f;
#pragma unroll
        for (int p = 0; p < 16; p++) s = fmaf(r2[p], Pb[p][hh], s);
        tb[(size_t)tid * 4 + hh] = s;
    }
}

// =====================================================================
// Windowed attention via MFMA (verified round 1): one block per (b, w).
// =====================================================================
#define VTP 132   // V^T row stride in u16
#define PPS 68    // P row stride in u16

__global__ __launch_bounds__(256) void attn_kernel(
    const u16* __restrict__ qg, const u16* __restrict__ kg,
    const u16* __restrict__ vg, const float* __restrict__ tb,
    u16* __restrict__ og)
{
    __shared__ __align__(16) u16 VT[128][VTP];    // V^T: [d][j]
    __shared__ __align__(16) u16 Pl[NH][32][PPS]; // per-head P half

    const int tid  = threadIdx.x;
    const int lane = tid & 63;
    const int h    = tid >> 6;             // wave id == head
    const int b    = blockIdx.x >> 9;
    const int w    = blockIdx.x & (NWIN - 1);
    const int row0 = w * NQ;
    const int kbase = row0 - PAD;          // first key atom (may be < 0)
    const int l15 = lane & 15;
    const int lg  = lane >> 4;

    // ---- stage V^T into LDS (all 256 threads; zero invalid rows) ----
    {
        const int j  = tid & 127;
        const int d0 = (tid >> 7) << 6;    // 0 or 64
        const int ga = kbase + j;
        const bool val = (ga >= 0) && (ga < NATOM);
        const u16* vrow = vg + ((long long)b * NATOM + ga) * CA + d0;
#pragma unroll
        for (int t2 = 0; t2 < 8; t2++) {
            union { uint4 q; u16 s[8]; } u;
            if (val) u.q = *(const uint4*)(vrow + t2 * 8);
            else     u.q = make_uint4(0u, 0u, 0u, 0u);
#pragma unroll
            for (int e = 0; e < 8; e++) VT[d0 + t2 * 8 + e][j] = u.s[e];
        }
    }

    // ---- QK^T: S[32][128] per head, frags direct from global ----
    const long long qoff = ((long long)b * NATOM + row0) * CA + h * DH;
    const long long koff = ((long long)b * NATOM + kbase) * CA + h * DH;
    bf16x8 aq0 = *(const bf16x8*)(qg + qoff + (long long)l15 * CA + lg * 8);
    bf16x8 aq1 = *(const bf16x8*)(qg + qoff + (long long)(l15 + 16) * CA + lg * 8);

    f32x4 acc[2][8];
    {
        f32x4 z = {0.f, 0.f, 0.f, 0.f};
#pragma unroll
        for (int m = 0; m < 2; m++)
#pragma unroll
            for (int n = 0; n < 8; n++) acc[m][n] = z;
    }
#pragma unroll
    for (int n = 0; n < 8; n++) {
        bf16x8 bk = *(const bf16x8*)(kg + koff + (long long)(n * 16 + l15) * CA + lg * 8);
        acc[0][n] = __builtin_amdgcn_mfma_f32_16x16x32_bf16(aq0, bk, acc[0][n], 0, 0, 0);
        acc[1][n] = __builtin_amdgcn_mfma_f32_16x16x32_bf16(aq1, bk, acc[1][n], 0, 0, 0);
    }

    // ---- bias + scale + mask ----
    const float scale = 0.17677669529663687f;  // 1/sqrt(32)
    float tj[8], ti[2][4];
#pragma unroll
    for (int n = 0; n < 8; n++)
        tj[n] = tb[((size_t)b * 128 + n * 16 + l15) * 4 + h];
#pragma unroll
    for (int m = 0; m < 2; m++)
#pragma unroll
        for (int r = 0; r < 4; r++)
            ti[m][r] = tb[((size_t)b * 128 + m * 16 + lg * 4 + r) * 4 + h];

#pragma unroll
    for (int n = 0; n < 8; n++) {
        const int ga = kbase + n * 16 + l15;
        const bool val = (ga >= 0) && (ga < NATOM);
#pragma unroll
        for (int m = 0; m < 2; m++)
#pragma unroll
            for (int r = 0; r < 4; r++) {
                const float s = acc[m][n][r] * scale + ti[m][r] + tj[n];
                acc[m][n][r] = val ? s : -1e9f;
            }
    }

    // ---- softmax ----
    float mx[2][4], inv[2][4];
#pragma unroll
    for (int m = 0; m < 2; m++)
#pragma unroll
        for (int r = 0; r < 4; r++) {
            float v = acc[m][0][r];
#pragma unroll
            for (int n = 1; n < 8; n++) v = fmaxf(v, acc[m][n][r]);
            v = fmaxf(v, __shfl_xor(v, 1, 64));
            v = fmaxf(v, __shfl_xor(v, 2, 64));
            v = fmaxf(v, __shfl_xor(v, 4, 64));
            v = fmaxf(v, __shfl_xor(v, 8, 64));
            mx[m][r] = v;
        }
#pragma unroll
    for (int m = 0; m < 2; m++)
#pragma unroll
        for (int n = 0; n < 8; n++)
#pragma unroll
            for (int r = 0; r < 4; r++)
                acc[m][n][r] = __expf(acc[m][n][r] - mx[m][r]);
#pragma unroll
    for (int m = 0; m < 2; m++)
#pragma unroll
        for (int r = 0; r < 4; r++) {
            float v = 0.f;
#pragma unroll
            for (int n = 0; n < 8; n++) v += acc[m][n][r];
            v += __shfl_xor(v, 1, 64);
            v += __shfl_xor(v, 2, 64);
            v += __shfl_xor(v, 4, 64);
            v += __shfl_xor(v, 8, 64);
            inv[m][r] = 1.0f / v;
        }

    __syncthreads();   // V^T staged

    // ---- PV ----
    f32x4 o[2][2];
    {
        f32x4 z = {0.f, 0.f, 0.f, 0.f};
        o[0][0] = z; o[0][1] = z; o[1][0] = z; o[1][1] = z;
    }
    union B8 { bf16x8 v; uint2 u[2]; };
#pragma unroll
    for (int half = 0; half < 2; half++) {
        asm volatile("s_waitcnt lgkmcnt(0)" ::: "memory");
#pragma unroll
        for (int m = 0; m < 2; m++)
#pragma unroll
            for (int nn = 0; nn < 4; nn++)
#pragma unroll
                for (int r = 0; r < 4; r++)
                    Pl[h][m * 16 + lg * 4 + r][nn * 16 + l15]
                        = f2bf(acc[m][half * 4 + nn][r]);
        asm volatile("s_waitcnt lgkmcnt(0)" ::: "memory");
#pragma unroll
        for (int ks2 = 0; ks2 < 2; ks2++) {
            const int jo = ks2 * 32 + lg * 8;
            const int jg = half * 64 + jo;
            B8 pa0, pa1, vb0, vb1;
            pa0.u[0] = *(const uint2*)&Pl[h][l15][jo];
            pa0.u[1] = *(const uint2*)&Pl[h][l15][jo + 4];
            pa1.u[0] = *(const uint2*)&Pl[h][l15 + 16][jo];
            pa1.u[1] = *(const uint2*)&Pl[h][l15 + 16][jo + 4];
            vb0.u[0] = *(const uint2*)&VT[h * DH + l15][jg];
            vb0.u[1] = *(const uint2*)&VT[h * DH + l15][jg + 4];
            vb1.u[0] = *(const uint2*)&VT[h * DH + 16 + l15][jg];
            vb1.u[1] = *(const uint2*)&VT[h * DH + 16 + l15][jg + 4];
            o[0][0] = __builtin_amdgcn_mfma_f32_16x16x32_bf16(pa0.v, vb0.v, o[0][0], 0, 0, 0);
            o[0][1] = __builtin_amdgcn_mfma_f32_16x16x32_bf16(pa0.v, vb1.v, o[0][1], 0, 0, 0);
            o[1][0] = __builtin_amdgcn_mfma_f32_16x16x32_bf16(pa1.v, vb0.v, o[1][0], 0, 0, 0);
            o[1][1] = __builtin_amdgcn_mfma_f32_16x16x32_bf16(pa1.v, vb1.v, o[1][1], 0, 0, 0);
        }
    }

#pragma unroll
    for (int m = 0; m < 2; m++)
#pragma unroll
        for (int n = 0; n < 2; n++)
#pragma unroll
            for (int r = 0; r < 4; r++)
                og[((long long)b * NATOM + row0 + m * 16 + lg * 4 + r) * CA
                   + h * DH + n * 16 + l15]
                    = f2bf(o[m][n][r] * inv[m][r]);
}

// =====================================================================
// Final selector: write d_out as bf16 (flag=1) or f32 (flag=0)
// =====================================================================
__global__ __launch_bounds__(256) void select_kernel(
    const int* __restrict__ flag, const u16* __restrict__ outb,
    void* __restrict__ d_out)
{
    const size_t i = (size_t)blockIdx.x * 256 + threadIdx.x;
    if (*flag) ((u16*)d_out)[i]   = outb[i];
    else       ((float*)d_out)[i] = bf2f(outb[i]);
}

// =====================================================================
// Launch — single dtype-independent pipeline; only wtrans + token
// projection are flag-gated pairs.
// =====================================================================
extern "C" void kernel_launch(void* const* d_in, const int* in_sizes, int n_in,
                              void* d_out, int out_size, void* d_ws, size_t ws_size,
                              hipStream_t stream)
{
    (void)in_sizes; (void)n_in; (void)out_size;
    const size_t NEL = (size_t)BB * NATOM * CA;   // 8388608

    char* p = (char*)d_ws;
    float* x    = (float*)p;  p += NEL * 4;
    u16*   h    = (u16*)p;    p += NEL * 2;
    u16*   qb   = (u16*)p;    p += NEL * 2;
    u16*   kb   = (u16*)p;    p += NEL * 2;
    u16*   vb   = (u16*)p;    p += NEL * 2;
    u16*   ob   = (u16*)p;    p += NEL * 2;
    float* atok = (float*)p;  p += (size_t)BB * NTOK * CA * 4;
    float* tbv  = (float*)p;  p += 8192;
    u16*   outb = (u16*)p;    p += NEL * 2;
    int*   flag = (int*)p;    p += 256;
    u16*   wt   = (u16*)p;    p += (size_t)WT_TOT * 2;
    float* aux  = (float*)p;  p += AX_TOT * 4;
    if ((size_t)(p - (char*)d_ws) > ws_size) return;  // workspace too small

    // 1) detect input storage dtype (writes flag: 1=bf16, 0=f32)
    detect_kernel<<<1, 256, 0, stream>>>((const u32*)d_in[3], flag);

    // 2) weight preprocessing (gated pair; exactly one runs)
    wtrans_kernel<u16><<<41, 256, 0, stream>>>(
        flag, 1, (const u16*)d_in[3], (const u16*)d_in[10], (const u16*)d_in[11],
        (const u16*)d_in[12], (const u16*)d_in[13], (const u16*)d_in[16],
        (const u16*)d_in[17], (const u16*)d_in[4], (const u16*)d_in[5],
        (const u16*)d_in[6], (const u16*)d_in[7], (const u16*)d_in[8],
        (const u16*)d_in[9], (const u16*)d_in[14], (const u16*)d_in[15],
        (const u16*)d_in[18], (const u16*)d_in[19], wt, aux);
    wtrans_kernel<float><<<41, 256, 0, stream>>>(
        flag, 0, (const float*)d_in[3], (const float*)d_in[10], (const float*)d_in[11],
        (const float*)d_in[12], (const float*)d_in[13], (const float*)d_in[16],
        (const float*)d_in[17], (const float*)d_in[4], (const float*)d_in[5],
        (const float*)d_in[6], (const float*)d_in[7], (const float*)d_in[8],
        (const float*)d_in[9], (const float*)d_in[14], (const float*)d_in[15],
        (const float*)d_in[18], (const float*)d_in[19], wt, aux);

    // 3) token projection (gated pair)
    sgemm_bf<1, 3, false, false><<<BB * NTOK / 128, 256, 0, stream>>>(
        flag, 1, (const u16*)d_in[0], CTOK, wt + WT_WA, wt + WT_WA + 49152,
        CTOK, 128, atok, CA);
    sgemm_f32<2, 3, false><<<BB * NTOK / 128, 256, 0, stream>>>(
        flag, 0, (const float*)d_in[0], CTOK, wt + WT_WA, wt + WT_WA + 49152,
        CTOK, 128, atok, CA);

    // 4) gather + layer-0 LN1
    gather_ln_kernel<<<BB * NATOM / 4, 256, 0, stream>>>(
        atok, (const int*)d_in[2], aux + AX_L1G, aux + AX_L1B, x, h);
    bias_kernel<<<1, 512, 0, stream>>>(x, aux, tbv);

    // 5) layers
    for (int l = 0; l < 3; l++) {
        u16* wl = wt + WT_L0 + (size_t)l * WT_LSZ;
        qkv_fused<<<256, 512, 0, stream>>>(h, wl, qb, kb, vb);
        attn_kernel<<<BB * NWIN, 256, 0, stream>>>(qb, kb, vb, tbv, ob);
        sgemm_add_ln<<<512, 256, 0, stream>>>(
            ob, wl + 98304, wl + 98304 + 16384, x,
            aux + AX_L2G + l * 128, aux + AX_L2B + l * 128, h);
        if (l < 2)
            mlp_ln<true><<<256, 512, 0, stream>>>(
                h, wl + 131072, wl + 262144, x,
                aux + AX_L1G + (l + 1) * 128, aux + AX_L1B + (l + 1) * 128, h);
        else
            mlp_ln<false><<<256, 512, 0, stream>>>(
                h, wl + 131072, wl + 262144, x, aux, aux, h);
    }

    // 6) out = x @ W_out -> bf16 outb (always runs)
    sgemm_f32<2, 1, true><<<512, 256, 0, stream>>>(
        flag, -1, x, CA, wt + WT_WO, wt + WT_WO + 16384, CA, 0, outb, CA);

    // 7) write d_out in the detected output format
    select_kernel<<<(unsigned)(NEL / 256), 256, 0, stream>>>(flag, outb, d_out);
}